// Round 2
// baseline (2333.141 us; speedup 1.0000x reference)
//
#include <hip/hip_runtime.h>
#include <math.h>

#define SEQ 2048
#define BSZ 2
#define DM 512
#define DIN 1024
#define DSTATE 16
#define NH 16
#define HD 64
#define CONVDIM 1056
#define DINPROJ 2096
#define DFF 2048
#define ROWS (BSZ*SEQ)

__device__ __forceinline__ float sigf(float x){ return 1.f/(1.f+expf(-x)); }

__device__ __forceinline__ float wave_reduce(float v){
#pragma unroll
  for (int o = 32; o > 0; o >>= 1) v += __shfl_down(v, o);
  return v;
}

// 256-thread block reduce (4 waves)
__device__ __forceinline__ float block_reduce_256(float v, float* sbuf){
  v = wave_reduce(v);
  int lane = threadIdx.x & 63, wid = threadIdx.x >> 6;
  if (lane == 0) sbuf[wid] = v;
  __syncthreads();
  float s = sbuf[0] + sbuf[1] + sbuf[2] + sbuf[3];
  __syncthreads();
  return s;
}

// ---------------- rmsnorm over D=512 ----------------
__global__ __launch_bounds__(256)
void rmsnorm512_k(const float* __restrict__ x, const float* __restrict__ w,
                  float* __restrict__ y, float eps){
  __shared__ float sbuf[4];
  int r = blockIdx.x;
  const float* xr = x + (size_t)r*DM;
  float* yr = y + (size_t)r*DM;
  float v0 = xr[threadIdx.x];
  float v1 = xr[threadIdx.x + 256];
  float ss = block_reduce_256(v0*v0 + v1*v1, sbuf);
  float rs = rsqrtf(ss*(1.f/DM) + eps);
  yr[threadIdx.x]       = w[threadIdx.x]*v0*rs;
  yr[threadIdx.x + 256] = w[threadIdx.x+256]*v1*rs;
}

// ---------------- gated fusion (modifies query rows in place) ----------------
__global__ __launch_bounds__(256)
void gated_fusion_k(float* __restrict__ h,
                    const float* __restrict__ wfc_w, const float* __restrict__ wfc_b,
                    const float* __restrict__ gfc_w, const float* __restrict__ gfc_b){
  int c = blockIdx.x;                // 0..B*NCK-1, contiguous chunks of 16 rows
  float* base = h + (size_t)c*16*DM;
  float* qrow = base + 15*DM;
  __shared__ float q[DM];
  __shared__ float dots[16];
  for (int i = threadIdx.x; i < DM; i += 256) q[i] = qrow[i];
  __syncthreads();
  int wid = threadIdx.x >> 6, lane = threadIdx.x & 63;
  for (int f = wid; f < 16; f += 4){
    const float* wf = (f < 15) ? (wfc_w + (size_t)f*DM) : gfc_w;
    float s = 0.f;
    for (int i = lane; i < DM; i += 64) s += q[i]*wf[i];
    s = wave_reduce(s);
    if (lane == 0) dots[f] = s;
  }
  __syncthreads();
  if (threadIdx.x == 0){
    float mx = -1e30f;
    for (int f = 0; f < 15; f++){ dots[f] += wfc_b[f]; mx = fmaxf(mx, dots[f]); }
    float sum = 0.f;
    for (int f = 0; f < 15; f++){ float e = expf(dots[f]-mx); dots[f] = e; sum += e; }
    float inv = 1.f/sum;
    for (int f = 0; f < 15; f++) dots[f] *= inv;
    float g = sigf(dots[15] + gfc_b[0]);
    dots[15] = g*0.98f + 0.01f;
  }
  __syncthreads();
  float gate = dots[15];
  for (int d = threadIdx.x; d < DM; d += 256){
    float agg = 0.f;
#pragma unroll
    for (int f = 0; f < 15; f++) agg += base[(size_t)f*DM + d]*dots[f];
    qrow[d] = q[d]*(1.f-gate) + agg*gate;
  }
}

// ---------------- generic C = A @ W^T, optional bias/silu/epilogue adds/flip ----------------
__global__ __launch_bounds__(256)
void gemm_k(const float* __restrict__ A, const float* __restrict__ W,
            const float* __restrict__ bias,
            const float* __restrict__ add1, const float* __restrict__ add2,
            float* __restrict__ C, int M, int N, int K, int flip, int act){
  __shared__ __align__(16) float As[16][68];
  __shared__ __align__(16) float Bs[16][68];
  int tid = threadIdx.x;
  int n0 = blockIdx.x*64, m0 = blockIdx.y*64;
  int lr = tid >> 2, lk = (tid & 3)*4;
  int tx = tid & 15, ty = tid >> 4;
  float acc[4][4] = {};
  int am = m0 + lr;
  if (flip) am = (am & ~(SEQ-1)) | ((SEQ-1) - (am & (SEQ-1)));
  const float* Arow = A + (size_t)am*K + lk;
  const float* Wrow = (n0 + lr < N) ? (W + (size_t)(n0+lr)*K + lk) : nullptr;
  for (int k0 = 0; k0 < K; k0 += 16){
    float4 av = *(const float4*)(Arow + k0);
    float4 wv = Wrow ? *(const float4*)(Wrow + k0) : make_float4(0.f,0.f,0.f,0.f);
    As[lk+0][lr]=av.x; As[lk+1][lr]=av.y; As[lk+2][lr]=av.z; As[lk+3][lr]=av.w;
    Bs[lk+0][lr]=wv.x; Bs[lk+1][lr]=wv.y; Bs[lk+2][lr]=wv.z; Bs[lk+3][lr]=wv.w;
    __syncthreads();
#pragma unroll
    for (int k = 0; k < 16; k++){
      float4 a = *(const float4*)&As[k][ty*4];
      float4 b = *(const float4*)&Bs[k][tx*4];
      acc[0][0] += a.x*b.x; acc[0][1] += a.x*b.y; acc[0][2] += a.x*b.z; acc[0][3] += a.x*b.w;
      acc[1][0] += a.y*b.x; acc[1][1] += a.y*b.y; acc[1][2] += a.y*b.z; acc[1][3] += a.y*b.w;
      acc[2][0] += a.z*b.x; acc[2][1] += a.z*b.y; acc[2][2] += a.z*b.z; acc[2][3] += a.z*b.w;
      acc[3][0] += a.w*b.x; acc[3][1] += a.w*b.y; acc[3][2] += a.w*b.z; acc[3][3] += a.w*b.w;
    }
    __syncthreads();
  }
#pragma unroll
  for (int i = 0; i < 4; i++){
    int m = m0 + ty*4 + i;
    float* crow = C + (size_t)m*N;
#pragma unroll
    for (int j = 0; j < 4; j++){
      int n = n0 + tx*4 + j;
      if (n < N){
        float v = acc[i][j];
        if (bias) v += bias[n];
        if (act == 1) v = v*sigf(v);
        if (add1) v += add1[(size_t)m*N + n] + add2[(size_t)m*N + n];
        crow[n] = v;
      }
    }
  }
}

// ---------------- causal depthwise conv (width 4) + silu + split ----------------
__global__ __launch_bounds__(256)
void conv_silu_k(const float* __restrict__ zx, const float* __restrict__ convw,
                 const float* __restrict__ convb,
                 float* __restrict__ xs, float* __restrict__ Bm, float* __restrict__ Cm){
  int c = blockIdx.x*256 + threadIdx.x;
  int r = blockIdx.y;
  if (c >= CONVDIM) return;
  int l = r & (SEQ-1);
  int rbase = r - l;
  float acc = convb[c];
#pragma unroll
  for (int k = 0; k < 4; k++){
    int ls = l + k - 3;
    if (ls >= 0) acc += zx[(size_t)(rbase+ls)*DINPROJ + DIN + c]*convw[c*4 + k];
  }
  float v = acc*sigf(acc);
  if (c < DIN) xs[(size_t)r*DIN + c] = v;
  else if (c < DIN + DSTATE) Bm[(size_t)r*DSTATE + (c - DIN)] = v;
  else Cm[(size_t)r*DSTATE + (c - DIN - DSTATE)] = v;
}

// ---------------- dt: softplus + dA ----------------
__global__ __launch_bounds__(256)
void dt_k(const float* __restrict__ zx, const float* __restrict__ dtbias,
          const float* __restrict__ Alog, float* __restrict__ dtv, float* __restrict__ dAv){
  int idx = blockIdx.x*256 + threadIdx.x;
  if (idx >= ROWS*NH) return;
  int r = idx >> 4, hh = idx & 15;
  float x = zx[(size_t)r*DINPROJ + (DIN + CONVDIM) + hh] + dtbias[hh];
  float sp = (x > 20.f) ? x : log1pf(expf(x));
  dtv[idx] = sp;
  dAv[idx] = expf(-expf(Alog[hh])*sp);
}

// ---------------- sequential selective scan: one WAVE per (b,h) ----------------
// Lane = p (HEADDIM=64). State h[p][n], n=0..15, in 16 registers per lane.
// B,C rows are wave-uniform -> staged per-64-t chunk in LDS, broadcast float4 reads.
// dt is scalar per t -> folded into x. Zero cross-lane ops in the hot loop.
__global__ __launch_bounds__(64)
void scan_k(const float* __restrict__ xs, const float* __restrict__ Bm,
            const float* __restrict__ Cm, const float* __restrict__ dtv,
            const float* __restrict__ dAv, float* __restrict__ y){
  int b = blockIdx.x >> 4, h = blockIdx.x & 15;
  int p = threadIdx.x;   // 0..63
  __shared__ __align__(16) float sB[64][16];
  __shared__ __align__(16) float sC[64][16];
  __shared__ float sdA[64];
  __shared__ float sdt[64];
  const float* xb  = xs  + (size_t)b*SEQ*DIN + h*HD;
  const float* Bb  = Bm  + (size_t)b*SEQ*DSTATE;
  const float* Cb  = Cm  + (size_t)b*SEQ*DSTATE;
  const float* dtb = dtv + (size_t)b*SEQ*NH + h;
  const float* dAb = dAv + (size_t)b*SEQ*NH + h;
  float* yb = y + (size_t)b*SEQ*DIN + h*HD;

  float hst[16];
#pragma unroll
  for (int n = 0; n < 16; n++) hst[n] = 0.f;

  for (int l0 = 0; l0 < SEQ; l0 += 64){
    __syncthreads();
    sdt[p] = dtb[(size_t)(l0+p)*NH];
    sdA[p] = dAb[(size_t)(l0+p)*NH];
#pragma unroll
    for (int k = 0; k < 16; k++){
      int i = p + k*64;           // 0..1023, contiguous -> coalesced
      ((float*)sB)[i] = Bb[(size_t)l0*DSTATE + i];
      ((float*)sC)[i] = Cb[(size_t)l0*DSTATE + i];
    }
    __syncthreads();
#pragma unroll 4
    for (int t = 0; t < 64; t++){
      float xv = xb[(size_t)(l0+t)*DIN + p] * sdt[t];
      float dA = sdA[t];
      float4 b0 = *(const float4*)&sB[t][0];
      float4 b1 = *(const float4*)&sB[t][4];
      float4 b2 = *(const float4*)&sB[t][8];
      float4 b3 = *(const float4*)&sB[t][12];
      hst[0]  = fmaf(dA, hst[0],  b0.x*xv);
      hst[1]  = fmaf(dA, hst[1],  b0.y*xv);
      hst[2]  = fmaf(dA, hst[2],  b0.z*xv);
      hst[3]  = fmaf(dA, hst[3],  b0.w*xv);
      hst[4]  = fmaf(dA, hst[4],  b1.x*xv);
      hst[5]  = fmaf(dA, hst[5],  b1.y*xv);
      hst[6]  = fmaf(dA, hst[6],  b1.z*xv);
      hst[7]  = fmaf(dA, hst[7],  b1.w*xv);
      hst[8]  = fmaf(dA, hst[8],  b2.x*xv);
      hst[9]  = fmaf(dA, hst[9],  b2.y*xv);
      hst[10] = fmaf(dA, hst[10], b2.z*xv);
      hst[11] = fmaf(dA, hst[11], b2.w*xv);
      hst[12] = fmaf(dA, hst[12], b3.x*xv);
      hst[13] = fmaf(dA, hst[13], b3.y*xv);
      hst[14] = fmaf(dA, hst[14], b3.z*xv);
      hst[15] = fmaf(dA, hst[15], b3.w*xv);
      float4 c0 = *(const float4*)&sC[t][0];
      float4 c1 = *(const float4*)&sC[t][4];
      float4 c2 = *(const float4*)&sC[t][8];
      float4 c3 = *(const float4*)&sC[t][12];
      float a0 = hst[0]*c0.x;  a0 = fmaf(hst[1],  c0.y, a0);
      a0 = fmaf(hst[2],  c0.z, a0); a0 = fmaf(hst[3],  c0.w, a0);
      float a1 = hst[4]*c1.x;  a1 = fmaf(hst[5],  c1.y, a1);
      a1 = fmaf(hst[6],  c1.z, a1); a1 = fmaf(hst[7],  c1.w, a1);
      float a2 = hst[8]*c2.x;  a2 = fmaf(hst[9],  c2.y, a2);
      a2 = fmaf(hst[10], c2.z, a2); a2 = fmaf(hst[11], c2.w, a2);
      float a3 = hst[12]*c3.x; a3 = fmaf(hst[13], c3.y, a3);
      a3 = fmaf(hst[14], c3.z, a3); a3 = fmaf(hst[15], c3.w, a3);
      yb[(size_t)(l0+t)*DIN + p] = (a0+a1)+(a2+a3);
    }
  }
}

// ---------------- y = (yscan + D*x) * silu(z); rmsnorm(1024); in-place on yscan ----------------
__global__ __launch_bounds__(256)
void gated_rms_k(float* __restrict__ y, const float* __restrict__ xs,
                 const float* __restrict__ zx, const float* __restrict__ Dp,
                 const float* __restrict__ normw){
  __shared__ float sbuf[4];
  int r = blockIdx.x;
  float* yr = y + (size_t)r*DIN;
  const float* xr = xs + (size_t)r*DIN;
  const float* zr = zx + (size_t)r*DINPROJ;
  float vals[4]; float ss = 0.f;
#pragma unroll
  for (int i = 0; i < 4; i++){
    int d = threadIdx.x + i*256;
    float yv = yr[d] + Dp[d >> 6]*xr[d];
    float z = zr[d];
    float g = yv*(z*sigf(z));
    vals[i] = g; ss += g*g;
  }
  ss = block_reduce_256(ss, sbuf);
  float rs = rsqrtf(ss*(1.f/DIN) + 1e-5f);
#pragma unroll
  for (int i = 0; i < 4; i++){
    int d = threadIdx.x + i*256;
    yr[d] = normw[d]*vals[i]*rs;
  }
}

// ---------------- hsum = outf + flip(outb) + hid; h2 = rmsnorm(hsum, norm2_w) ----------------
__global__ __launch_bounds__(256)
void addres_rms_k(const float* __restrict__ outf, const float* __restrict__ outb,
                  const float* __restrict__ hid, const float* __restrict__ w,
                  float* __restrict__ hsum, float* __restrict__ h2){
  __shared__ float sbuf[4];
  int r = blockIdx.x;
  int l = r & (SEQ-1);
  int rb = (r - l) + ((SEQ-1) - l);
  float vals[2]; float ss = 0.f;
#pragma unroll
  for (int i = 0; i < 2; i++){
    int d = threadIdx.x + i*256;
    float v = outf[(size_t)r*DM + d] + outb[(size_t)rb*DM + d] + hid[(size_t)r*DM + d];
    hsum[(size_t)r*DM + d] = v;
    vals[i] = v; ss += v*v;
  }
  ss = block_reduce_256(ss, sbuf);
  float rs = rsqrtf(ss*(1.f/DM) + 1e-6f);
#pragma unroll
  for (int i = 0; i < 2; i++){
    int d = threadIdx.x + i*256;
    h2[(size_t)r*DM + d] = w[d]*vals[i]*rs;
  }
}

extern "C" void kernel_launch(void* const* d_in, const int* in_sizes, int n_in,
                              void* d_out, int out_size, void* d_ws, size_t ws_size,
                              hipStream_t stream){
  const float* hid     = (const float*)d_in[0];
  const float* norm1_w = (const float*)d_in[1];
  const float* wfc_w   = (const float*)d_in[2];
  const float* wfc_b   = (const float*)d_in[3];
  const float* gfc_w   = (const float*)d_in[4];
  const float* gfc_b   = (const float*)d_in[5];
  const float* norm2_w = (const float*)d_in[6];
  const float* fc1_w   = (const float*)d_in[7];
  const float* fc1_b   = (const float*)d_in[8];
  const float* fc2_w   = (const float*)d_in[9];
  const float* fc2_b   = (const float*)d_in[10];
  const float* inproj[2]  = {(const float*)d_in[11], (const float*)d_in[19]};
  const float* convw[2]   = {(const float*)d_in[12], (const float*)d_in[20]};
  const float* convb[2]   = {(const float*)d_in[13], (const float*)d_in[21]};
  const float* dtbias[2]  = {(const float*)d_in[14], (const float*)d_in[22]};
  const float* Alog[2]    = {(const float*)d_in[15], (const float*)d_in[23]};
  const float* Dp[2]      = {(const float*)d_in[16], (const float*)d_in[24]};
  const float* normw[2]   = {(const float*)d_in[17], (const float*)d_in[25]};
  const float* outproj[2] = {(const float*)d_in[18], (const float*)d_in[26]};

  float* ws = (float*)d_ws;
  float* hnorm = ws;                       // 2,097,152
  float* zx    = hnorm + 2097152;          // 8,585,216 (reused later as a1)
  float* xs    = zx + 8585216;             // 4,194,304 (reused later as h2)
  float* Bmb   = xs + 4194304;             // 65,536
  float* Cmb   = Bmb + 65536;              // 65,536
  float* dtv   = Cmb + 65536;              // 65,536
  float* dAv   = dtv + 65536;              // 65,536
  float* ysc   = dAv + 65536;              // 4,194,304
  float* outd0 = ysc + 4194304;            // 2,097,152
  float* outd1 = outd0 + 2097152;          // 2,097,152
  float* hsum  = outd1 + 2097152;          // 2,097,152
  float* a1 = zx;
  float* h2 = xs;
  size_t need_bytes = (size_t)(25624576)*4;
  if (ws_size < need_bytes) return;

  rmsnorm512_k<<<ROWS, 256, 0, stream>>>(hid, norm1_w, hnorm, 1e-6f);
  gated_fusion_k<<<BSZ*(SEQ/16), 256, 0, stream>>>(hnorm, wfc_w, wfc_b, gfc_w, gfc_b);

  float* outd[2] = {outd0, outd1};
  for (int dir = 0; dir < 2; dir++){
    gemm_k<<<dim3((DINPROJ+63)/64, ROWS/64), 256, 0, stream>>>(
        hnorm, inproj[dir], nullptr, nullptr, nullptr, zx, ROWS, DINPROJ, DM, dir, 0);
    conv_silu_k<<<dim3((CONVDIM+255)/256, ROWS), 256, 0, stream>>>(
        zx, convw[dir], convb[dir], xs, Bmb, Cmb);
    dt_k<<<(ROWS*NH+255)/256, 256, 0, stream>>>(zx, dtbias[dir], Alog[dir], dtv, dAv);
    scan_k<<<BSZ*NH, 64, 0, stream>>>(xs, Bmb, Cmb, dtv, dAv, ysc);
    gated_rms_k<<<ROWS, 256, 0, stream>>>(ysc, xs, zx, Dp[dir], normw[dir]);
    gemm_k<<<dim3(DM/64, ROWS/64), 256, 0, stream>>>(
        ysc, outproj[dir], nullptr, nullptr, nullptr, outd[dir], ROWS, DM, DIN, 0, 0);
  }

  addres_rms_k<<<ROWS, 256, 0, stream>>>(outd0, outd1, hid, norm2_w, hsum, h2);
  gemm_k<<<dim3(DFF/64, ROWS/64), 256, 0, stream>>>(
      h2, fc1_w, fc1_b, nullptr, nullptr, a1, ROWS, DFF, DM, 0, 1);
  gemm_k<<<dim3(DM/64, ROWS/64), 256, 0, stream>>>(
      a1, fc2_w, fc2_b, hsum, hid, (float*)d_out, ROWS, DM, DFF, 0, 0);
}

// Round 3
// 863.774 us; speedup vs baseline: 2.7011x; 2.7011x over previous
//
#include <hip/hip_runtime.h>
#include <math.h>

#define SEQ 2048
#define BSZ 2
#define DM 512
#define DIN 1024
#define DSTATE 16
#define NH 16
#define HD 64
#define CONVDIM 1056
#define DINPROJ 2096
#define DFF 2048
#define ROWS (BSZ*SEQ)
#define NCH 16          // chunks per sequence
#define CT  (SEQ/NCH)   // 128 timesteps per chunk

__device__ __forceinline__ float sigf(float x){ return 1.f/(1.f+expf(-x)); }

__device__ __forceinline__ float wave_reduce(float v){
#pragma unroll
  for (int o = 32; o > 0; o >>= 1) v += __shfl_down(v, o);
  return v;
}

__device__ __forceinline__ float block_reduce_256(float v, float* sbuf){
  v = wave_reduce(v);
  int lane = threadIdx.x & 63, wid = threadIdx.x >> 6;
  if (lane == 0) sbuf[wid] = v;
  __syncthreads();
  float s = sbuf[0] + sbuf[1] + sbuf[2] + sbuf[3];
  __syncthreads();
  return s;
}

// ---------------- rmsnorm over D=512 ----------------
__global__ __launch_bounds__(256)
void rmsnorm512_k(const float* __restrict__ x, const float* __restrict__ w,
                  float* __restrict__ y, float eps){
  __shared__ float sbuf[4];
  int r = blockIdx.x;
  const float* xr = x + (size_t)r*DM;
  float* yr = y + (size_t)r*DM;
  float v0 = xr[threadIdx.x];
  float v1 = xr[threadIdx.x + 256];
  float ss = block_reduce_256(v0*v0 + v1*v1, sbuf);
  float rs = rsqrtf(ss*(1.f/DM) + eps);
  yr[threadIdx.x]       = w[threadIdx.x]*v0*rs;
  yr[threadIdx.x + 256] = w[threadIdx.x+256]*v1*rs;
}

// ---------------- gated fusion (modifies query rows in place) ----------------
__global__ __launch_bounds__(256)
void gated_fusion_k(float* __restrict__ h,
                    const float* __restrict__ wfc_w, const float* __restrict__ wfc_b,
                    const float* __restrict__ gfc_w, const float* __restrict__ gfc_b){
  int c = blockIdx.x;
  float* base = h + (size_t)c*16*DM;
  float* qrow = base + 15*DM;
  __shared__ float q[DM];
  __shared__ float dots[16];
  for (int i = threadIdx.x; i < DM; i += 256) q[i] = qrow[i];
  __syncthreads();
  int wid = threadIdx.x >> 6, lane = threadIdx.x & 63;
  for (int f = wid; f < 16; f += 4){
    const float* wf = (f < 15) ? (wfc_w + (size_t)f*DM) : gfc_w;
    float s = 0.f;
    for (int i = lane; i < DM; i += 64) s += q[i]*wf[i];
    s = wave_reduce(s);
    if (lane == 0) dots[f] = s;
  }
  __syncthreads();
  if (threadIdx.x == 0){
    float mx = -1e30f;
    for (int f = 0; f < 15; f++){ dots[f] += wfc_b[f]; mx = fmaxf(mx, dots[f]); }
    float sum = 0.f;
    for (int f = 0; f < 15; f++){ float e = expf(dots[f]-mx); dots[f] = e; sum += e; }
    float inv = 1.f/sum;
    for (int f = 0; f < 15; f++) dots[f] *= inv;
    float g = sigf(dots[15] + gfc_b[0]);
    dots[15] = g*0.98f + 0.01f;
  }
  __syncthreads();
  float gate = dots[15];
  for (int d = threadIdx.x; d < DM; d += 256){
    float agg = 0.f;
#pragma unroll
    for (int f = 0; f < 15; f++) agg += base[(size_t)f*DM + d]*dots[f];
    qrow[d] = q[d]*(1.f-gate) + agg*gate;
  }
}

// ---------------- generic C = A @ W^T ----------------
__global__ __launch_bounds__(256)
void gemm_k(const float* __restrict__ A, const float* __restrict__ W,
            const float* __restrict__ bias,
            const float* __restrict__ add1, const float* __restrict__ add2,
            float* __restrict__ C, int M, int N, int K, int flip, int act){
  __shared__ __align__(16) float As[16][68];
  __shared__ __align__(16) float Bs[16][68];
  int tid = threadIdx.x;
  int n0 = blockIdx.x*64, m0 = blockIdx.y*64;
  int lr = tid >> 2, lk = (tid & 3)*4;
  int tx = tid & 15, ty = tid >> 4;
  float acc[4][4] = {};
  int am = m0 + lr;
  if (flip) am = (am & ~(SEQ-1)) | ((SEQ-1) - (am & (SEQ-1)));
  const float* Arow = A + (size_t)am*K + lk;
  const float* Wrow = (n0 + lr < N) ? (W + (size_t)(n0+lr)*K + lk) : nullptr;
  for (int k0 = 0; k0 < K; k0 += 16){
    float4 av = *(const float4*)(Arow + k0);
    float4 wv = Wrow ? *(const float4*)(Wrow + k0) : make_float4(0.f,0.f,0.f,0.f);
    As[lk+0][lr]=av.x; As[lk+1][lr]=av.y; As[lk+2][lr]=av.z; As[lk+3][lr]=av.w;
    Bs[lk+0][lr]=wv.x; Bs[lk+1][lr]=wv.y; Bs[lk+2][lr]=wv.z; Bs[lk+3][lr]=wv.w;
    __syncthreads();
#pragma unroll
    for (int k = 0; k < 16; k++){
      float4 a = *(const float4*)&As[k][ty*4];
      float4 b = *(const float4*)&Bs[k][tx*4];
      acc[0][0] += a.x*b.x; acc[0][1] += a.x*b.y; acc[0][2] += a.x*b.z; acc[0][3] += a.x*b.w;
      acc[1][0] += a.y*b.x; acc[1][1] += a.y*b.y; acc[1][2] += a.y*b.z; acc[1][3] += a.y*b.w;
      acc[2][0] += a.z*b.x; acc[2][1] += a.z*b.y; acc[2][2] += a.z*b.z; acc[2][3] += a.z*b.w;
      acc[3][0] += a.w*b.x; acc[3][1] += a.w*b.y; acc[3][2] += a.w*b.z; acc[3][3] += a.w*b.w;
    }
    __syncthreads();
  }
#pragma unroll
  for (int i = 0; i < 4; i++){
    int m = m0 + ty*4 + i;
    float* crow = C + (size_t)m*N;
#pragma unroll
    for (int j = 0; j < 4; j++){
      int n = n0 + tx*4 + j;
      if (n < N){
        float v = acc[i][j];
        if (bias) v += bias[n];
        if (act == 1) v = v*sigf(v);
        if (add1) v += add1[(size_t)m*N + n] + add2[(size_t)m*N + n];
        crow[n] = v;
      }
    }
  }
}

// ---------------- causal depthwise conv (width 4) + silu + split ----------------
__global__ __launch_bounds__(256)
void conv_silu_k(const float* __restrict__ zx, const float* __restrict__ convw,
                 const float* __restrict__ convb,
                 float* __restrict__ xs, float* __restrict__ Bm, float* __restrict__ Cm){
  int c = blockIdx.x*256 + threadIdx.x;
  int r = blockIdx.y;
  if (c >= CONVDIM) return;
  int l = r & (SEQ-1);
  int rbase = r - l;
  float acc = convb[c];
#pragma unroll
  for (int k = 0; k < 4; k++){
    int ls = l + k - 3;
    if (ls >= 0) acc += zx[(size_t)(rbase+ls)*DINPROJ + DIN + c]*convw[c*4 + k];
  }
  float v = acc*sigf(acc);
  if (c < DIN) xs[(size_t)r*DIN + c] = v;
  else if (c < DIN + DSTATE) Bm[(size_t)r*DSTATE + (c - DIN)] = v;
  else Cm[(size_t)r*DSTATE + (c - DIN - DSTATE)] = v;
}

// ---------------- dt: softplus + dA ----------------
__global__ __launch_bounds__(256)
void dt_k(const float* __restrict__ zx, const float* __restrict__ dtbias,
          const float* __restrict__ Alog, float* __restrict__ dtv, float* __restrict__ dAv){
  int idx = blockIdx.x*256 + threadIdx.x;
  if (idx >= ROWS*NH) return;
  int r = idx >> 4, hh = idx & 15;
  float x = zx[(size_t)r*DINPROJ + (DIN + CONVDIM) + hh] + dtbias[hh];
  float sp = (x > 20.f) ? x : log1pf(expf(x));
  dtv[idx] = sp;
  dAv[idx] = expf(-expf(Alog[hh])*sp);
}

// ================= chunked selective scan =================
// h_t = a_t h_{t-1} + u_t with SCALAR a_t per (t,h) and rank-1 u_t.
// scanA: per-chunk local scan (h_start=0): writes y_local, P_c = prod a,
//        H_c = end state. 1 wave per (b,h,chunk); x double-buffered 16 ahead.
// scanC: h_start_c = fold of predecessors' (P,H); y_t += cumprod_a * (C_t . h_start).
__global__ __launch_bounds__(64)
void scanA_k(const float* __restrict__ xs, const float* __restrict__ Bm,
             const float* __restrict__ Cm, const float* __restrict__ dtv,
             const float* __restrict__ dAv, float* __restrict__ y,
             float* __restrict__ Hs, float* __restrict__ Ps){
  int c = blockIdx.x & (NCH-1);
  int h = (blockIdx.x >> 4) & 15;
  int b = blockIdx.x >> 8;
  int p = threadIdx.x;
  int t0 = c*CT;
  __shared__ __align__(16) float sB[CT][16];
  __shared__ __align__(16) float sC[CT][16];
  __shared__ float sdt[CT];
  __shared__ float sdA[CT];
  const float* xb  = xs + ((size_t)b*SEQ + t0)*DIN + h*HD;
  float*       yb  = y  + ((size_t)b*SEQ + t0)*DIN + h*HD;
  const float* Bb  = Bm + ((size_t)b*SEQ + t0)*DSTATE;
  const float* Cb  = Cm + ((size_t)b*SEQ + t0)*DSTATE;
  const float* dtb = dtv + ((size_t)b*SEQ + t0)*NH + h;
  const float* dAb = dAv + ((size_t)b*SEQ + t0)*NH + h;
  // stage B, C, dt, dA for the whole chunk (coalesced)
#pragma unroll
  for (int k = 0; k < (CT*16)/64; k++){
    int i = p + k*64;
    ((float*)sB)[i] = Bb[i];
    ((float*)sC)[i] = Cb[i];
  }
#pragma unroll
  for (int k = 0; k < CT/64; k++){
    int i = p + k*64;
    sdt[i] = dtb[(size_t)i*NH];
    sdA[i] = dAb[(size_t)i*NH];
  }
  __syncthreads();

  float hst[16];
#pragma unroll
  for (int n = 0; n < 16; n++) hst[n] = 0.f;
  float P = 1.f;
  float xcur[16], xnxt[16];
#pragma unroll
  for (int j = 0; j < 16; j++) xcur[j] = xb[(size_t)j*DIN + p];

  for (int tt = 0; tt < CT; tt += 16){
    bool pf = (tt + 16 < CT);
    if (pf){
#pragma unroll
      for (int j = 0; j < 16; j++) xnxt[j] = xb[(size_t)(tt+16+j)*DIN + p];
    }
#pragma unroll
    for (int j = 0; j < 16; j++){
      int t = tt + j;
      float xv = xcur[j]*sdt[t];
      float dA = sdA[t];
      P *= dA;
      float4 b0 = *(const float4*)&sB[t][0];
      float4 b1 = *(const float4*)&sB[t][4];
      float4 b2 = *(const float4*)&sB[t][8];
      float4 b3 = *(const float4*)&sB[t][12];
      hst[0]  = fmaf(dA, hst[0],  b0.x*xv);
      hst[1]  = fmaf(dA, hst[1],  b0.y*xv);
      hst[2]  = fmaf(dA, hst[2],  b0.z*xv);
      hst[3]  = fmaf(dA, hst[3],  b0.w*xv);
      hst[4]  = fmaf(dA, hst[4],  b1.x*xv);
      hst[5]  = fmaf(dA, hst[5],  b1.y*xv);
      hst[6]  = fmaf(dA, hst[6],  b1.z*xv);
      hst[7]  = fmaf(dA, hst[7],  b1.w*xv);
      hst[8]  = fmaf(dA, hst[8],  b2.x*xv);
      hst[9]  = fmaf(dA, hst[9],  b2.y*xv);
      hst[10] = fmaf(dA, hst[10], b2.z*xv);
      hst[11] = fmaf(dA, hst[11], b2.w*xv);
      hst[12] = fmaf(dA, hst[12], b3.x*xv);
      hst[13] = fmaf(dA, hst[13], b3.y*xv);
      hst[14] = fmaf(dA, hst[14], b3.z*xv);
      hst[15] = fmaf(dA, hst[15], b3.w*xv);
      float4 c0 = *(const float4*)&sC[t][0];
      float4 c1 = *(const float4*)&sC[t][4];
      float4 c2 = *(const float4*)&sC[t][8];
      float4 c3 = *(const float4*)&sC[t][12];
      float a0 = hst[0]*c0.x;  a0 = fmaf(hst[1],  c0.y, a0);
      a0 = fmaf(hst[2],  c0.z, a0); a0 = fmaf(hst[3],  c0.w, a0);
      float a1 = hst[4]*c1.x;  a1 = fmaf(hst[5],  c1.y, a1);
      a1 = fmaf(hst[6],  c1.z, a1); a1 = fmaf(hst[7],  c1.w, a1);
      float a2 = hst[8]*c2.x;  a2 = fmaf(hst[9],  c2.y, a2);
      a2 = fmaf(hst[10], c2.z, a2); a2 = fmaf(hst[11], c2.w, a2);
      float a3 = hst[12]*c3.x; a3 = fmaf(hst[13], c3.y, a3);
      a3 = fmaf(hst[14], c3.z, a3); a3 = fmaf(hst[15], c3.w, a3);
      yb[(size_t)t*DIN + p] = (a0+a1)+(a2+a3);
    }
    if (pf){
#pragma unroll
      for (int j = 0; j < 16; j++) xcur[j] = xnxt[j];
    }
  }
  // write chunk summary
  size_t base = ((size_t)((b*NH + h)*NCH + c))*1024;
#pragma unroll
  for (int n = 0; n < 16; n++) Hs[base + n*64 + p] = hst[n];
  if (p == 0) Ps[(b*NH + h)*NCH + c] = P;
}

__global__ __launch_bounds__(64)
void scanC_k(const float* __restrict__ Cm, const float* __restrict__ dAv,
             const float* __restrict__ Hs, const float* __restrict__ Ps,
             float* __restrict__ y){
  int c = blockIdx.x & (NCH-1);
  if (c == 0) return;                 // chunk 0 needs no correction
  int h = (blockIdx.x >> 4) & 15;
  int b = blockIdx.x >> 8;
  int p = threadIdx.x;
  int t0 = c*CT;
  int bh = b*NH + h;
  // fold predecessor summaries: s = P_j * s + H_j, j = 0..c-1
  float hstart[16];
#pragma unroll
  for (int n = 0; n < 16; n++) hstart[n] = 0.f;
  for (int j = 0; j < c; j++){
    float Pj = Ps[bh*NCH + j];
    const float* Hj = Hs + ((size_t)(bh*NCH + j))*1024;
#pragma unroll
    for (int n = 0; n < 16; n++) hstart[n] = fmaf(Pj, hstart[n], Hj[n*64 + p]);
  }
  __shared__ __align__(16) float sC[CT][16];
  __shared__ float sdA[CT];
  const float* Cb  = Cm + ((size_t)b*SEQ + t0)*DSTATE;
  const float* dAb = dAv + ((size_t)b*SEQ + t0)*NH + h;
  float*       yb  = y  + ((size_t)b*SEQ + t0)*DIN + h*HD;
#pragma unroll
  for (int k = 0; k < (CT*16)/64; k++){
    int i = p + k*64;
    ((float*)sC)[i] = Cb[i];
  }
#pragma unroll
  for (int k = 0; k < CT/64; k++){
    int i = p + k*64;
    sdA[i] = dAb[(size_t)i*NH];
  }
  __syncthreads();

  float cp = 1.f;
  float ycur[16], ynxt[16];
#pragma unroll
  for (int j = 0; j < 16; j++) ycur[j] = yb[(size_t)j*DIN + p];
  for (int tt = 0; tt < CT; tt += 16){
    bool pf = (tt + 16 < CT);
    if (pf){
#pragma unroll
      for (int j = 0; j < 16; j++) ynxt[j] = yb[(size_t)(tt+16+j)*DIN + p];
    }
#pragma unroll
    for (int j = 0; j < 16; j++){
      int t = tt + j;
      cp *= sdA[t];
      float4 c0 = *(const float4*)&sC[t][0];
      float4 c1 = *(const float4*)&sC[t][4];
      float4 c2 = *(const float4*)&sC[t][8];
      float4 c3 = *(const float4*)&sC[t][12];
      float a0 = hstart[0]*c0.x;  a0 = fmaf(hstart[1],  c0.y, a0);
      a0 = fmaf(hstart[2],  c0.z, a0); a0 = fmaf(hstart[3],  c0.w, a0);
      float a1 = hstart[4]*c1.x;  a1 = fmaf(hstart[5],  c1.y, a1);
      a1 = fmaf(hstart[6],  c1.z, a1); a1 = fmaf(hstart[7],  c1.w, a1);
      float a2 = hstart[8]*c2.x;  a2 = fmaf(hstart[9],  c2.y, a2);
      a2 = fmaf(hstart[10], c2.z, a2); a2 = fmaf(hstart[11], c2.w, a2);
      float a3 = hstart[12]*c3.x; a3 = fmaf(hstart[13], c3.y, a3);
      a3 = fmaf(hstart[14], c3.z, a3); a3 = fmaf(hstart[15], c3.w, a3);
      float dot = (a0+a1)+(a2+a3);
      yb[(size_t)t*DIN + p] = ycur[j] + cp*dot;
    }
    if (pf){
#pragma unroll
      for (int j = 0; j < 16; j++) ycur[j] = ynxt[j];
    }
  }
}

// ---------------- y = (yscan + D*x) * silu(z); rmsnorm(1024) ----------------
__global__ __launch_bounds__(256)
void gated_rms_k(float* __restrict__ y, const float* __restrict__ xs,
                 const float* __restrict__ zx, const float* __restrict__ Dp,
                 const float* __restrict__ normw){
  __shared__ float sbuf[4];
  int r = blockIdx.x;
  float* yr = y + (size_t)r*DIN;
  const float* xr = xs + (size_t)r*DIN;
  const float* zr = zx + (size_t)r*DINPROJ;
  float vals[4]; float ss = 0.f;
#pragma unroll
  for (int i = 0; i < 4; i++){
    int d = threadIdx.x + i*256;
    float yv = yr[d] + Dp[d >> 6]*xr[d];
    float z = zr[d];
    float g = yv*(z*sigf(z));
    vals[i] = g; ss += g*g;
  }
  ss = block_reduce_256(ss, sbuf);
  float rs = rsqrtf(ss*(1.f/DIN) + 1e-5f);
#pragma unroll
  for (int i = 0; i < 4; i++){
    int d = threadIdx.x + i*256;
    yr[d] = normw[d]*vals[i]*rs;
  }
}

// ---------------- hsum = outf + flip(outb) + hid; h2 = rmsnorm(hsum) ----------------
__global__ __launch_bounds__(256)
void addres_rms_k(const float* __restrict__ outf, const float* __restrict__ outb,
                  const float* __restrict__ hid, const float* __restrict__ w,
                  float* __restrict__ hsum, float* __restrict__ h2){
  __shared__ float sbuf[4];
  int r = blockIdx.x;
  int l = r & (SEQ-1);
  int rb = (r - l) + ((SEQ-1) - l);
  float vals[2]; float ss = 0.f;
#pragma unroll
  for (int i = 0; i < 2; i++){
    int d = threadIdx.x + i*256;
    float v = outf[(size_t)r*DM + d] + outb[(size_t)rb*DM + d] + hid[(size_t)r*DM + d];
    hsum[(size_t)r*DM + d] = v;
    vals[i] = v; ss += v*v;
  }
  ss = block_reduce_256(ss, sbuf);
  float rs = rsqrtf(ss*(1.f/DM) + 1e-6f);
#pragma unroll
  for (int i = 0; i < 2; i++){
    int d = threadIdx.x + i*256;
    h2[(size_t)r*DM + d] = w[d]*vals[i]*rs;
  }
}

extern "C" void kernel_launch(void* const* d_in, const int* in_sizes, int n_in,
                              void* d_out, int out_size, void* d_ws, size_t ws_size,
                              hipStream_t stream){
  const float* hid     = (const float*)d_in[0];
  const float* norm1_w = (const float*)d_in[1];
  const float* wfc_w   = (const float*)d_in[2];
  const float* wfc_b   = (const float*)d_in[3];
  const float* gfc_w   = (const float*)d_in[4];
  const float* gfc_b   = (const float*)d_in[5];
  const float* norm2_w = (const float*)d_in[6];
  const float* fc1_w   = (const float*)d_in[7];
  const float* fc1_b   = (const float*)d_in[8];
  const float* fc2_w   = (const float*)d_in[9];
  const float* fc2_b   = (const float*)d_in[10];
  const float* inproj[2]  = {(const float*)d_in[11], (const float*)d_in[19]};
  const float* convw[2]   = {(const float*)d_in[12], (const float*)d_in[20]};
  const float* convb[2]   = {(const float*)d_in[13], (const float*)d_in[21]};
  const float* dtbias[2]  = {(const float*)d_in[14], (const float*)d_in[22]};
  const float* Alog[2]    = {(const float*)d_in[15], (const float*)d_in[23]};
  const float* Dp[2]      = {(const float*)d_in[16], (const float*)d_in[24]};
  const float* normw[2]   = {(const float*)d_in[17], (const float*)d_in[25]};
  const float* outproj[2] = {(const float*)d_in[18], (const float*)d_in[26]};

  float* ws = (float*)d_ws;
  float* hnorm = ws;                       // 2,097,152
  float* zx    = hnorm + 2097152;          // 8,585,216 (reused later as a1)
  float* xs    = zx + 8585216;             // 4,194,304 (reused later as h2)
  float* Bmb   = xs + 4194304;             // 65,536
  float* Cmb   = Bmb + 65536;              // 65,536
  float* dtv   = Cmb + 65536;              // 65,536
  float* dAv   = dtv + 65536;              // 65,536
  float* ysc   = dAv + 65536;              // 4,194,304
  float* outd0 = ysc + 4194304;            // 2,097,152
  float* outd1 = outd0 + 2097152;          // 2,097,152
  float* hsum  = outd1 + 2097152;          // 2,097,152
  float* a1 = zx;
  float* h2 = xs;
  // chunk-scan summaries live in the hsum region (hsum is only written by
  // addres_rms_k AFTER both scans are done): Hs = 524,288 floats, Ps = 512.
  float* Hs = hsum;
  float* Ps = hsum + 524288;
  size_t need_bytes = (size_t)(25624576)*4;
  if (ws_size < need_bytes) return;

  rmsnorm512_k<<<ROWS, 256, 0, stream>>>(hid, norm1_w, hnorm, 1e-6f);
  gated_fusion_k<<<BSZ*(SEQ/16), 256, 0, stream>>>(hnorm, wfc_w, wfc_b, gfc_w, gfc_b);

  float* outd[2] = {outd0, outd1};
  for (int dir = 0; dir < 2; dir++){
    gemm_k<<<dim3((DINPROJ+63)/64, ROWS/64), 256, 0, stream>>>(
        hnorm, inproj[dir], nullptr, nullptr, nullptr, zx, ROWS, DINPROJ, DM, dir, 0);
    conv_silu_k<<<dim3((CONVDIM+255)/256, ROWS), 256, 0, stream>>>(
        zx, convw[dir], convb[dir], xs, Bmb, Cmb);
    dt_k<<<(ROWS*NH+255)/256, 256, 0, stream>>>(zx, dtbias[dir], Alog[dir], dtv, dAv);
    scanA_k<<<BSZ*NH*NCH, 64, 0, stream>>>(xs, Bmb, Cmb, dtv, dAv, ysc, Hs, Ps);
    scanC_k<<<BSZ*NH*NCH, 64, 0, stream>>>(Cmb, dAv, Hs, Ps, ysc);
    gated_rms_k<<<ROWS, 256, 0, stream>>>(ysc, xs, zx, Dp[dir], normw[dir]);
    gemm_k<<<dim3(DM/64, ROWS/64), 256, 0, stream>>>(
        ysc, outproj[dir], nullptr, nullptr, nullptr, outd[dir], ROWS, DM, DIN, 0, 0);
  }

  addres_rms_k<<<ROWS, 256, 0, stream>>>(outd0, outd1, hid, norm2_w, hsum, h2);
  gemm_k<<<dim3(DFF/64, ROWS/64), 256, 0, stream>>>(
      h2, fc1_w, fc1_b, nullptr, nullptr, a1, ROWS, DFF, DM, 0, 1);
  gemm_k<<<dim3(DM/64, ROWS/64), 256, 0, stream>>>(
      a1, fc2_w, fc2_b, hsum, hid, (float*)d_out, ROWS, DM, DFF, 0, 0);
}

// Round 4
// 403.874 us; speedup vs baseline: 5.7769x; 2.1387x over previous
//
#include <hip/hip_runtime.h>
#include <math.h>

#define SEQ 2048
#define BSZ 2
#define DM 512
#define DIN 1024
#define DSTATE 16
#define NH 16
#define HD 64
#define CONVDIM 1056
#define DINPROJ 2096
#define DFF 2048
#define ROWS (BSZ*SEQ)
#define NCH 16
#define CT  (SEQ/NCH)

typedef short bf16x8 __attribute__((ext_vector_type(8)));
typedef float f32x4  __attribute__((ext_vector_type(4)));

__device__ __forceinline__ float sigf(float x){ return 1.f/(1.f+expf(-x)); }

__device__ __forceinline__ unsigned short f2bf(float f){
  union { float f; unsigned u; } v; v.f = f;
  unsigned r = (v.u + 0x7FFFu + ((v.u >> 16) & 1u)) >> 16;
  return (unsigned short)r;
}
__device__ __forceinline__ float bf2f(unsigned short h){
  union { unsigned u; float f; } v; v.u = ((unsigned)h) << 16;
  return v.f;
}

__device__ __forceinline__ float wave_reduce(float v){
#pragma unroll
  for (int o = 32; o > 0; o >>= 1) v += __shfl_down(v, o);
  return v;
}

__device__ __forceinline__ float block_reduce_256(float v, float* sbuf){
  v = wave_reduce(v);
  int lane = threadIdx.x & 63, wid = threadIdx.x >> 6;
  if (lane == 0) sbuf[wid] = v;
  __syncthreads();
  float s = sbuf[0] + sbuf[1] + sbuf[2] + sbuf[3];
  __syncthreads();
  return s;
}

// ---------------- weight cast + N-pad to bf16 ----------------
__global__ __launch_bounds__(256)
void castpad_k(const float* __restrict__ in, unsigned short* __restrict__ out,
               int N, int K, int Npad){
  int idx = blockIdx.x*256 + threadIdx.x;
  if (idx >= Npad*K) return;
  int n = idx / K, k = idx - n*K;
  out[idx] = (n < N) ? f2bf(in[(size_t)n*K + k]) : (unsigned short)0;
}

// ---------------- rmsnorm over D=512, writes fp32 + bf16 ----------------
__global__ __launch_bounds__(256)
void rmsnorm512_k(const float* __restrict__ x, const float* __restrict__ w,
                  float* __restrict__ y, unsigned short* __restrict__ yb, float eps){
  __shared__ float sbuf[4];
  int r = blockIdx.x;
  const float* xr = x + (size_t)r*DM;
  float v0 = xr[threadIdx.x];
  float v1 = xr[threadIdx.x + 256];
  float ss = block_reduce_256(v0*v0 + v1*v1, sbuf);
  float rs = rsqrtf(ss*(1.f/DM) + eps);
  float o0 = w[threadIdx.x]*v0*rs;
  float o1 = w[threadIdx.x+256]*v1*rs;
  y[(size_t)r*DM + threadIdx.x]       = o0;
  y[(size_t)r*DM + threadIdx.x + 256] = o1;
  yb[(size_t)r*DM + threadIdx.x]       = f2bf(o0);
  yb[(size_t)r*DM + threadIdx.x + 256] = f2bf(o1);
}

// ---------------- gated fusion (query rows, updates fp32 + bf16) ----------------
__global__ __launch_bounds__(256)
void gated_fusion_k(float* __restrict__ h, unsigned short* __restrict__ hb,
                    const float* __restrict__ wfc_w, const float* __restrict__ wfc_b,
                    const float* __restrict__ gfc_w, const float* __restrict__ gfc_b){
  int c = blockIdx.x;
  float* base = h + (size_t)c*16*DM;
  float* qrow = base + 15*DM;
  unsigned short* qrow_b = hb + (size_t)c*16*DM + 15*DM;
  __shared__ float q[DM];
  __shared__ float dots[16];
  for (int i = threadIdx.x; i < DM; i += 256) q[i] = qrow[i];
  __syncthreads();
  int wid = threadIdx.x >> 6, lane = threadIdx.x & 63;
  for (int f = wid; f < 16; f += 4){
    const float* wf = (f < 15) ? (wfc_w + (size_t)f*DM) : gfc_w;
    float s = 0.f;
    for (int i = lane; i < DM; i += 64) s += q[i]*wf[i];
    s = wave_reduce(s);
    if (lane == 0) dots[f] = s;
  }
  __syncthreads();
  if (threadIdx.x == 0){
    float mx = -1e30f;
    for (int f = 0; f < 15; f++){ dots[f] += wfc_b[f]; mx = fmaxf(mx, dots[f]); }
    float sum = 0.f;
    for (int f = 0; f < 15; f++){ float e = expf(dots[f]-mx); dots[f] = e; sum += e; }
    float inv = 1.f/sum;
    for (int f = 0; f < 15; f++) dots[f] *= inv;
    float g = sigf(dots[15] + gfc_b[0]);
    dots[15] = g*0.98f + 0.01f;
  }
  __syncthreads();
  float gate = dots[15];
  for (int d = threadIdx.x; d < DM; d += 256){
    float agg = 0.f;
#pragma unroll
    for (int f = 0; f < 15; f++) agg += base[(size_t)f*DM + d]*dots[f];
    float qn = q[d]*(1.f-gate) + agg*gate;
    qrow[d] = qn;
    qrow_b[d] = f2bf(qn);
  }
}

// ---------------- MFMA bf16 GEMM: C = A @ W^T ----------------
// A: (M,K) bf16 row-major (rows flipped per-SEQ if flip). W: (Np,K) bf16 padded.
// 256 threads; wave grid WM x WN; per-wave FM x FN frags of 16x16; BK=32.
template<int WM, int WN, int FM, int FN>
__global__ __launch_bounds__(256)
void mgemm_k(const unsigned short* __restrict__ A, const unsigned short* __restrict__ W,
             const float* __restrict__ bias, const float* __restrict__ add1,
             const float* __restrict__ add2, float* __restrict__ Cf,
             unsigned short* __restrict__ Cb,
             int K, int Nreal, int flip, int act){
  constexpr int BM = WM*FM*16;
  constexpr int BN = WN*FN*16;
  constexpr int QA = BM/64;
  constexpr int QB = BN/64;
  __shared__ unsigned short As[BM*32];
  __shared__ unsigned short Bs[BN*32];
  int tid = threadIdx.x;
  int w = tid >> 6, lane = tid & 63;
  int n0 = blockIdx.x*BN, m0 = blockIdx.y*BM;
  int wr = w / WN, wc = w % WN;

  f32x4 acc[FM][FN];
#pragma unroll
  for (int i = 0; i < FM; i++)
#pragma unroll
    for (int j = 0; j < FN; j++)
#pragma unroll
      for (int r = 0; r < 4; r++) acc[i][j][r] = 0.f;

  // staging source pointers (per lane)
  const unsigned short* aptr[QA];
#pragma unroll
  for (int q = 0; q < QA; q++){
    int row = q*64 + w*16 + (lane >> 2);
    int gm = m0 + row;
    if (flip) gm = (gm & ~(SEQ-1)) | ((SEQ-1) - (gm & (SEQ-1)));
    aptr[q] = A + (size_t)gm*K + (lane & 3)*8;
  }
  const unsigned short* bptr[QB];
#pragma unroll
  for (int q = 0; q < QB; q++){
    int row = q*64 + w*16 + (lane >> 2);
    bptr[q] = W + (size_t)(n0 + row)*K + (lane & 3)*8;
  }
  // frag LDS offsets
  int aoff[FM], boff[FN];
#pragma unroll
  for (int i = 0; i < FM; i++) aoff[i] = (wr*FM*16 + i*16 + (lane & 15))*32 + (lane >> 4)*8;
#pragma unroll
  for (int j = 0; j < FN; j++) boff[j] = (wc*FN*16 + j*16 + (lane & 15))*32 + (lane >> 4)*8;

  for (int k0 = 0; k0 < K; k0 += 32){
#pragma unroll
    for (int q = 0; q < QA; q++)
      __builtin_amdgcn_global_load_lds(
        (const __attribute__((address_space(1))) void*)(aptr[q] + k0),
        (__attribute__((address_space(3))) void*)&As[(q*64 + w*16)*32], 16, 0, 0);
#pragma unroll
    for (int q = 0; q < QB; q++)
      __builtin_amdgcn_global_load_lds(
        (const __attribute__((address_space(1))) void*)(bptr[q] + k0),
        (__attribute__((address_space(3))) void*)&Bs[(q*64 + w*16)*32], 16, 0, 0);
    __syncthreads();
    bf16x8 af[FM], bfr[FN];
#pragma unroll
    for (int i = 0; i < FM; i++) af[i] = *(const bf16x8*)&As[aoff[i]];
#pragma unroll
    for (int j = 0; j < FN; j++) bfr[j] = *(const bf16x8*)&Bs[boff[j]];
#pragma unroll
    for (int i = 0; i < FM; i++)
#pragma unroll
      for (int j = 0; j < FN; j++)
        acc[i][j] = __builtin_amdgcn_mfma_f32_16x16x32_bf16(af[i], bfr[j], acc[i][j], 0, 0, 0);
    __syncthreads();
  }

  // epilogue: D layout col=lane&15, row=(lane>>4)*4+r
  int mbase = m0 + wr*FM*16 + (lane >> 4)*4;
  int nbase = n0 + wc*FN*16 + (lane & 15);
#pragma unroll
  for (int i = 0; i < FM; i++){
#pragma unroll
    for (int j = 0; j < FN; j++){
      int col = nbase + j*16;
      if (col < Nreal){
        float bv = bias ? bias[col] : 0.f;
#pragma unroll
        for (int r = 0; r < 4; r++){
          size_t idx = (size_t)(mbase + i*16 + r)*Nreal + col;
          float x = acc[i][j][r] + bv;
          if (act) x = x*sigf(x);
          if (add1) x += add1[idx] + add2[idx];
          if (Cb) Cb[idx] = f2bf(x); else Cf[idx] = x;
        }
      }
    }
  }
}

// ---------------- fp32 recompute of zx cols 2048..2095 (B/C conv inputs + dt) ----------------
__global__ __launch_bounds__(256)
void skinny48_k(const float* __restrict__ hnorm, const float* __restrict__ W,
                float* __restrict__ zx, int flip){
  int r = blockIdx.x;
  int rf = flip ? ((r & ~(SEQ-1)) | ((SEQ-1) - (r & (SEQ-1)))) : r;
  __shared__ float row[DM];
  row[threadIdx.x] = hnorm[(size_t)rf*DM + threadIdx.x];
  row[threadIdx.x + 256] = hnorm[(size_t)rf*DM + threadIdx.x + 256];
  __syncthreads();
  int wv = threadIdx.x >> 6, lane = threadIdx.x & 63;
  for (int c = wv; c < 48; c += 4){
    const float* wr = W + (size_t)(2048 + c)*DM;
    float s = 0.f;
#pragma unroll
    for (int i = lane; i < DM; i += 64) s += row[i]*wr[i];
    s = wave_reduce(s);
    if (lane == 0) zx[(size_t)r*DINPROJ + 2048 + c] = s;
  }
}

// ---------------- causal depthwise conv (width 4) + silu + split ----------------
__global__ __launch_bounds__(256)
void conv_silu_k(const float* __restrict__ zx, const float* __restrict__ convw,
                 const float* __restrict__ convb,
                 float* __restrict__ xs, float* __restrict__ Bm, float* __restrict__ Cm){
  int c = blockIdx.x*256 + threadIdx.x;
  int r = blockIdx.y;
  if (c >= CONVDIM) return;
  int l = r & (SEQ-1);
  int rbase = r - l;
  float acc = convb[c];
#pragma unroll
  for (int k = 0; k < 4; k++){
    int ls = l + k - 3;
    if (ls >= 0) acc += zx[(size_t)(rbase+ls)*DINPROJ + DIN + c]*convw[c*4 + k];
  }
  float v = acc*sigf(acc);
  if (c < DIN) xs[(size_t)r*DIN + c] = v;
  else if (c < DIN + DSTATE) Bm[(size_t)r*DSTATE + (c - DIN)] = v;
  else Cm[(size_t)r*DSTATE + (c - DIN - DSTATE)] = v;
}

// ---------------- dt: softplus + dA ----------------
__global__ __launch_bounds__(256)
void dt_k(const float* __restrict__ zx, const float* __restrict__ dtbias,
          const float* __restrict__ Alog, float* __restrict__ dtv, float* __restrict__ dAv){
  int idx = blockIdx.x*256 + threadIdx.x;
  if (idx >= ROWS*NH) return;
  int r = idx >> 4, hh = idx & 15;
  float x = zx[(size_t)r*DINPROJ + (DIN + CONVDIM) + hh] + dtbias[hh];
  float sp = (x > 20.f) ? x : log1pf(expf(x));
  dtv[idx] = sp;
  dAv[idx] = expf(-expf(Alog[hh])*sp);
}

// ================= chunked selective scan =================
__global__ __launch_bounds__(64)
void scanA_k(const float* __restrict__ xs, const float* __restrict__ Bm,
             const float* __restrict__ Cm, const float* __restrict__ dtv,
             const float* __restrict__ dAv, float* __restrict__ y,
             float* __restrict__ Hs, float* __restrict__ Ps){
  int c = blockIdx.x & (NCH-1);
  int h = (blockIdx.x >> 4) & 15;
  int b = blockIdx.x >> 8;
  int p = threadIdx.x;
  int t0 = c*CT;
  __shared__ __align__(16) float sB[CT][16];
  __shared__ __align__(16) float sC[CT][16];
  __shared__ float sdt[CT];
  __shared__ float sdA[CT];
  const float* xb  = xs + ((size_t)b*SEQ + t0)*DIN + h*HD;
  float*       yb  = y  + ((size_t)b*SEQ + t0)*DIN + h*HD;
  const float* Bb  = Bm + ((size_t)b*SEQ + t0)*DSTATE;
  const float* Cb  = Cm + ((size_t)b*SEQ + t0)*DSTATE;
  const float* dtb = dtv + ((size_t)b*SEQ + t0)*NH + h;
  const float* dAb = dAv + ((size_t)b*SEQ + t0)*NH + h;
#pragma unroll
  for (int k = 0; k < (CT*16)/64; k++){
    int i = p + k*64;
    ((float*)sB)[i] = Bb[i];
    ((float*)sC)[i] = Cb[i];
  }
#pragma unroll
  for (int k = 0; k < CT/64; k++){
    int i = p + k*64;
    sdt[i] = dtb[(size_t)i*NH];
    sdA[i] = dAb[(size_t)i*NH];
  }
  __syncthreads();

  float hst[16];
#pragma unroll
  for (int n = 0; n < 16; n++) hst[n] = 0.f;
  float P = 1.f;
  float xcur[16], xnxt[16];
#pragma unroll
  for (int j = 0; j < 16; j++) xcur[j] = xb[(size_t)j*DIN + p];

  for (int tt = 0; tt < CT; tt += 16){
    bool pf = (tt + 16 < CT);
    if (pf){
#pragma unroll
      for (int j = 0; j < 16; j++) xnxt[j] = xb[(size_t)(tt+16+j)*DIN + p];
    }
#pragma unroll
    for (int j = 0; j < 16; j++){
      int t = tt + j;
      float xv = xcur[j]*sdt[t];
      float dA = sdA[t];
      P *= dA;
      float4 b0 = *(const float4*)&sB[t][0];
      float4 b1 = *(const float4*)&sB[t][4];
      float4 b2 = *(const float4*)&sB[t][8];
      float4 b3 = *(const float4*)&sB[t][12];
      hst[0]  = fmaf(dA, hst[0],  b0.x*xv);
      hst[1]  = fmaf(dA, hst[1],  b0.y*xv);
      hst[2]  = fmaf(dA, hst[2],  b0.z*xv);
      hst[3]  = fmaf(dA, hst[3],  b0.w*xv);
      hst[4]  = fmaf(dA, hst[4],  b1.x*xv);
      hst[5]  = fmaf(dA, hst[5],  b1.y*xv);
      hst[6]  = fmaf(dA, hst[6],  b1.z*xv);
      hst[7]  = fmaf(dA, hst[7],  b1.w*xv);
      hst[8]  = fmaf(dA, hst[8],  b2.x*xv);
      hst[9]  = fmaf(dA, hst[9],  b2.y*xv);
      hst[10] = fmaf(dA, hst[10], b2.z*xv);
      hst[11] = fmaf(dA, hst[11], b2.w*xv);
      hst[12] = fmaf(dA, hst[12], b3.x*xv);
      hst[13] = fmaf(dA, hst[13], b3.y*xv);
      hst[14] = fmaf(dA, hst[14], b3.z*xv);
      hst[15] = fmaf(dA, hst[15], b3.w*xv);
      float4 c0 = *(const float4*)&sC[t][0];
      float4 c1 = *(const float4*)&sC[t][4];
      float4 c2 = *(const float4*)&sC[t][8];
      float4 c3 = *(const float4*)&sC[t][12];
      float a0 = hst[0]*c0.x;  a0 = fmaf(hst[1],  c0.y, a0);
      a0 = fmaf(hst[2],  c0.z, a0); a0 = fmaf(hst[3],  c0.w, a0);
      float a1 = hst[4]*c1.x;  a1 = fmaf(hst[5],  c1.y, a1);
      a1 = fmaf(hst[6],  c1.z, a1); a1 = fmaf(hst[7],  c1.w, a1);
      float a2 = hst[8]*c2.x;  a2 = fmaf(hst[9],  c2.y, a2);
      a2 = fmaf(hst[10], c2.z, a2); a2 = fmaf(hst[11], c2.w, a2);
      float a3 = hst[12]*c3.x; a3 = fmaf(hst[13], c3.y, a3);
      a3 = fmaf(hst[14], c3.z, a3); a3 = fmaf(hst[15], c3.w, a3);
      yb[(size_t)t*DIN + p] = (a0+a1)+(a2+a3);
    }
    if (pf){
#pragma unroll
      for (int j = 0; j < 16; j++) xcur[j] = xnxt[j];
    }
  }
  size_t base = ((size_t)((b*NH + h)*NCH + c))*1024;
#pragma unroll
  for (int n = 0; n < 16; n++) Hs[base + n*64 + p] = hst[n];
  if (p == 0) Ps[(b*NH + h)*NCH + c] = P;
}

__global__ __launch_bounds__(64)
void scanC_k(const float* __restrict__ Cm, const float* __restrict__ dAv,
             const float* __restrict__ Hs, const float* __restrict__ Ps,
             float* __restrict__ y){
  int c = blockIdx.x & (NCH-1);
  if (c == 0) return;
  int h = (blockIdx.x >> 4) & 15;
  int b = blockIdx.x >> 8;
  int p = threadIdx.x;
  int t0 = c*CT;
  int bh = b*NH + h;
  float hstart[16];
#pragma unroll
  for (int n = 0; n < 16; n++) hstart[n] = 0.f;
  for (int j = 0; j < c; j++){
    float Pj = Ps[bh*NCH + j];
    const float* Hj = Hs + ((size_t)(bh*NCH + j))*1024;
#pragma unroll
    for (int n = 0; n < 16; n++) hstart[n] = fmaf(Pj, hstart[n], Hj[n*64 + p]);
  }
  __shared__ __align__(16) float sC[CT][16];
  __shared__ float sdA[CT];
  const float* Cb  = Cm + ((size_t)b*SEQ + t0)*DSTATE;
  const float* dAb = dAv + ((size_t)b*SEQ + t0)*NH + h;
  float*       yb  = y  + ((size_t)b*SEQ + t0)*DIN + h*HD;
#pragma unroll
  for (int k = 0; k < (CT*16)/64; k++){
    int i = p + k*64;
    ((float*)sC)[i] = Cb[i];
  }
#pragma unroll
  for (int k = 0; k < CT/64; k++){
    int i = p + k*64;
    sdA[i] = dAb[(size_t)i*NH];
  }
  __syncthreads();

  float cp = 1.f;
  float ycur[16], ynxt[16];
#pragma unroll
  for (int j = 0; j < 16; j++) ycur[j] = yb[(size_t)j*DIN + p];
  for (int tt = 0; tt < CT; tt += 16){
    bool pf = (tt + 16 < CT);
    if (pf){
#pragma unroll
      for (int j = 0; j < 16; j++) ynxt[j] = yb[(size_t)(tt+16+j)*DIN + p];
    }
#pragma unroll
    for (int j = 0; j < 16; j++){
      int t = tt + j;
      cp *= sdA[t];
      float4 c0 = *(const float4*)&sC[t][0];
      float4 c1 = *(const float4*)&sC[t][4];
      float4 c2 = *(const float4*)&sC[t][8];
      float4 c3 = *(const float4*)&sC[t][12];
      float a0 = hstart[0]*c0.x;  a0 = fmaf(hstart[1],  c0.y, a0);
      a0 = fmaf(hstart[2],  c0.z, a0); a0 = fmaf(hstart[3],  c0.w, a0);
      float a1 = hstart[4]*c1.x;  a1 = fmaf(hstart[5],  c1.y, a1);
      a1 = fmaf(hstart[6],  c1.z, a1); a1 = fmaf(hstart[7],  c1.w, a1);
      float a2 = hstart[8]*c2.x;  a2 = fmaf(hstart[9],  c2.y, a2);
      a2 = fmaf(hstart[10], c2.z, a2); a2 = fmaf(hstart[11], c2.w, a2);
      float a3 = hstart[12]*c3.x; a3 = fmaf(hstart[13], c3.y, a3);
      a3 = fmaf(hstart[14], c3.z, a3); a3 = fmaf(hstart[15], c3.w, a3);
      float dot = (a0+a1)+(a2+a3);
      yb[(size_t)t*DIN + p] = ycur[j] + cp*dot;
    }
    if (pf){
#pragma unroll
      for (int j = 0; j < 16; j++) ycur[j] = ynxt[j];
    }
  }
}

// ---------------- y = (yscan + D*x)*silu(z); rmsnorm(1024); out bf16 ----------------
__global__ __launch_bounds__(256)
void gated_rms_k(const float* __restrict__ y, const float* __restrict__ xs,
                 const float* __restrict__ zx, const float* __restrict__ Dp,
                 const float* __restrict__ normw, unsigned short* __restrict__ out){
  __shared__ float sbuf[4];
  int r = blockIdx.x;
  const float* yr = y + (size_t)r*DIN;
  const float* xr = xs + (size_t)r*DIN;
  const float* zr = zx + (size_t)r*DINPROJ;
  float vals[4]; float ss = 0.f;
#pragma unroll
  for (int i = 0; i < 4; i++){
    int d = threadIdx.x + i*256;
    float yv = yr[d] + Dp[d >> 6]*xr[d];
    float z = zr[d];
    float g = yv*(z*sigf(z));
    vals[i] = g; ss += g*g;
  }
  ss = block_reduce_256(ss, sbuf);
  float rs = rsqrtf(ss*(1.f/DIN) + 1e-5f);
#pragma unroll
  for (int i = 0; i < 4; i++){
    int d = threadIdx.x + i*256;
    out[(size_t)r*DIN + d] = f2bf(normw[d]*vals[i]*rs);
  }
}

// ---------------- hsum = outf + flip(outb) + hid; h2_bf = rmsnorm(hsum) ----------------
__global__ __launch_bounds__(256)
void addres_rms_k(const float* __restrict__ outf, const float* __restrict__ outb,
                  const float* __restrict__ hid, const float* __restrict__ w,
                  float* __restrict__ hsum, unsigned short* __restrict__ h2b){
  __shared__ float sbuf[4];
  int r = blockIdx.x;
  int l = r & (SEQ-1);
  int rb = (r - l) + ((SEQ-1) - l);
  float vals[2]; float ss = 0.f;
#pragma unroll
  for (int i = 0; i < 2; i++){
    int d = threadIdx.x + i*256;
    float v = outf[(size_t)r*DM + d] + outb[(size_t)rb*DM + d] + hid[(size_t)r*DM + d];
    hsum[(size_t)r*DM + d] = v;
    vals[i] = v; ss += v*v;
  }
  ss = block_reduce_256(ss, sbuf);
  float rs = rsqrtf(ss*(1.f/DM) + 1e-6f);
#pragma unroll
  for (int i = 0; i < 2; i++){
    int d = threadIdx.x + i*256;
    h2b[(size_t)r*DM + d] = f2bf(w[d]*vals[i]*rs);
  }
}

extern "C" void kernel_launch(void* const* d_in, const int* in_sizes, int n_in,
                              void* d_out, int out_size, void* d_ws, size_t ws_size,
                              hipStream_t stream){
  const float* hid     = (const float*)d_in[0];
  const float* norm1_w = (const float*)d_in[1];
  const float* wfc_w   = (const float*)d_in[2];
  const float* wfc_b   = (const float*)d_in[3];
  const float* gfc_w   = (const float*)d_in[4];
  const float* gfc_b   = (const float*)d_in[5];
  const float* norm2_w = (const float*)d_in[6];
  const float* fc1_w   = (const float*)d_in[7];
  const float* fc1_b   = (const float*)d_in[8];
  const float* fc2_w   = (const float*)d_in[9];
  const float* fc2_b   = (const float*)d_in[10];
  const float* inproj[2]  = {(const float*)d_in[11], (const float*)d_in[19]};
  const float* convw[2]   = {(const float*)d_in[12], (const float*)d_in[20]};
  const float* convb[2]   = {(const float*)d_in[13], (const float*)d_in[21]};
  const float* dtbias[2]  = {(const float*)d_in[14], (const float*)d_in[22]};
  const float* Alog[2]    = {(const float*)d_in[15], (const float*)d_in[23]};
  const float* Dp[2]      = {(const float*)d_in[16], (const float*)d_in[24]};
  const float* normw[2]   = {(const float*)d_in[17], (const float*)d_in[25]};
  const float* outproj[2] = {(const float*)d_in[18], (const float*)d_in[26]};

  float* ws = (float*)d_ws;
  float* zx    = ws;                        // 8,585,216 f
  float* xs    = zx + 8585216;              // 4,194,304 f
  float* Bmb   = xs + 4194304;              // 65,536 f
  float* Cmb   = Bmb + 65536;               // 65,536 f
  float* dtv   = Cmb + 65536;               // 65,536 f
  float* dAv   = dtv + 65536;               // 65,536 f
  float* ysc   = dAv + 65536;               // 4,194,304 f
  float* outd0 = ysc + 4194304;             // 2,097,152 f
  float* outd1 = outd0 + 2097152;           // 2,097,152 f
  float* hsum  = outd1 + 2097152;           // 2,097,152 f  (hosts Hs/Ps, then ysc_bf)
  float* hnorm = hsum + 2097152;            // 2,097,152 f
  unsigned short* hnorm_bf = (unsigned short*)(hnorm + 2097152);   // 2,097,152 bf16 (1,048,576 f slots)
  unsigned short* wbf = (unsigned short*)(hnorm + 2097152 + 1048576); // 5,373,952 bf16
  // overlays:
  float* Hs = hsum;                  // 524,288 f (scan phase only)
  float* Ps = hsum + 524288;         // 512 f
  unsigned short* ysc_bf = (unsigned short*)hsum;   // 4,194,304 bf16 (post-scan phase)
  unsigned short* a1_bf  = (unsigned short*)zx;     // 8,388,608 bf16 (after dir loop)
  unsigned short* h2_bf  = (unsigned short*)xs;     // 2,097,152 bf16 (after dir loop)
  unsigned short* wi[2] = {wbf, wbf + 1114112};
  unsigned short* wo[2] = {wbf + 2228224, wbf + 2752512};
  unsigned short* wf1 = wbf + 3276800;
  unsigned short* wf2 = wbf + 4325376;

  size_t need_bytes = (size_t)29360128*4;
  if (ws_size < need_bytes) return;

  // weight casts (pad inproj N 2096->2176)
  castpad_k<<<(2176*512)/256, 256, 0, stream>>>(inproj[0], wi[0], 2096, 512, 2176);
  castpad_k<<<(2176*512)/256, 256, 0, stream>>>(inproj[1], wi[1], 2096, 512, 2176);
  castpad_k<<<(512*1024)/256, 256, 0, stream>>>(outproj[0], wo[0], 512, 1024, 512);
  castpad_k<<<(512*1024)/256, 256, 0, stream>>>(outproj[1], wo[1], 512, 1024, 512);
  castpad_k<<<(2048*512)/256, 256, 0, stream>>>(fc1_w, wf1, 2048, 512, 2048);
  castpad_k<<<(512*2048)/256, 256, 0, stream>>>(fc2_w, wf2, 512, 2048, 512);

  rmsnorm512_k<<<ROWS, 256, 0, stream>>>(hid, norm1_w, hnorm, hnorm_bf, 1e-6f);
  gated_fusion_k<<<BSZ*(SEQ/16), 256, 0, stream>>>(hnorm, hnorm_bf, wfc_w, wfc_b, gfc_w, gfc_b);

  float* outd[2] = {outd0, outd1};
  for (int dir = 0; dir < 2; dir++){
    mgemm_k<2,2,4,4><<<dim3(2176/128, 4096/128), 256, 0, stream>>>(
        hnorm_bf, wi[dir], nullptr, nullptr, nullptr, zx, nullptr, 512, DINPROJ, dir, 0);
    skinny48_k<<<ROWS, 256, 0, stream>>>(hnorm, inproj[dir], zx, dir);
    conv_silu_k<<<dim3((CONVDIM+255)/256, ROWS), 256, 0, stream>>>(
        zx, convw[dir], convb[dir], xs, Bmb, Cmb);
    dt_k<<<(ROWS*NH+255)/256, 256, 0, stream>>>(zx, dtbias[dir], Alog[dir], dtv, dAv);
    scanA_k<<<BSZ*NH*NCH, 64, 0, stream>>>(xs, Bmb, Cmb, dtv, dAv, ysc, Hs, Ps);
    scanC_k<<<BSZ*NH*NCH, 64, 0, stream>>>(Cmb, dAv, Hs, Ps, ysc);
    gated_rms_k<<<ROWS, 256, 0, stream>>>(ysc, xs, zx, Dp[dir], normw[dir], ysc_bf);
    mgemm_k<1,4,4,2><<<dim3(512/128, 4096/64), 256, 0, stream>>>(
        ysc_bf, wo[dir], nullptr, nullptr, nullptr, outd[dir], nullptr, 1024, DM, 0, 0);
  }

  addres_rms_k<<<ROWS, 256, 0, stream>>>(outd0, outd1, hid, norm2_w, hsum, h2_bf);
  mgemm_k<2,2,4,4><<<dim3(2048/128, 4096/128), 256, 0, stream>>>(
      h2_bf, wf1, fc1_b, nullptr, nullptr, nullptr, a1_bf, 512, DFF, 0, 1);
  mgemm_k<1,4,4,2><<<dim3(512/128, 4096/64), 256, 0, stream>>>(
      a1_bf, wf2, fc2_b, hsum, hid, (float*)d_out, nullptr, 2048, DM, 0, 0);
}

// Round 5
// 360.795 us; speedup vs baseline: 6.4667x; 1.1194x over previous
//
#include <hip/hip_runtime.h>
#include <math.h>

#define SEQ 2048
#define BSZ 2
#define DM 512
#define DIN 1024
#define DSTATE 16
#define NH 16
#define HD 64
#define CONVDIM 1056
#define DINPROJ 2096
#define DFF 2048
#define ROWS (BSZ*SEQ)
#define NCH 16
#define CT  (SEQ/NCH)

typedef short bf16x8 __attribute__((ext_vector_type(8)));
typedef float f32x4  __attribute__((ext_vector_type(4)));

__device__ __forceinline__ float sigf(float x){ return 1.f/(1.f+expf(-x)); }

__device__ __forceinline__ unsigned short f2bf(float f){
  union { float f; unsigned u; } v; v.f = f;
  unsigned r = (v.u + 0x7FFFu + ((v.u >> 16) & 1u)) >> 16;
  return (unsigned short)r;
}

__device__ __forceinline__ float wave_reduce(float v){
#pragma unroll
  for (int o = 32; o > 0; o >>= 1) v += __shfl_down(v, o);
  return v;
}

__device__ __forceinline__ float block_reduce_256(float v, float* sbuf){
  v = wave_reduce(v);
  int lane = threadIdx.x & 63, wid = threadIdx.x >> 6;
  if (lane == 0) sbuf[wid] = v;
  __syncthreads();
  float s = sbuf[0] + sbuf[1] + sbuf[2] + sbuf[3];
  __syncthreads();
  return s;
}

// ---------------- weight cast + N-pad to bf16 ----------------
__global__ __launch_bounds__(256)
void castpad_k(const float* __restrict__ in, unsigned short* __restrict__ out,
               int N, int K, int Npad){
  int idx = blockIdx.x*256 + threadIdx.x;
  if (idx >= Npad*K) return;
  int n = idx / K, k = idx - n*K;
  out[idx] = (n < N) ? f2bf(in[(size_t)n*K + k]) : (unsigned short)0;
}

// ---------------- rmsnorm over D=512, writes fp32 + bf16 ----------------
__global__ __launch_bounds__(256)
void rmsnorm512_k(const float* __restrict__ x, const float* __restrict__ w,
                  float* __restrict__ y, unsigned short* __restrict__ yb, float eps){
  __shared__ float sbuf[4];
  int r = blockIdx.x;
  const float* xr = x + (size_t)r*DM;
  float v0 = xr[threadIdx.x];
  float v1 = xr[threadIdx.x + 256];
  float ss = block_reduce_256(v0*v0 + v1*v1, sbuf);
  float rs = rsqrtf(ss*(1.f/DM) + eps);
  float o0 = w[threadIdx.x]*v0*rs;
  float o1 = w[threadIdx.x+256]*v1*rs;
  y[(size_t)r*DM + threadIdx.x]       = o0;
  y[(size_t)r*DM + threadIdx.x + 256] = o1;
  yb[(size_t)r*DM + threadIdx.x]       = f2bf(o0);
  yb[(size_t)r*DM + threadIdx.x + 256] = f2bf(o1);
}

// ---------------- gated fusion (query rows, updates fp32 + bf16) ----------------
__global__ __launch_bounds__(256)
void gated_fusion_k(float* __restrict__ h, unsigned short* __restrict__ hb,
                    const float* __restrict__ wfc_w, const float* __restrict__ wfc_b,
                    const float* __restrict__ gfc_w, const float* __restrict__ gfc_b){
  int c = blockIdx.x;
  float* base = h + (size_t)c*16*DM;
  float* qrow = base + 15*DM;
  unsigned short* qrow_b = hb + (size_t)c*16*DM + 15*DM;
  __shared__ float q[DM];
  __shared__ float dots[16];
  for (int i = threadIdx.x; i < DM; i += 256) q[i] = qrow[i];
  __syncthreads();
  int wid = threadIdx.x >> 6, lane = threadIdx.x & 63;
  for (int f = wid; f < 16; f += 4){
    const float* wf = (f < 15) ? (wfc_w + (size_t)f*DM) : gfc_w;
    float s = 0.f;
    for (int i = lane; i < DM; i += 64) s += q[i]*wf[i];
    s = wave_reduce(s);
    if (lane == 0) dots[f] = s;
  }
  __syncthreads();
  if (threadIdx.x == 0){
    float mx = -1e30f;
    for (int f = 0; f < 15; f++){ dots[f] += wfc_b[f]; mx = fmaxf(mx, dots[f]); }
    float sum = 0.f;
    for (int f = 0; f < 15; f++){ float e = expf(dots[f]-mx); dots[f] = e; sum += e; }
    float inv = 1.f/sum;
    for (int f = 0; f < 15; f++) dots[f] *= inv;
    float g = sigf(dots[15] + gfc_b[0]);
    dots[15] = g*0.98f + 0.01f;
  }
  __syncthreads();
  float gate = dots[15];
  for (int d = threadIdx.x; d < DM; d += 256){
    float agg = 0.f;
#pragma unroll
    for (int f = 0; f < 15; f++) agg += base[(size_t)f*DM + d]*dots[f];
    float qn = q[d]*(1.f-gate) + agg*gate;
    qrow[d] = qn;
    qrow_b[d] = f2bf(qn);
  }
}

// ---------------- MFMA bf16 GEMM, 2-phase double-buffered LDS ----------------
// C = A @ W^T.  A:(M,K) bf16 (rows flipped per-SEQ if flip), W:(Npad,K) bf16.
// NW waves (NW*64 threads). Wave grid WM x WN; per-wave FM x FN 16x16 frags; BK=32.
// Staging: A-rows then W-rows as unified 16-row groups round-robined over waves;
// next K-tile's global_load_lds issued BEFORE current tile's ds_read+MFMA, so the
// single __syncthreads() (vmcnt0+lgkm0 drain) per K-step hides load latency.
template<int NW, int WM, int WN, int FM, int FN>
__global__ __launch_bounds__(NW*64)
void mgemm_k(const unsigned short* __restrict__ A, const unsigned short* __restrict__ W,
             const float* __restrict__ bias, const float* __restrict__ add1,
             const float* __restrict__ add2, float* __restrict__ Cf,
             unsigned short* __restrict__ Cb,
             int K, int Nreal, int flip, int act){
  constexpr int BM = WM*FM*16;
  constexpr int BN = WN*FN*16;
  constexpr int NG = (BM+BN)/16;          // 16-row staging groups (A rows, then B rows)
  constexpr int MAXG = (NG + NW - 1)/NW;
  __shared__ unsigned short S[2][(BM+BN)*32];
  int tid = threadIdx.x;
  int w = tid >> 6, lane = tid & 63;
  int n0 = blockIdx.x*BN, m0 = blockIdx.y*BM;
  int wr = w / WN, wc = w % WN;

  f32x4 acc[FM][FN];
#pragma unroll
  for (int i = 0; i < FM; i++)
#pragma unroll
    for (int j = 0; j < FN; j++)
#pragma unroll
      for (int r = 0; r < 4; r++) acc[i][j][r] = 0.f;

  // per-wave staging: group g handled by wave g%NW; lane covers row g*16+(lane>>2),
  // 16B chunk (lane&3). Pointers kept in registers via full unroll (static idx).
  const unsigned short* gp[MAXG];
  int gdst[MAXG];
#pragma unroll
  for (int gi = 0; gi < MAXG; gi++){
    int g = w + gi*NW;
    gp[gi] = nullptr; gdst[gi] = 0;
    if (g < NG){
      int r = g*16 + (lane >> 2);
      const unsigned short* src;
      if (r < BM){
        int gm = m0 + r;
        if (flip) gm = (gm & ~(SEQ-1)) | ((SEQ-1) - (gm & (SEQ-1)));
        src = A + (size_t)gm*K;
      } else {
        src = W + (size_t)(n0 + (r - BM))*K;
      }
      gp[gi] = src + (lane & 3)*8;
      gdst[gi] = g*16*32;          // shorts
    }
  }
  // fragment LDS offsets (shorts)
  int aoff[FM], boff[FN];
#pragma unroll
  for (int i = 0; i < FM; i++)
    aoff[i] = (wr*FM*16 + i*16 + (lane & 15))*32 + (lane >> 4)*8;
#pragma unroll
  for (int j = 0; j < FN; j++)
    boff[j] = ((BM + wc*FN*16 + j*16 + (lane & 15)))*32 + (lane >> 4)*8;

  // prologue: stage tile 0 into buf 0
#pragma unroll
  for (int gi = 0; gi < MAXG; gi++)
    if (w + gi*NW < NG)
      __builtin_amdgcn_global_load_lds(
        (const __attribute__((address_space(1))) void*)gp[gi],
        (__attribute__((address_space(3))) void*)&S[0][gdst[gi]], 16, 0, 0);
  __syncthreads();

  int cur = 0;
  for (int k0 = 0; k0 < K; k0 += 32){
    if (k0 + 32 < K){
#pragma unroll
      for (int gi = 0; gi < MAXG; gi++)
        if (w + gi*NW < NG)
          __builtin_amdgcn_global_load_lds(
            (const __attribute__((address_space(1))) void*)(gp[gi] + (k0 + 32)),
            (__attribute__((address_space(3))) void*)&S[cur^1][gdst[gi]], 16, 0, 0);
    }
    bf16x8 af[FM], bfr[FN];
#pragma unroll
    for (int i = 0; i < FM; i++) af[i] = *(const bf16x8*)&S[cur][aoff[i]];
#pragma unroll
    for (int j = 0; j < FN; j++) bfr[j] = *(const bf16x8*)&S[cur][boff[j]];
#pragma unroll
    for (int i = 0; i < FM; i++)
#pragma unroll
      for (int j = 0; j < FN; j++)
        acc[i][j] = __builtin_amdgcn_mfma_f32_16x16x32_bf16(af[i], bfr[j], acc[i][j], 0, 0, 0);
    __syncthreads();   // drains vmcnt(0): buf^1 ready; also protects buf cur for overwrite
    cur ^= 1;
  }

  // epilogue: D layout col=lane&15, row=(lane>>4)*4+r
  int mbase = m0 + wr*FM*16 + (lane >> 4)*4;
  int nbase = n0 + wc*FN*16 + (lane & 15);
#pragma unroll
  for (int i = 0; i < FM; i++){
#pragma unroll
    for (int j = 0; j < FN; j++){
      int col = nbase + j*16;
      if (col < Nreal){
        float bv = bias ? bias[col] : 0.f;
#pragma unroll
        for (int r = 0; r < 4; r++){
          size_t idx = (size_t)(mbase + i*16 + r)*Nreal + col;
          float x = acc[i][j][r] + bv;
          if (act) x = x*sigf(x);
          if (add1) x += add1[idx] + add2[idx];
          if (Cb) Cb[idx] = f2bf(x); else Cf[idx] = x;
        }
      }
    }
  }
}

// ---------------- fp32 recompute of zx cols 2048..2095 (B/C conv inputs + dt) ----------------
__global__ __launch_bounds__(256)
void skinny48_k(const float* __restrict__ hnorm, const float* __restrict__ W,
                float* __restrict__ zx, int flip){
  int r = blockIdx.x;
  int rf = flip ? ((r & ~(SEQ-1)) | ((SEQ-1) - (r & (SEQ-1)))) : r;
  __shared__ float row[DM];
  row[threadIdx.x] = hnorm[(size_t)rf*DM + threadIdx.x];
  row[threadIdx.x + 256] = hnorm[(size_t)rf*DM + threadIdx.x + 256];
  __syncthreads();
  int wv = threadIdx.x >> 6, lane = threadIdx.x & 63;
  for (int c = wv; c < 48; c += 4){
    const float* wr = W + (size_t)(2048 + c)*DM;
    float s = 0.f;
#pragma unroll
    for (int i = lane; i < DM; i += 64) s += row[i]*wr[i];
    s = wave_reduce(s);
    if (lane == 0) zx[(size_t)r*DINPROJ + 2048 + c] = s;
  }
}

// ---------------- causal depthwise conv (width 4) + silu + split ----------------
__global__ __launch_bounds__(256)
void conv_silu_k(const float* __restrict__ zx, const float* __restrict__ convw,
                 const float* __restrict__ convb,
                 float* __restrict__ xs, float* __restrict__ Bm, float* __restrict__ Cm){
  int c = blockIdx.x*256 + threadIdx.x;
  int r = blockIdx.y;
  if (c >= CONVDIM) return;
  int l = r & (SEQ-1);
  int rbase = r - l;
  float acc = convb[c];
#pragma unroll
  for (int k = 0; k < 4; k++){
    int ls = l + k - 3;
    if (ls >= 0) acc += zx[(size_t)(rbase+ls)*DINPROJ + DIN + c]*convw[c*4 + k];
  }
  float v = acc*sigf(acc);
  if (c < DIN) xs[(size_t)r*DIN + c] = v;
  else if (c < DIN + DSTATE) Bm[(size_t)r*DSTATE + (c - DIN)] = v;
  else Cm[(size_t)r*DSTATE + (c - DIN - DSTATE)] = v;
}

// ---------------- dt: softplus + dA ----------------
__global__ __launch_bounds__(256)
void dt_k(const float* __restrict__ zx, const float* __restrict__ dtbias,
          const float* __restrict__ Alog, float* __restrict__ dtv, float* __restrict__ dAv){
  int idx = blockIdx.x*256 + threadIdx.x;
  if (idx >= ROWS*NH) return;
  int r = idx >> 4, hh = idx & 15;
  float x = zx[(size_t)r*DINPROJ + (DIN + CONVDIM) + hh] + dtbias[hh];
  float sp = (x > 20.f) ? x : log1pf(expf(x));
  dtv[idx] = sp;
  dAv[idx] = expf(-expf(Alog[hh])*sp);
}

// ================= chunked selective scan =================
__global__ __launch_bounds__(64)
void scanA_k(const float* __restrict__ xs, const float* __restrict__ Bm,
             const float* __restrict__ Cm, const float* __restrict__ dtv,
             const float* __restrict__ dAv, float* __restrict__ y,
             float* __restrict__ Hs, float* __restrict__ Ps){
  int c = blockIdx.x & (NCH-1);
  int h = (blockIdx.x >> 4) & 15;
  int b = blockIdx.x >> 8;
  int p = threadIdx.x;
  int t0 = c*CT;
  __shared__ __align__(16) float sB[CT][16];
  __shared__ __align__(16) float sC[CT][16];
  __shared__ float sdt[CT];
  __shared__ float sdA[CT];
  const float* xb  = xs + ((size_t)b*SEQ + t0)*DIN + h*HD;
  float*       yb  = y  + ((size_t)b*SEQ + t0)*DIN + h*HD;
  const float* Bb  = Bm + ((size_t)b*SEQ + t0)*DSTATE;
  const float* Cb  = Cm + ((size_t)b*SEQ + t0)*DSTATE;
  const float* dtb = dtv + ((size_t)b*SEQ + t0)*NH + h;
  const float* dAb = dAv + ((size_t)b*SEQ + t0)*NH + h;
#pragma unroll
  for (int k = 0; k < (CT*16)/64; k++){
    int i = p + k*64;
    ((float*)sB)[i] = Bb[i];
    ((float*)sC)[i] = Cb[i];
  }
#pragma unroll
  for (int k = 0; k < CT/64; k++){
    int i = p + k*64;
    sdt[i] = dtb[(size_t)i*NH];
    sdA[i] = dAb[(size_t)i*NH];
  }
  __syncthreads();

  float hst[16];
#pragma unroll
  for (int n = 0; n < 16; n++) hst[n] = 0.f;
  float P = 1.f;
  float xcur[16], xnxt[16];
#pragma unroll
  for (int j = 0; j < 16; j++) xcur[j] = xb[(size_t)j*DIN + p];

  for (int tt = 0; tt < CT; tt += 16){
    bool pf = (tt + 16 < CT);
    if (pf){
#pragma unroll
      for (int j = 0; j < 16; j++) xnxt[j] = xb[(size_t)(tt+16+j)*DIN + p];
    }
#pragma unroll
    for (int j = 0; j < 16; j++){
      int t = tt + j;
      float xv = xcur[j]*sdt[t];
      float dA = sdA[t];
      P *= dA;
      float4 b0 = *(const float4*)&sB[t][0];
      float4 b1 = *(const float4*)&sB[t][4];
      float4 b2 = *(const float4*)&sB[t][8];
      float4 b3 = *(const float4*)&sB[t][12];
      hst[0]  = fmaf(dA, hst[0],  b0.x*xv);
      hst[1]  = fmaf(dA, hst[1],  b0.y*xv);
      hst[2]  = fmaf(dA, hst[2],  b0.z*xv);
      hst[3]  = fmaf(dA, hst[3],  b0.w*xv);
      hst[4]  = fmaf(dA, hst[4],  b1.x*xv);
      hst[5]  = fmaf(dA, hst[5],  b1.y*xv);
      hst[6]  = fmaf(dA, hst[6],  b1.z*xv);
      hst[7]  = fmaf(dA, hst[7],  b1.w*xv);
      hst[8]  = fmaf(dA, hst[8],  b2.x*xv);
      hst[9]  = fmaf(dA, hst[9],  b2.y*xv);
      hst[10] = fmaf(dA, hst[10], b2.z*xv);
      hst[11] = fmaf(dA, hst[11], b2.w*xv);
      hst[12] = fmaf(dA, hst[12], b3.x*xv);
      hst[13] = fmaf(dA, hst[13], b3.y*xv);
      hst[14] = fmaf(dA, hst[14], b3.z*xv);
      hst[15] = fmaf(dA, hst[15], b3.w*xv);
      float4 c0 = *(const float4*)&sC[t][0];
      float4 c1 = *(const float4*)&sC[t][4];
      float4 c2 = *(const float4*)&sC[t][8];
      float4 c3 = *(const float4*)&sC[t][12];
      float a0 = hst[0]*c0.x;  a0 = fmaf(hst[1],  c0.y, a0);
      a0 = fmaf(hst[2],  c0.z, a0); a0 = fmaf(hst[3],  c0.w, a0);
      float a1 = hst[4]*c1.x;  a1 = fmaf(hst[5],  c1.y, a1);
      a1 = fmaf(hst[6],  c1.z, a1); a1 = fmaf(hst[7],  c1.w, a1);
      float a2 = hst[8]*c2.x;  a2 = fmaf(hst[9],  c2.y, a2);
      a2 = fmaf(hst[10], c2.z, a2); a2 = fmaf(hst[11], c2.w, a2);
      float a3 = hst[12]*c3.x; a3 = fmaf(hst[13], c3.y, a3);
      a3 = fmaf(hst[14], c3.z, a3); a3 = fmaf(hst[15], c3.w, a3);
      yb[(size_t)t*DIN + p] = (a0+a1)+(a2+a3);
    }
    if (pf){
#pragma unroll
      for (int j = 0; j < 16; j++) xcur[j] = xnxt[j];
    }
  }
  size_t base = ((size_t)((b*NH + h)*NCH + c))*1024;
#pragma unroll
  for (int n = 0; n < 16; n++) Hs[base + n*64 + p] = hst[n];
  if (p == 0) Ps[(b*NH + h)*NCH + c] = P;
}

__global__ __launch_bounds__(64)
void scanC_k(const float* __restrict__ Cm, const float* __restrict__ dAv,
             const float* __restrict__ Hs, const float* __restrict__ Ps,
             float* __restrict__ y){
  int c = blockIdx.x & (NCH-1);
  if (c == 0) return;
  int h = (blockIdx.x >> 4) & 15;
  int b = blockIdx.x >> 8;
  int p = threadIdx.x;
  int t0 = c*CT;
  int bh = b*NH + h;
  float hstart[16];
#pragma unroll
  for (int n = 0; n < 16; n++) hstart[n] = 0.f;
  for (int j = 0; j < c; j++){
    float Pj = Ps[bh*NCH + j];
    const float* Hj = Hs + ((size_t)(bh*NCH + j))*1024;
#pragma unroll
    for (int n = 0; n < 16; n++) hstart[n] = fmaf(Pj, hstart[n], Hj[n*64 + p]);
  }
  __shared__ __align__(16) float sC[CT][16];
  __shared__ float sdA[CT];
  const float* Cb  = Cm + ((size_t)b*SEQ + t0)*DSTATE;
  const float* dAb = dAv + ((size_t)b*SEQ + t0)*NH + h;
  float*       yb  = y  + ((size_t)b*SEQ + t0)*DIN + h*HD;
#pragma unroll
  for (int k = 0; k < (CT*16)/64; k++){
    int i = p + k*64;
    ((float*)sC)[i] = Cb[i];
  }
#pragma unroll
  for (int k = 0; k < CT/64; k++){
    int i = p + k*64;
    sdA[i] = dAb[(size_t)i*NH];
  }
  __syncthreads();

  float cp = 1.f;
  float ycur[16], ynxt[16];
#pragma unroll
  for (int j = 0; j < 16; j++) ycur[j] = yb[(size_t)j*DIN + p];
  for (int tt = 0; tt < CT; tt += 16){
    bool pf = (tt + 16 < CT);
    if (pf){
#pragma unroll
      for (int j = 0; j < 16; j++) ynxt[j] = yb[(size_t)(tt+16+j)*DIN + p];
    }
#pragma unroll
    for (int j = 0; j < 16; j++){
      int t = tt + j;
      cp *= sdA[t];
      float4 c0 = *(const float4*)&sC[t][0];
      float4 c1 = *(const float4*)&sC[t][4];
      float4 c2 = *(const float4*)&sC[t][8];
      float4 c3 = *(const float4*)&sC[t][12];
      float a0 = hstart[0]*c0.x;  a0 = fmaf(hstart[1],  c0.y, a0);
      a0 = fmaf(hstart[2],  c0.z, a0); a0 = fmaf(hstart[3],  c0.w, a0);
      float a1 = hstart[4]*c1.x;  a1 = fmaf(hstart[5],  c1.y, a1);
      a1 = fmaf(hstart[6],  c1.z, a1); a1 = fmaf(hstart[7],  c1.w, a1);
      float a2 = hstart[8]*c2.x;  a2 = fmaf(hstart[9],  c2.y, a2);
      a2 = fmaf(hstart[10], c2.z, a2); a2 = fmaf(hstart[11], c2.w, a2);
      float a3 = hstart[12]*c3.x; a3 = fmaf(hstart[13], c3.y, a3);
      a3 = fmaf(hstart[14], c3.z, a3); a3 = fmaf(hstart[15], c3.w, a3);
      float dot = (a0+a1)+(a2+a3);
      yb[(size_t)t*DIN + p] = ycur[j] + cp*dot;
    }
    if (pf){
#pragma unroll
      for (int j = 0; j < 16; j++) ycur[j] = ynxt[j];
    }
  }
}

// ---------------- y = (yscan + D*x)*silu(z); rmsnorm(1024); out bf16 ----------------
__global__ __launch_bounds__(256)
void gated_rms_k(const float* __restrict__ y, const float* __restrict__ xs,
                 const float* __restrict__ zx, const float* __restrict__ Dp,
                 const float* __restrict__ normw, unsigned short* __restrict__ out){
  __shared__ float sbuf[4];
  int r = blockIdx.x;
  const float* yr = y + (size_t)r*DIN;
  const float* xr = xs + (size_t)r*DIN;
  const float* zr = zx + (size_t)r*DINPROJ;
  float vals[4]; float ss = 0.f;
#pragma unroll
  for (int i = 0; i < 4; i++){
    int d = threadIdx.x + i*256;
    float yv = yr[d] + Dp[d >> 6]*xr[d];
    float z = zr[d];
    float g = yv*(z*sigf(z));
    vals[i] = g; ss += g*g;
  }
  ss = block_reduce_256(ss, sbuf);
  float rs = rsqrtf(ss*(1.f/DIN) + 1e-5f);
#pragma unroll
  for (int i = 0; i < 4; i++){
    int d = threadIdx.x + i*256;
    out[(size_t)r*DIN + d] = f2bf(normw[d]*vals[i]*rs);
  }
}

// ---------------- hsum = outf + flip(outb) + hid; h2_bf = rmsnorm(hsum) ----------------
__global__ __launch_bounds__(256)
void addres_rms_k(const float* __restrict__ outf, const float* __restrict__ outb,
                  const float* __restrict__ hid, const float* __restrict__ w,
                  float* __restrict__ hsum, unsigned short* __restrict__ h2b){
  __shared__ float sbuf[4];
  int r = blockIdx.x;
  int l = r & (SEQ-1);
  int rb = (r - l) + ((SEQ-1) - l);
  float vals[2]; float ss = 0.f;
#pragma unroll
  for (int i = 0; i < 2; i++){
    int d = threadIdx.x + i*256;
    float v = outf[(size_t)r*DM + d] + outb[(size_t)rb*DM + d] + hid[(size_t)r*DM + d];
    hsum[(size_t)r*DM + d] = v;
    vals[i] = v; ss += v*v;
  }
  ss = block_reduce_256(ss, sbuf);
  float rs = rsqrtf(ss*(1.f/DM) + 1e-6f);
#pragma unroll
  for (int i = 0; i < 2; i++){
    int d = threadIdx.x + i*256;
    h2b[(size_t)r*DM + d] = f2bf(w[d]*vals[i]*rs);
  }
}

extern "C" void kernel_launch(void* const* d_in, const int* in_sizes, int n_in,
                              void* d_out, int out_size, void* d_ws, size_t ws_size,
                              hipStream_t stream){
  const float* hid     = (const float*)d_in[0];
  const float* norm1_w = (const float*)d_in[1];
  const float* wfc_w   = (const float*)d_in[2];
  const float* wfc_b   = (const float*)d_in[3];
  const float* gfc_w   = (const float*)d_in[4];
  const float* gfc_b   = (const float*)d_in[5];
  const float* norm2_w = (const float*)d_in[6];
  const float* fc1_w   = (const float*)d_in[7];
  const float* fc1_b   = (const float*)d_in[8];
  const float* fc2_w   = (const float*)d_in[9];
  const float* fc2_b   = (const float*)d_in[10];
  const float* inproj[2]  = {(const float*)d_in[11], (const float*)d_in[19]};
  const float* convw[2]   = {(const float*)d_in[12], (const float*)d_in[20]};
  const float* convb[2]   = {(const float*)d_in[13], (const float*)d_in[21]};
  const float* dtbias[2]  = {(const float*)d_in[14], (const float*)d_in[22]};
  const float* Alog[2]    = {(const float*)d_in[15], (const float*)d_in[23]};
  const float* Dp[2]      = {(const float*)d_in[16], (const float*)d_in[24]};
  const float* normw[2]   = {(const float*)d_in[17], (const float*)d_in[25]};
  const float* outproj[2] = {(const float*)d_in[18], (const float*)d_in[26]};

  float* ws = (float*)d_ws;
  float* zx    = ws;                        // 8,585,216 f
  float* xs    = zx + 8585216;              // 4,194,304 f
  float* Bmb   = xs + 4194304;              // 65,536 f
  float* Cmb   = Bmb + 65536;               // 65,536 f
  float* dtv   = Cmb + 65536;               // 65,536 f
  float* dAv   = dtv + 65536;               // 65,536 f
  float* ysc   = dAv + 65536;               // 4,194,304 f
  float* outd0 = ysc + 4194304;             // 2,097,152 f
  float* outd1 = outd0 + 2097152;           // 2,097,152 f
  float* hsum  = outd1 + 2097152;           // 2,097,152 f  (hosts Hs/Ps, then ysc_bf)
  float* hnorm = hsum + 2097152;            // 2,097,152 f
  unsigned short* hnorm_bf = (unsigned short*)(hnorm + 2097152);   // 1,048,576 f slots
  unsigned short* wbf = (unsigned short*)(hnorm + 2097152 + 1048576); // 2,686,976 f slots
  // overlays:
  float* Hs = hsum;                  // 524,288 f (scan phase only)
  float* Ps = hsum + 524288;         // 512 f
  unsigned short* ysc_bf = (unsigned short*)hsum;   // post-scan phase
  unsigned short* a1_bf  = (unsigned short*)zx;     // after dir loop
  unsigned short* h2_bf  = (unsigned short*)xs;     // after dir loop
  unsigned short* wi[2] = {wbf, wbf + 1114112};
  unsigned short* wo[2] = {wbf + 2228224, wbf + 2752512};
  unsigned short* wf1 = wbf + 3276800;
  unsigned short* wf2 = wbf + 4325376;

  size_t need_bytes = (size_t)29360128*4;
  if (ws_size < need_bytes) return;

  // weight casts (pad inproj N 2096->2176)
  castpad_k<<<(2176*512)/256, 256, 0, stream>>>(inproj[0], wi[0], 2096, 512, 2176);
  castpad_k<<<(2176*512)/256, 256, 0, stream>>>(inproj[1], wi[1], 2096, 512, 2176);
  castpad_k<<<(512*1024)/256, 256, 0, stream>>>(outproj[0], wo[0], 512, 1024, 512);
  castpad_k<<<(512*1024)/256, 256, 0, stream>>>(outproj[1], wo[1], 512, 1024, 512);
  castpad_k<<<(2048*512)/256, 256, 0, stream>>>(fc1_w, wf1, 2048, 512, 2048);
  castpad_k<<<(512*2048)/256, 256, 0, stream>>>(fc2_w, wf2, 512, 2048, 512);

  rmsnorm512_k<<<ROWS, 256, 0, stream>>>(hid, norm1_w, hnorm, hnorm_bf, 1e-6f);
  gated_fusion_k<<<BSZ*(SEQ/16), 256, 0, stream>>>(hnorm, hnorm_bf, wfc_w, wfc_b, gfc_w, gfc_b);

  float* outd[2] = {outd0, outd1};
  for (int dir = 0; dir < 2; dir++){
    mgemm_k<8,2,4,4,2><<<dim3(2176/128, 4096/128), 512, 0, stream>>>(
        hnorm_bf, wi[dir], nullptr, nullptr, nullptr, zx, nullptr, 512, DINPROJ, dir, 0);
    skinny48_k<<<ROWS, 256, 0, stream>>>(hnorm, inproj[dir], zx, dir);
    conv_silu_k<<<dim3((CONVDIM+255)/256, ROWS), 256, 0, stream>>>(
        zx, convw[dir], convb[dir], xs, Bmb, Cmb);
    dt_k<<<(ROWS*NH+255)/256, 256, 0, stream>>>(zx, dtbias[dir], Alog[dir], dtv, dAv);
    scanA_k<<<BSZ*NH*NCH, 64, 0, stream>>>(xs, Bmb, Cmb, dtv, dAv, ysc, Hs, Ps);
    scanC_k<<<BSZ*NH*NCH, 64, 0, stream>>>(Cmb, dAv, Hs, Ps, ysc);
    gated_rms_k<<<ROWS, 256, 0, stream>>>(ysc, xs, zx, Dp[dir], normw[dir], ysc_bf);
    mgemm_k<8,2,4,2,2><<<dim3(512/128, 4096/64), 512, 0, stream>>>(
        ysc_bf, wo[dir], nullptr, nullptr, nullptr, outd[dir], nullptr, 1024, DM, 0, 0);
  }

  addres_rms_k<<<ROWS, 256, 0, stream>>>(outd0, outd1, hid, norm2_w, hsum, h2_bf);
  mgemm_k<8,2,4,4,2><<<dim3(2048/128, 4096/128), 512, 0, stream>>>(
      h2_bf, wf1, fc1_b, nullptr, nullptr, nullptr, a1_bf, 512, DFF, 0, 1);
  mgemm_k<8,2,4,2,2><<<dim3(512/128, 4096/64), 512, 0, stream>>>(
      a1_bf, wf2, fc2_b, hsum, hid, (float*)d_out, nullptr, 2048, DM, 0, 0);
}

// Round 6
// 359.164 us; speedup vs baseline: 6.4960x; 1.0045x over previous
//
#include <hip/hip_runtime.h>
#include <math.h>

#define SEQ 2048
#define BSZ 2
#define DM 512
#define DIN 1024
#define DSTATE 16
#define NH 16
#define HD 64
#define CONVDIM 1056
#define DINPROJ 2096
#define DFF 2048
#define ROWS (BSZ*SEQ)
#define NCH 16
#define CT  (SEQ/NCH)

typedef short bf16x8 __attribute__((ext_vector_type(8)));
typedef float f32x4  __attribute__((ext_vector_type(4)));

__device__ __forceinline__ float sigf(float x){ return 1.f/(1.f+expf(-x)); }

__device__ __forceinline__ unsigned short f2bf(float f){
  union { float f; unsigned u; } v; v.f = f;
  unsigned r = (v.u + 0x7FFFu + ((v.u >> 16) & 1u)) >> 16;
  return (unsigned short)r;
}

template<int N> __device__ __forceinline__ void s_wait_vmcnt(){
  if constexpr (N == 0)      asm volatile("s_waitcnt vmcnt(0)" ::: "memory");
  else if constexpr (N == 1) asm volatile("s_waitcnt vmcnt(1)" ::: "memory");
  else if constexpr (N == 2) asm volatile("s_waitcnt vmcnt(2)" ::: "memory");
  else if constexpr (N == 3) asm volatile("s_waitcnt vmcnt(3)" ::: "memory");
  else if constexpr (N == 4) asm volatile("s_waitcnt vmcnt(4)" ::: "memory");
  else if constexpr (N == 6) asm volatile("s_waitcnt vmcnt(6)" ::: "memory");
  else                       asm volatile("s_waitcnt vmcnt(8)" ::: "memory");
}

__device__ __forceinline__ float wave_reduce(float v){
#pragma unroll
  for (int o = 32; o > 0; o >>= 1) v += __shfl_down(v, o);
  return v;
}

__device__ __forceinline__ float block_reduce_256(float v, float* sbuf){
  v = wave_reduce(v);
  int lane = threadIdx.x & 63, wid = threadIdx.x >> 6;
  if (lane == 0) sbuf[wid] = v;
  __syncthreads();
  float s = sbuf[0] + sbuf[1] + sbuf[2] + sbuf[3];
  __syncthreads();
  return s;
}

// ---------------- weight cast + N-pad to bf16 ----------------
__global__ __launch_bounds__(256)
void castpad_k(const float* __restrict__ in, unsigned short* __restrict__ out,
               int N, int K, int Npad){
  int idx = blockIdx.x*256 + threadIdx.x;
  if (idx >= Npad*K) return;
  int n = idx / K, k = idx - n*K;
  out[idx] = (n < N) ? f2bf(in[(size_t)n*K + k]) : (unsigned short)0;
}

// ---------------- rmsnorm over D=512, writes fp32 + bf16 ----------------
__global__ __launch_bounds__(256)
void rmsnorm512_k(const float* __restrict__ x, const float* __restrict__ w,
                  float* __restrict__ y, unsigned short* __restrict__ yb, float eps){
  __shared__ float sbuf[4];
  int r = blockIdx.x;
  const float* xr = x + (size_t)r*DM;
  float v0 = xr[threadIdx.x];
  float v1 = xr[threadIdx.x + 256];
  float ss = block_reduce_256(v0*v0 + v1*v1, sbuf);
  float rs = rsqrtf(ss*(1.f/DM) + eps);
  float o0 = w[threadIdx.x]*v0*rs;
  float o1 = w[threadIdx.x+256]*v1*rs;
  y[(size_t)r*DM + threadIdx.x]       = o0;
  y[(size_t)r*DM + threadIdx.x + 256] = o1;
  yb[(size_t)r*DM + threadIdx.x]       = f2bf(o0);
  yb[(size_t)r*DM + threadIdx.x + 256] = f2bf(o1);
}

// ---------------- gated fusion (query rows, updates fp32 + bf16) ----------------
__global__ __launch_bounds__(256)
void gated_fusion_k(float* __restrict__ h, unsigned short* __restrict__ hb,
                    const float* __restrict__ wfc_w, const float* __restrict__ wfc_b,
                    const float* __restrict__ gfc_w, const float* __restrict__ gfc_b){
  int c = blockIdx.x;
  float* base = h + (size_t)c*16*DM;
  float* qrow = base + 15*DM;
  unsigned short* qrow_b = hb + (size_t)c*16*DM + 15*DM;
  __shared__ float q[DM];
  __shared__ float dots[16];
  for (int i = threadIdx.x; i < DM; i += 256) q[i] = qrow[i];
  __syncthreads();
  int wid = threadIdx.x >> 6, lane = threadIdx.x & 63;
  for (int f = wid; f < 16; f += 4){
    const float* wf = (f < 15) ? (wfc_w + (size_t)f*DM) : gfc_w;
    float s = 0.f;
    for (int i = lane; i < DM; i += 64) s += q[i]*wf[i];
    s = wave_reduce(s);
    if (lane == 0) dots[f] = s;
  }
  __syncthreads();
  if (threadIdx.x == 0){
    float mx = -1e30f;
    for (int f = 0; f < 15; f++){ dots[f] += wfc_b[f]; mx = fmaxf(mx, dots[f]); }
    float sum = 0.f;
    for (int f = 0; f < 15; f++){ float e = expf(dots[f]-mx); dots[f] = e; sum += e; }
    float inv = 1.f/sum;
    for (int f = 0; f < 15; f++) dots[f] *= inv;
    float g = sigf(dots[15] + gfc_b[0]);
    dots[15] = g*0.98f + 0.01f;
  }
  __syncthreads();
  float gate = dots[15];
  for (int d = threadIdx.x; d < DM; d += 256){
    float agg = 0.f;
#pragma unroll
    for (int f = 0; f < 15; f++) agg += base[(size_t)f*DM + d]*dots[f];
    float qn = q[d]*(1.f-gate) + agg*gate;
    qrow[d] = qn;
    qrow_b[d] = f2bf(qn);
  }
}

// ---------------- MFMA bf16 GEMM, depth-3 counted-vmcnt pipeline ----------------
// C = A @ W^T.  A:(M,K) bf16 (rows flipped per-SEQ if flip), W:(Npad,K) bf16.
// NW waves. Wave grid WM x WN; per-wave FM x FN 16x16 frags; BK=32.
// 4 LDS buffers; tiles staged 3 ahead; per-iter: s_waitcnt vmcnt(2L/L/0) +
// raw s_barrier (NOT __syncthreads - no vmcnt(0) drain), so loads stay in
// flight across ~3 phases (>= HBM latency). L = (BM+BN)/16/NW loads per wave
// per tile (uniform, required for exact per-wave vmcnt arithmetic).
// Bank-conflict fix: K-chunk rotation sigma=(row>>1)&3 applied on the GLOBAL
// source (LDS dest stays linear as global_load_lds requires), inverted on the
// fragment-read slot -> 2-way (free) instead of 8-way conflicts.
template<int NW, int WM, int WN, int FM, int FN>
__global__ __launch_bounds__(NW*64)
void mgemm_k(const unsigned short* __restrict__ A, const unsigned short* __restrict__ W,
             const float* __restrict__ bias, const float* __restrict__ add1,
             const float* __restrict__ add2, float* __restrict__ Cf,
             unsigned short* __restrict__ Cb,
             int K, int Nreal, int flip, int act){
  constexpr int BM = WM*FM*16;
  constexpr int BN = WN*FN*16;
  constexpr int NG = (BM+BN)/16;          // 16-row staging groups
  constexpr int L  = NG/NW;               // loads per wave per tile (uniform)
  static_assert(NG % NW == 0, "staging must be uniform per wave");
  constexpr int BUFS = (BM+BN)*32;        // shorts per K-tile buffer
  __shared__ unsigned short S[4*BUFS];
  int tid = threadIdx.x;
  int w = tid >> 6, lane = tid & 63;
  int n0 = blockIdx.x*BN, m0 = blockIdx.y*BM;
  int wr = w / WN, wc = w % WN;

  f32x4 acc[FM][FN];
#pragma unroll
  for (int i = 0; i < FM; i++)
#pragma unroll
    for (int j = 0; j < FN; j++)
#pragma unroll
      for (int r = 0; r < 4; r++) acc[i][j][r] = 0.f;

  // staging source pointers: group g = w + gi*NW; r16 = lane>>2, chunk = lane&3
  const unsigned short* gp[L];
  int gdst[L];
#pragma unroll
  for (int gi = 0; gi < L; gi++){
    int g = w + gi*NW;
    int r16 = lane >> 2, cch = lane & 3;
    int r = g*16 + r16;
    const unsigned short* src;
    if (r < BM){
      int gm = m0 + r;
      if (flip) gm = (gm & ~(SEQ-1)) | ((SEQ-1) - (gm & (SEQ-1)));
      src = A + (size_t)gm*K;
    } else {
      src = W + (size_t)(n0 + (r - BM))*K;
    }
    int c2 = (cch + ((r16 >> 1) & 3)) & 3;   // rotated source chunk
    gp[gi] = src + c2*8;
    gdst[gi] = g*16*32;                       // shorts (linear dest)
  }
  // fragment LDS offsets (shorts), with inverse-rotation slot
  int aoff[FM], boff[FN];
#pragma unroll
  for (int i = 0; i < FM; i++){
    int R = wr*FM*16 + i*16 + (lane & 15);
    int slot = ((lane >> 4) - ((R >> 1) & 3)) & 3;
    aoff[i] = R*32 + slot*8;
  }
#pragma unroll
  for (int j = 0; j < FN; j++){
    int R = BM + wc*FN*16 + j*16 + (lane & 15);
    int slot = ((lane >> 4) - ((R >> 1) & 3)) & 3;
    boff[j] = R*32 + slot*8;
  }

  int T = K >> 5;
  // prologue: stage tiles 0..2 (T >= 16 for all our shapes)
#pragma unroll
  for (int jt = 0; jt < 3; jt++){
#pragma unroll
    for (int gi = 0; gi < L; gi++)
      __builtin_amdgcn_global_load_lds(
        (const __attribute__((address_space(1))) void*)(gp[gi] + (jt << 5)),
        (__attribute__((address_space(3))) void*)&S[jt*BUFS + gdst[gi]], 16, 0, 0);
  }

  for (int t = 0; t < T; t++){
    int rem = T - 1 - t;
    if (rem >= 2)      s_wait_vmcnt<2*L>();
    else if (rem == 1) s_wait_vmcnt<L>();
    else               s_wait_vmcnt<0>();
    __builtin_amdgcn_s_barrier();
    __builtin_amdgcn_sched_barrier(0);
    const unsigned short* buf = &S[(t & 3)*BUFS];
    bf16x8 af[FM], bfr[FN];
#pragma unroll
    for (int i = 0; i < FM; i++) af[i] = *(const bf16x8*)&buf[aoff[i]];
#pragma unroll
    for (int j = 0; j < FN; j++) bfr[j] = *(const bf16x8*)&buf[boff[j]];
#pragma unroll
    for (int i = 0; i < FM; i++)
#pragma unroll
      for (int j = 0; j < FN; j++)
        acc[i][j] = __builtin_amdgcn_mfma_f32_16x16x32_bf16(af[i], bfr[j], acc[i][j], 0, 0, 0);
    if (t + 3 < T){
#pragma unroll
      for (int gi = 0; gi < L; gi++)
        __builtin_amdgcn_global_load_lds(
          (const __attribute__((address_space(1))) void*)(gp[gi] + ((t + 3) << 5)),
          (__attribute__((address_space(3))) void*)&S[((t + 3) & 3)*BUFS + gdst[gi]], 16, 0, 0);
    }
  }

  // epilogue: D layout col=lane&15, row=(lane>>4)*4+r
  int mbase = m0 + wr*FM*16 + (lane >> 4)*4;
  int nbase = n0 + wc*FN*16 + (lane & 15);
#pragma unroll
  for (int i = 0; i < FM; i++){
#pragma unroll
    for (int j = 0; j < FN; j++){
      int col = nbase + j*16;
      if (col < Nreal){
        float bv = bias ? bias[col] : 0.f;
#pragma unroll
        for (int r = 0; r < 4; r++){
          size_t idx = (size_t)(mbase + i*16 + r)*Nreal + col;
          float x = acc[i][j][r] + bv;
          if (act) x = x*sigf(x);
          if (add1) x += add1[idx] + add2[idx];
          if (Cb) Cb[idx] = f2bf(x); else Cf[idx] = x;
        }
      }
    }
  }
}

// ---------------- fp32 recompute of zx cols 2048..2095 (B/C conv inputs + dt) ----------------
__global__ __launch_bounds__(256)
void skinny48_k(const float* __restrict__ hnorm, const float* __restrict__ W,
                float* __restrict__ zx, int flip){
  int r = blockIdx.x;
  int rf = flip ? ((r & ~(SEQ-1)) | ((SEQ-1) - (r & (SEQ-1)))) : r;
  __shared__ float row[DM];
  row[threadIdx.x] = hnorm[(size_t)rf*DM + threadIdx.x];
  row[threadIdx.x + 256] = hnorm[(size_t)rf*DM + threadIdx.x + 256];
  __syncthreads();
  int wv = threadIdx.x >> 6, lane = threadIdx.x & 63;
  for (int c = wv; c < 48; c += 4){
    const float* wr = W + (size_t)(2048 + c)*DM;
    float s = 0.f;
#pragma unroll
    for (int i = lane; i < DM; i += 64) s += row[i]*wr[i];
    s = wave_reduce(s);
    if (lane == 0) zx[(size_t)r*DINPROJ + 2048 + c] = s;
  }
}

// ---------------- causal depthwise conv (width 4) + silu + split ----------------
__global__ __launch_bounds__(256)
void conv_silu_k(const float* __restrict__ zx, const float* __restrict__ convw,
                 const float* __restrict__ convb,
                 float* __restrict__ xs, float* __restrict__ Bm, float* __restrict__ Cm){
  int c = blockIdx.x*256 + threadIdx.x;
  int r = blockIdx.y;
  if (c >= CONVDIM) return;
  int l = r & (SEQ-1);
  int rbase = r - l;
  float acc = convb[c];
#pragma unroll
  for (int k = 0; k < 4; k++){
    int ls = l + k - 3;
    if (ls >= 0) acc += zx[(size_t)(rbase+ls)*DINPROJ + DIN + c]*convw[c*4 + k];
  }
  float v = acc*sigf(acc);
  if (c < DIN) xs[(size_t)r*DIN + c] = v;
  else if (c < DIN + DSTATE) Bm[(size_t)r*DSTATE + (c - DIN)] = v;
  else Cm[(size_t)r*DSTATE + (c - DIN - DSTATE)] = v;
}

// ---------------- dt: softplus + dA ----------------
__global__ __launch_bounds__(256)
void dt_k(const float* __restrict__ zx, const float* __restrict__ dtbias,
          const float* __restrict__ Alog, float* __restrict__ dtv, float* __restrict__ dAv){
  int idx = blockIdx.x*256 + threadIdx.x;
  if (idx >= ROWS*NH) return;
  int r = idx >> 4, hh = idx & 15;
  float x = zx[(size_t)r*DINPROJ + (DIN + CONVDIM) + hh] + dtbias[hh];
  float sp = (x > 20.f) ? x : log1pf(expf(x));
  dtv[idx] = sp;
  dAv[idx] = expf(-expf(Alog[hh])*sp);
}

// ================= chunked selective scan =================
__global__ __launch_bounds__(64)
void scanA_k(const float* __restrict__ xs, const float* __restrict__ Bm,
             const float* __restrict__ Cm, const float* __restrict__ dtv,
             const float* __restrict__ dAv, float* __restrict__ y,
             float* __restrict__ Hs, float* __restrict__ Ps){
  int c = blockIdx.x & (NCH-1);
  int h = (blockIdx.x >> 4) & 15;
  int b = blockIdx.x >> 8;
  int p = threadIdx.x;
  int t0 = c*CT;
  __shared__ __align__(16) float sB[CT][16];
  __shared__ __align__(16) float sC[CT][16];
  __shared__ float sdt[CT];
  __shared__ float sdA[CT];
  const float* xb  = xs + ((size_t)b*SEQ + t0)*DIN + h*HD;
  float*       yb  = y  + ((size_t)b*SEQ + t0)*DIN + h*HD;
  const float* Bb  = Bm + ((size_t)b*SEQ + t0)*DSTATE;
  const float* Cb  = Cm + ((size_t)b*SEQ + t0)*DSTATE;
  const float* dtb = dtv + ((size_t)b*SEQ + t0)*NH + h;
  const float* dAb = dAv + ((size_t)b*SEQ + t0)*NH + h;
#pragma unroll
  for (int k = 0; k < (CT*16)/64; k++){
    int i = p + k*64;
    ((float*)sB)[i] = Bb[i];
    ((float*)sC)[i] = Cb[i];
  }
#pragma unroll
  for (int k = 0; k < CT/64; k++){
    int i = p + k*64;
    sdt[i] = dtb[(size_t)i*NH];
    sdA[i] = dAb[(size_t)i*NH];
  }
  __syncthreads();

  float hst[16];
#pragma unroll
  for (int n = 0; n < 16; n++) hst[n] = 0.f;
  float P = 1.f;
  float xcur[16], xnxt[16];
#pragma unroll
  for (int j = 0; j < 16; j++) xcur[j] = xb[(size_t)j*DIN + p];

  for (int tt = 0; tt < CT; tt += 16){
    bool pf = (tt + 16 < CT);
    if (pf){
#pragma unroll
      for (int j = 0; j < 16; j++) xnxt[j] = xb[(size_t)(tt+16+j)*DIN + p];
    }
#pragma unroll
    for (int j = 0; j < 16; j++){
      int t = tt + j;
      float xv = xcur[j]*sdt[t];
      float dA = sdA[t];
      P *= dA;
      float4 b0 = *(const float4*)&sB[t][0];
      float4 b1 = *(const float4*)&sB[t][4];
      float4 b2 = *(const float4*)&sB[t][8];
      float4 b3 = *(const float4*)&sB[t][12];
      hst[0]  = fmaf(dA, hst[0],  b0.x*xv);
      hst[1]  = fmaf(dA, hst[1],  b0.y*xv);
      hst[2]  = fmaf(dA, hst[2],  b0.z*xv);
      hst[3]  = fmaf(dA, hst[3],  b0.w*xv);
      hst[4]  = fmaf(dA, hst[4],  b1.x*xv);
      hst[5]  = fmaf(dA, hst[5],  b1.y*xv);
      hst[6]  = fmaf(dA, hst[6],  b1.z*xv);
      hst[7]  = fmaf(dA, hst[7],  b1.w*xv);
      hst[8]  = fmaf(dA, hst[8],  b2.x*xv);
      hst[9]  = fmaf(dA, hst[9],  b2.y*xv);
      hst[10] = fmaf(dA, hst[10], b2.z*xv);
      hst[11] = fmaf(dA, hst[11], b2.w*xv);
      hst[12] = fmaf(dA, hst[12], b3.x*xv);
      hst[13] = fmaf(dA, hst[13], b3.y*xv);
      hst[14] = fmaf(dA, hst[14], b3.z*xv);
      hst[15] = fmaf(dA, hst[15], b3.w*xv);
      float4 c0 = *(const float4*)&sC[t][0];
      float4 c1 = *(const float4*)&sC[t][4];
      float4 c2 = *(const float4*)&sC[t][8];
      float4 c3 = *(const float4*)&sC[t][12];
      float a0 = hst[0]*c0.x;  a0 = fmaf(hst[1],  c0.y, a0);
      a0 = fmaf(hst[2],  c0.z, a0); a0 = fmaf(hst[3],  c0.w, a0);
      float a1 = hst[4]*c1.x;  a1 = fmaf(hst[5],  c1.y, a1);
      a1 = fmaf(hst[6],  c1.z, a1); a1 = fmaf(hst[7],  c1.w, a1);
      float a2 = hst[8]*c2.x;  a2 = fmaf(hst[9],  c2.y, a2);
      a2 = fmaf(hst[10], c2.z, a2); a2 = fmaf(hst[11], c2.w, a2);
      float a3 = hst[12]*c3.x; a3 = fmaf(hst[13], c3.y, a3);
      a3 = fmaf(hst[14], c3.z, a3); a3 = fmaf(hst[15], c3.w, a3);
      yb[(size_t)t*DIN + p] = (a0+a1)+(a2+a3);
    }
    if (pf){
#pragma unroll
      for (int j = 0; j < 16; j++) xcur[j] = xnxt[j];
    }
  }
  size_t base = ((size_t)((b*NH + h)*NCH + c))*1024;
#pragma unroll
  for (int n = 0; n < 16; n++) Hs[base + n*64 + p] = hst[n];
  if (p == 0) Ps[(b*NH + h)*NCH + c] = P;
}

__global__ __launch_bounds__(64)
void scanC_k(const float* __restrict__ Cm, const float* __restrict__ dAv,
             const float* __restrict__ Hs, const float* __restrict__ Ps,
             float* __restrict__ y){
  int c = blockIdx.x & (NCH-1);
  if (c == 0) return;
  int h = (blockIdx.x >> 4) & 15;
  int b = blockIdx.x >> 8;
  int p = threadIdx.x;
  int t0 = c*CT;
  int bh = b*NH + h;
  float hstart[16];
#pragma unroll
  for (int n = 0; n < 16; n++) hstart[n] = 0.f;
  for (int j = 0; j < c; j++){
    float Pj = Ps[bh*NCH + j];
    const float* Hj = Hs + ((size_t)(bh*NCH + j))*1024;
#pragma unroll
    for (int n = 0; n < 16; n++) hstart[n] = fmaf(Pj, hstart[n], Hj[n*64 + p]);
  }
  __shared__ __align__(16) float sC[CT][16];
  __shared__ float sdA[CT];
  const float* Cb  = Cm + ((size_t)b*SEQ + t0)*DSTATE;
  const float* dAb = dAv + ((size_t)b*SEQ + t0)*NH + h;
  float*       yb  = y  + ((size_t)b*SEQ + t0)*DIN + h*HD;
#pragma unroll
  for (int k = 0; k < (CT*16)/64; k++){
    int i = p + k*64;
    ((float*)sC)[i] = Cb[i];
  }
#pragma unroll
  for (int k = 0; k < CT/64; k++){
    int i = p + k*64;
    sdA[i] = dAb[(size_t)i*NH];
  }
  __syncthreads();

  float cp = 1.f;
  float ycur[16], ynxt[16];
#pragma unroll
  for (int j = 0; j < 16; j++) ycur[j] = yb[(size_t)j*DIN + p];
  for (int tt = 0; tt < CT; tt += 16){
    bool pf = (tt + 16 < CT);
    if (pf){
#pragma unroll
      for (int j = 0; j < 16; j++) ynxt[j] = yb[(size_t)(tt+16+j)*DIN + p];
    }
#pragma unroll
    for (int j = 0; j < 16; j++){
      int t = tt + j;
      cp *= sdA[t];
      float4 c0 = *(const float4*)&sC[t][0];
      float4 c1 = *(const float4*)&sC[t][4];
      float4 c2 = *(const float4*)&sC[t][8];
      float4 c3 = *(const float4*)&sC[t][12];
      float a0 = hstart[0]*c0.x;  a0 = fmaf(hstart[1],  c0.y, a0);
      a0 = fmaf(hstart[2],  c0.z, a0); a0 = fmaf(hstart[3],  c0.w, a0);
      float a1 = hstart[4]*c1.x;  a1 = fmaf(hstart[5],  c1.y, a1);
      a1 = fmaf(hstart[6],  c1.z, a1); a1 = fmaf(hstart[7],  c1.w, a1);
      float a2 = hstart[8]*c2.x;  a2 = fmaf(hstart[9],  c2.y, a2);
      a2 = fmaf(hstart[10], c2.z, a2); a2 = fmaf(hstart[11], c2.w, a2);
      float a3 = hstart[12]*c3.x; a3 = fmaf(hstart[13], c3.y, a3);
      a3 = fmaf(hstart[14], c3.z, a3); a3 = fmaf(hstart[15], c3.w, a3);
      float dot = (a0+a1)+(a2+a3);
      yb[(size_t)t*DIN + p] = ycur[j] + cp*dot;
    }
    if (pf){
#pragma unroll
      for (int j = 0; j < 16; j++) ycur[j] = ynxt[j];
    }
  }
}

// ---------------- y = (yscan + D*x)*silu(z); rmsnorm(1024); out bf16 ----------------
__global__ __launch_bounds__(256)
void gated_rms_k(const float* __restrict__ y, const float* __restrict__ xs,
                 const float* __restrict__ zx, const float* __restrict__ Dp,
                 const float* __restrict__ normw, unsigned short* __restrict__ out){
  __shared__ float sbuf[4];
  int r = blockIdx.x;
  const float* yr = y + (size_t)r*DIN;
  const float* xr = xs + (size_t)r*DIN;
  const float* zr = zx + (size_t)r*DINPROJ;
  float vals[4]; float ss = 0.f;
#pragma unroll
  for (int i = 0; i < 4; i++){
    int d = threadIdx.x + i*256;
    float yv = yr[d] + Dp[d >> 6]*xr[d];
    float z = zr[d];
    float g = yv*(z*sigf(z));
    vals[i] = g; ss += g*g;
  }
  ss = block_reduce_256(ss, sbuf);
  float rs = rsqrtf(ss*(1.f/DIN) + 1e-5f);
#pragma unroll
  for (int i = 0; i < 4; i++){
    int d = threadIdx.x + i*256;
    out[(size_t)r*DIN + d] = f2bf(normw[d]*vals[i]*rs);
  }
}

// ---------------- hsum = outf + flip(outb) + hid; h2_bf = rmsnorm(hsum) ----------------
__global__ __launch_bounds__(256)
void addres_rms_k(const float* __restrict__ outf, const float* __restrict__ outb,
                  const float* __restrict__ hid, const float* __restrict__ w,
                  float* __restrict__ hsum, unsigned short* __restrict__ h2b){
  __shared__ float sbuf[4];
  int r = blockIdx.x;
  int l = r & (SEQ-1);
  int rb = (r - l) + ((SEQ-1) - l);
  float vals[2]; float ss = 0.f;
#pragma unroll
  for (int i = 0; i < 2; i++){
    int d = threadIdx.x + i*256;
    float v = outf[(size_t)r*DM + d] + outb[(size_t)rb*DM + d] + hid[(size_t)r*DM + d];
    hsum[(size_t)r*DM + d] = v;
    vals[i] = v; ss += v*v;
  }
  ss = block_reduce_256(ss, sbuf);
  float rs = rsqrtf(ss*(1.f/DM) + 1e-6f);
#pragma unroll
  for (int i = 0; i < 2; i++){
    int d = threadIdx.x + i*256;
    h2b[(size_t)r*DM + d] = f2bf(w[d]*vals[i]*rs);
  }
}

extern "C" void kernel_launch(void* const* d_in, const int* in_sizes, int n_in,
                              void* d_out, int out_size, void* d_ws, size_t ws_size,
                              hipStream_t stream){
  const float* hid     = (const float*)d_in[0];
  const float* norm1_w = (const float*)d_in[1];
  const float* wfc_w   = (const float*)d_in[2];
  const float* wfc_b   = (const float*)d_in[3];
  const float* gfc_w   = (const float*)d_in[4];
  const float* gfc_b   = (const float*)d_in[5];
  const float* norm2_w = (const float*)d_in[6];
  const float* fc1_w   = (const float*)d_in[7];
  const float* fc1_b   = (const float*)d_in[8];
  const float* fc2_w   = (const float*)d_in[9];
  const float* fc2_b   = (const float*)d_in[10];
  const float* inproj[2]  = {(const float*)d_in[11], (const float*)d_in[19]};
  const float* convw[2]   = {(const float*)d_in[12], (const float*)d_in[20]};
  const float* convb[2]   = {(const float*)d_in[13], (const float*)d_in[21]};
  const float* dtbias[2]  = {(const float*)d_in[14], (const float*)d_in[22]};
  const float* Alog[2]    = {(const float*)d_in[15], (const float*)d_in[23]};
  const float* Dp[2]      = {(const float*)d_in[16], (const float*)d_in[24]};
  const float* normw[2]   = {(const float*)d_in[17], (const float*)d_in[25]};
  const float* outproj[2] = {(const float*)d_in[18], (const float*)d_in[26]};

  float* ws = (float*)d_ws;
  float* zx    = ws;                        // 8,585,216 f
  float* xs    = zx + 8585216;              // 4,194,304 f
  float* Bmb   = xs + 4194304;              // 65,536 f
  float* Cmb   = Bmb + 65536;               // 65,536 f
  float* dtv   = Cmb + 65536;               // 65,536 f
  float* dAv   = dtv + 65536;               // 65,536 f
  float* ysc   = dAv + 65536;               // 4,194,304 f
  float* outd0 = ysc + 4194304;             // 2,097,152 f
  float* outd1 = outd0 + 2097152;           // 2,097,152 f
  float* hsum  = outd1 + 2097152;           // 2,097,152 f  (hosts Hs/Ps, then ysc_bf)
  float* hnorm = hsum + 2097152;            // 2,097,152 f
  unsigned short* hnorm_bf = (unsigned short*)(hnorm + 2097152);   // 1,048,576 f slots
  unsigned short* wbf = (unsigned short*)(hnorm + 2097152 + 1048576); // 2,686,976 f slots
  // overlays:
  float* Hs = hsum;                  // 524,288 f (scan phase only)
  float* Ps = hsum + 524288;         // 512 f
  unsigned short* ysc_bf = (unsigned short*)hsum;   // post-scan phase
  unsigned short* a1_bf  = (unsigned short*)zx;     // after dir loop
  unsigned short* h2_bf  = (unsigned short*)xs;     // after dir loop
  unsigned short* wi[2] = {wbf, wbf + 1114112};
  unsigned short* wo[2] = {wbf + 2228224, wbf + 2752512};
  unsigned short* wf1 = wbf + 3276800;
  unsigned short* wf2 = wbf + 4325376;

  size_t need_bytes = (size_t)29360128*4;
  if (ws_size < need_bytes) return;

  // weight casts (pad inproj N 2096->2176)
  castpad_k<<<(2176*512)/256, 256, 0, stream>>>(inproj[0], wi[0], 2096, 512, 2176);
  castpad_k<<<(2176*512)/256, 256, 0, stream>>>(inproj[1], wi[1], 2096, 512, 2176);
  castpad_k<<<(512*1024)/256, 256, 0, stream>>>(outproj[0], wo[0], 512, 1024, 512);
  castpad_k<<<(512*1024)/256, 256, 0, stream>>>(outproj[1], wo[1], 512, 1024, 512);
  castpad_k<<<(2048*512)/256, 256, 0, stream>>>(fc1_w, wf1, 2048, 512, 2048);
  castpad_k<<<(512*2048)/256, 256, 0, stream>>>(fc2_w, wf2, 512, 2048, 512);

  rmsnorm512_k<<<ROWS, 256, 0, stream>>>(hid, norm1_w, hnorm, hnorm_bf, 1e-6f);
  gated_fusion_k<<<BSZ*(SEQ/16), 256, 0, stream>>>(hnorm, hnorm_bf, wfc_w, wfc_b, gfc_w, gfc_b);

  float* outd[2] = {outd0, outd1};
  for (int dir = 0; dir < 2; dir++){
    // inproj: BM=128 BN=128, 544 blocks
    mgemm_k<8,2,4,4,2><<<dim3(2176/128, 4096/128), 512, 0, stream>>>(
        hnorm_bf, wi[dir], nullptr, nullptr, nullptr, zx, nullptr, 512, DINPROJ, dir, 0);
    skinny48_k<<<ROWS, 256, 0, stream>>>(hnorm, inproj[dir], zx, dir);
    conv_silu_k<<<dim3((CONVDIM+255)/256, ROWS), 256, 0, stream>>>(
        zx, convw[dir], convb[dir], xs, Bmb, Cmb);
    dt_k<<<(ROWS*NH+255)/256, 256, 0, stream>>>(zx, dtbias[dir], Alog[dir], dtv, dAv);
    scanA_k<<<BSZ*NH*NCH, 64, 0, stream>>>(xs, Bmb, Cmb, dtv, dAv, ysc, Hs, Ps);
    scanC_k<<<BSZ*NH*NCH, 64, 0, stream>>>(Cmb, dAv, Hs, Ps, ysc);
    gated_rms_k<<<ROWS, 256, 0, stream>>>(ysc, xs, zx, Dp[dir], normw[dir], ysc_bf);
    // outproj: BM=64 BN=64, 512 blocks (2/CU)
    mgemm_k<8,2,4,2,1><<<dim3(512/64, 4096/64), 512, 0, stream>>>(
        ysc_bf, wo[dir], nullptr, nullptr, nullptr, outd[dir], nullptr, 1024, DM, 0, 0);
  }

  addres_rms_k<<<ROWS, 256, 0, stream>>>(outd0, outd1, hid, norm2_w, hsum, h2_bf);
  mgemm_k<8,2,4,4,2><<<dim3(2048/128, 4096/128), 512, 0, stream>>>(
      h2_bf, wf1, fc1_b, nullptr, nullptr, nullptr, a1_bf, 512, DFF, 0, 1);
  mgemm_k<8,2,4,2,1><<<dim3(512/64, 4096/64), 512, 0, stream>>>(
      a1_bf, wf2, fc2_b, hsum, hid, (float*)d_out, nullptr, 2048, DM, 0, 0);
}

// Round 7
// 269.401 us; speedup vs baseline: 8.6605x; 1.3332x over previous
//
#include <hip/hip_runtime.h>
#include <math.h>

#define SEQ 2048
#define BSZ 2
#define DM 512
#define DIN 1024
#define DSTATE 16
#define NH 16
#define HD 64
#define CONVDIM 1056
#define DINPROJ 2096
#define DFF 2048
#define ROWS (BSZ*SEQ)
#define NCH 16
#define CT  (SEQ/NCH)
// per-direction strides (floats)
#define ZXN 8585216ull
#define XSN 4194304ull
#define BCN 65536ull
#define DTN 65536ull
#define YN  4194304ull
#define HSN 524288ull

typedef short bf16x8 __attribute__((ext_vector_type(8)));
typedef float f32x4  __attribute__((ext_vector_type(4)));

__device__ __forceinline__ float sigf(float x){ return 1.f/(1.f+expf(-x)); }

__device__ __forceinline__ unsigned short f2bf(float f){
  union { float f; unsigned u; } v; v.f = f;
  unsigned r = (v.u + 0x7FFFu + ((v.u >> 16) & 1u)) >> 16;
  return (unsigned short)r;
}

template<int N> __device__ __forceinline__ void s_wait_vmcnt(){
  if constexpr (N == 0)      asm volatile("s_waitcnt vmcnt(0)" ::: "memory");
  else if constexpr (N == 1) asm volatile("s_waitcnt vmcnt(1)" ::: "memory");
  else if constexpr (N == 2) asm volatile("s_waitcnt vmcnt(2)" ::: "memory");
  else if constexpr (N == 3) asm volatile("s_waitcnt vmcnt(3)" ::: "memory");
  else                       asm volatile("s_waitcnt vmcnt(4)" ::: "memory");
}

__device__ __forceinline__ float wave_reduce(float v){
#pragma unroll
  for (int o = 32; o > 0; o >>= 1) v += __shfl_down(v, o);
  return v;
}

__device__ __forceinline__ float block_reduce_256(float v, float* sbuf){
  v = wave_reduce(v);
  int lane = threadIdx.x & 63, wid = threadIdx.x >> 6;
  if (lane == 0) sbuf[wid] = v;
  __syncthreads();
  float s = sbuf[0] + sbuf[1] + sbuf[2] + sbuf[3];
  __syncthreads();
  return s;
}

// ---------------- weight cast + N-pad to bf16 (paired) ----------------
__global__ __launch_bounds__(256)
void castpad2_k(const float* __restrict__ in0, const float* __restrict__ in1,
                unsigned short* __restrict__ out0, unsigned short* __restrict__ out1,
                int N, int K, int Npad){
  int tot = Npad*K;
  int idx = blockIdx.x*256 + threadIdx.x;
  const float* in = in0; unsigned short* out = out0;
  if (idx >= tot){ idx -= tot; in = in1; out = out1; }
  if (idx >= tot) return;
  int n = idx / K, k = idx - n*K;
  out[idx] = (n < N) ? f2bf(in[(size_t)n*K + k]) : (unsigned short)0;
}

// ---------------- rmsnorm over D=512, writes fp32 + bf16 ----------------
__global__ __launch_bounds__(256)
void rmsnorm512_k(const float* __restrict__ x, const float* __restrict__ w,
                  float* __restrict__ y, unsigned short* __restrict__ yb, float eps){
  __shared__ float sbuf[4];
  int r = blockIdx.x;
  const float* xr = x + (size_t)r*DM;
  float v0 = xr[threadIdx.x];
  float v1 = xr[threadIdx.x + 256];
  float ss = block_reduce_256(v0*v0 + v1*v1, sbuf);
  float rs = rsqrtf(ss*(1.f/DM) + eps);
  float o0 = w[threadIdx.x]*v0*rs;
  float o1 = w[threadIdx.x+256]*v1*rs;
  y[(size_t)r*DM + threadIdx.x]       = o0;
  y[(size_t)r*DM + threadIdx.x + 256] = o1;
  yb[(size_t)r*DM + threadIdx.x]       = f2bf(o0);
  yb[(size_t)r*DM + threadIdx.x + 256] = f2bf(o1);
}

// ---------------- gated fusion (query rows, updates fp32 + bf16) ----------------
__global__ __launch_bounds__(256)
void gated_fusion_k(float* __restrict__ h, unsigned short* __restrict__ hb,
                    const float* __restrict__ wfc_w, const float* __restrict__ wfc_b,
                    const float* __restrict__ gfc_w, const float* __restrict__ gfc_b){
  int c = blockIdx.x;
  float* base = h + (size_t)c*16*DM;
  float* qrow = base + 15*DM;
  unsigned short* qrow_b = hb + (size_t)c*16*DM + 15*DM;
  __shared__ float q[DM];
  __shared__ float dots[16];
  for (int i = threadIdx.x; i < DM; i += 256) q[i] = qrow[i];
  __syncthreads();
  int wid = threadIdx.x >> 6, lane = threadIdx.x & 63;
  for (int f = wid; f < 16; f += 4){
    const float* wf = (f < 15) ? (wfc_w + (size_t)f*DM) : gfc_w;
    float s = 0.f;
    for (int i = lane; i < DM; i += 64) s += q[i]*wf[i];
    s = wave_reduce(s);
    if (lane == 0) dots[f] = s;
  }
  __syncthreads();
  if (threadIdx.x == 0){
    float mx = -1e30f;
    for (int f = 0; f < 15; f++){ dots[f] += wfc_b[f]; mx = fmaxf(mx, dots[f]); }
    float sum = 0.f;
    for (int f = 0; f < 15; f++){ float e = expf(dots[f]-mx); dots[f] = e; sum += e; }
    float inv = 1.f/sum;
    for (int f = 0; f < 15; f++) dots[f] *= inv;
    float g = sigf(dots[15] + gfc_b[0]);
    dots[15] = g*0.98f + 0.01f;
  }
  __syncthreads();
  float gate = dots[15];
  for (int d = threadIdx.x; d < DM; d += 256){
    float agg = 0.f;
#pragma unroll
    for (int f = 0; f < 15; f++) agg += base[(size_t)f*DM + d]*dots[f];
    float qn = q[d]*(1.f-gate) + agg*gate;
    qrow[d] = qn;
    qrow_b[d] = f2bf(qn);
  }
}

// ---------------- MFMA bf16 GEMM, counted-vmcnt pipeline, dual-dir via z ----------------
// C = A @ W^T.  A:(M,K) bf16 (rows flipped per-SEQ if flip), W:(Npad,K) bf16.
// DEPTH tiles in flight over NBUF cyclic LDS buffers; per-iter wait
// s_waitcnt vmcnt(L*(DEPTH-1)) + raw s_barrier (loads stay in flight across
// DEPTH windows). L = (BM+BN)/16/NW loads/wave/tile (uniform).
// Bank-conflict fix: K-chunk rotation on GLOBAL source, inverted on read slot.
// blockIdx.z = dir: picks W0/W1, offsets A/C by strides, flipArg<0 -> flip=dir.
template<int NW, int WM, int WN, int FM, int FN, int DEPTH, int NBUF>
__global__ __launch_bounds__(NW*64)
void mgemm_k(const unsigned short* __restrict__ A, size_t Astride,
             const unsigned short* __restrict__ W0, const unsigned short* __restrict__ W1,
             const float* __restrict__ bias, const float* __restrict__ add1,
             const float* __restrict__ add2, float* __restrict__ Cf,
             unsigned short* __restrict__ Cb, size_t Cstride,
             int K, int Nreal, int flipArg, int act){
  constexpr int BM = WM*FM*16;
  constexpr int BN = WN*FN*16;
  constexpr int NG = (BM+BN)/16;
  constexpr int L  = NG/NW;
  static_assert(NG % NW == 0, "staging must be uniform per wave");
  constexpr int BUFS = (BM+BN)*32;        // shorts per K-tile buffer
  __shared__ unsigned short S[NBUF*BUFS];
  int tid = threadIdx.x;
  int w = tid >> 6, lane = tid & 63;
  int n0 = blockIdx.x*BN, m0 = blockIdx.y*BM;
  int dir = blockIdx.z;
  const unsigned short* Aa = A + (size_t)dir*Astride;
  const unsigned short* Wd = dir ? W1 : W0;
  int flip = (flipArg < 0) ? dir : flipArg;
  int wr = w / WN, wc = w % WN;

  f32x4 acc[FM][FN];
#pragma unroll
  for (int i = 0; i < FM; i++)
#pragma unroll
    for (int j = 0; j < FN; j++)
#pragma unroll
      for (int r = 0; r < 4; r++) acc[i][j][r] = 0.f;

  const unsigned short* gp[L];
  int gdst[L];
#pragma unroll
  for (int gi = 0; gi < L; gi++){
    int g = w + gi*NW;
    int r16 = lane >> 2, cch = lane & 3;
    int r = g*16 + r16;
    const unsigned short* src;
    if (r < BM){
      int gm = m0 + r;
      if (flip) gm = (gm & ~(SEQ-1)) | ((SEQ-1) - (gm & (SEQ-1)));
      src = Aa + (size_t)gm*K;
    } else {
      src = Wd + (size_t)(n0 + (r - BM))*K;
    }
    int c2 = (cch + ((r16 >> 1) & 3)) & 3;   // rotated source chunk
    gp[gi] = src + c2*8;
    gdst[gi] = g*16*32;                       // shorts (linear dest)
  }
  int aoff[FM], boff[FN];
#pragma unroll
  for (int i = 0; i < FM; i++){
    int R = wr*FM*16 + i*16 + (lane & 15);
    int slot = ((lane >> 4) - ((R >> 1) & 3)) & 3;
    aoff[i] = R*32 + slot*8;
  }
#pragma unroll
  for (int j = 0; j < FN; j++){
    int R = BM + wc*FN*16 + j*16 + (lane & 15);
    int slot = ((lane >> 4) - ((R >> 1) & 3)) & 3;
    boff[j] = R*32 + slot*8;
  }

  int T = K >> 5;
  // prologue: stage tiles 0..DEPTH-1
#pragma unroll
  for (int jt = 0; jt < DEPTH; jt++){
#pragma unroll
    for (int gi = 0; gi < L; gi++)
      __builtin_amdgcn_global_load_lds(
        (const __attribute__((address_space(1))) void*)(gp[gi] + (jt << 5)),
        (__attribute__((address_space(3))) void*)&S[jt*BUFS + gdst[gi]], 16, 0, 0);
  }

  int cs = 0;
  for (int t = 0; t < T; t++){
    int rem = T - 1 - t;
    if (rem >= DEPTH-1)             s_wait_vmcnt<L*(DEPTH-1)>();
    else if constexpr (DEPTH >= 3){ if (rem == 1) s_wait_vmcnt<L>(); else s_wait_vmcnt<0>(); }
    else                            s_wait_vmcnt<0>();
    __builtin_amdgcn_s_barrier();
    __builtin_amdgcn_sched_barrier(0);
    const unsigned short* buf = &S[cs*BUFS];
    bf16x8 af[FM], bfr[FN];
#pragma unroll
    for (int i = 0; i < FM; i++) af[i] = *(const bf16x8*)&buf[aoff[i]];
#pragma unroll
    for (int j = 0; j < FN; j++) bfr[j] = *(const bf16x8*)&buf[boff[j]];
#pragma unroll
    for (int i = 0; i < FM; i++)
#pragma unroll
      for (int j = 0; j < FN; j++)
        acc[i][j] = __builtin_amdgcn_mfma_f32_16x16x32_bf16(af[i], bfr[j], acc[i][j], 0, 0, 0);
    if (t + DEPTH < T){
      int ss = cs + DEPTH; if (ss >= NBUF) ss -= NBUF;   // slot of tile t+DEPTH
#pragma unroll
      for (int gi = 0; gi < L; gi++)
        __builtin_amdgcn_global_load_lds(
          (const __attribute__((address_space(1))) void*)(gp[gi] + ((t + DEPTH) << 5)),
          (__attribute__((address_space(3))) void*)&S[ss*BUFS + gdst[gi]], 16, 0, 0);
    }
    cs = (cs + 1 == NBUF) ? 0 : cs + 1;
  }

  // epilogue: D layout col=lane&15, row=(lane>>4)*4+r
  float* Cfd = Cf ? Cf + (size_t)dir*Cstride : nullptr;
  unsigned short* Cbd = Cb ? Cb + (size_t)dir*Cstride : nullptr;
  int mbase = m0 + wr*FM*16 + (lane >> 4)*4;
  int nbase = n0 + wc*FN*16 + (lane & 15);
#pragma unroll
  for (int i = 0; i < FM; i++){
#pragma unroll
    for (int j = 0; j < FN; j++){
      int col = nbase + j*16;
      if (col < Nreal){
        float bv = bias ? bias[col] : 0.f;
#pragma unroll
        for (int r = 0; r < 4; r++){
          size_t idx = (size_t)(mbase + i*16 + r)*Nreal + col;
          float x = acc[i][j][r] + bv;
          if (act) x = x*sigf(x);
          if (add1) x += add1[idx] + add2[idx];
          if (Cbd) Cbd[idx] = f2bf(x); else Cfd[idx] = x;
        }
      }
    }
  }
}

// ---------------- fp32 recompute of zx cols 2048..2095, both dirs ----------------
__global__ __launch_bounds__(256)
void skinny48_k(const float* __restrict__ hnorm,
                const float* __restrict__ W0, const float* __restrict__ W1,
                float* __restrict__ zx){
  int r = blockIdx.x;
  int dir = blockIdx.y;
  const float* W = dir ? W1 : W0;
  float* zxd = zx + (size_t)dir*ZXN;
  int rf = dir ? ((r & ~(SEQ-1)) | ((SEQ-1) - (r & (SEQ-1)))) : r;
  __shared__ float row[DM];
  row[threadIdx.x] = hnorm[(size_t)rf*DM + threadIdx.x];
  row[threadIdx.x + 256] = hnorm[(size_t)rf*DM + threadIdx.x + 256];
  __syncthreads();
  int wv = threadIdx.x >> 6, lane = threadIdx.x & 63;
  for (int c = wv; c < 48; c += 4){
    const float* wr = W + (size_t)(2048 + c)*DM;
    float s = 0.f;
#pragma unroll
    for (int i = lane; i < DM; i += 64) s += row[i]*wr[i];
    s = wave_reduce(s);
    if (lane == 0) zxd[(size_t)r*DINPROJ + 2048 + c] = s;
  }
}

// ---------------- causal conv4 + silu + split + dt/dA, 4 rows/block, both dirs ----------------
__global__ __launch_bounds__(256)
void conv_dt_k(const float* __restrict__ zx,
               const float* __restrict__ convw0, const float* __restrict__ convw1,
               const float* __restrict__ convb0, const float* __restrict__ convb1,
               const float* __restrict__ dtbias0, const float* __restrict__ dtbias1,
               const float* __restrict__ Alog0, const float* __restrict__ Alog1,
               float* __restrict__ xs, float* __restrict__ Bm, float* __restrict__ Cm,
               float* __restrict__ dtv, float* __restrict__ dAv){
  int dir = blockIdx.z;
  const float* zxd = zx + (size_t)dir*ZXN;
  const float* convw = dir ? convw1 : convw0;
  const float* convb = dir ? convb1 : convb0;
  int r0 = blockIdx.y*4;
  int l0 = r0 & (SEQ-1);
  int rbase = r0 - l0;
  int c = blockIdx.x*256 + threadIdx.x;
  if (c < CONVDIM){
    float w0 = convw[c*4+0], w1 = convw[c*4+1], w2 = convw[c*4+2], w3 = convw[c*4+3];
    float bv = convb[c];
    float v[7];
#pragma unroll
    for (int i = 0; i < 7; i++){
      int ls = l0 - 3 + i;
      v[i] = (ls >= 0) ? zxd[(size_t)(rbase+ls)*DINPROJ + DIN + c] : 0.f;
    }
#pragma unroll
    for (int j = 0; j < 4; j++){
      float acc = bv + v[j]*w0 + v[j+1]*w1 + v[j+2]*w2 + v[j+3]*w3;
      float val = acc*sigf(acc);
      int r = r0 + j;
      if (c < DIN) xs[(size_t)dir*XSN + (size_t)r*DIN + c] = val;
      else if (c < DIN + DSTATE) Bm[(size_t)dir*BCN + (size_t)r*DSTATE + (c - DIN)] = val;
      else Cm[(size_t)dir*BCN + (size_t)r*DSTATE + (c - DIN - DSTATE)] = val;
    }
  } else if (blockIdx.x == 4 && threadIdx.x >= 64 && threadIdx.x < 128){
    const float* dtbias = dir ? dtbias1 : dtbias0;
    const float* Alog   = dir ? Alog1 : Alog0;
    int i = threadIdx.x - 64;       // 0..63 -> 4 rows x 16 heads
    int j = i >> 4, hh = i & 15;
    int r = r0 + j;
    float x = zxd[(size_t)r*DINPROJ + 2080 + hh] + dtbias[hh];
    float sp = (x > 20.f) ? x : log1pf(expf(x));
    dtv[(size_t)dir*DTN + (size_t)r*NH + hh] = sp;
    dAv[(size_t)dir*DTN + (size_t)r*NH + hh] = expf(-expf(Alog[hh])*sp);
  }
}

// ================= chunked selective scan (both dirs in one launch) =================
__global__ __launch_bounds__(64)
void scanA_k(const float* __restrict__ xs, const float* __restrict__ Bm,
             const float* __restrict__ Cm, const float* __restrict__ dtv,
             const float* __restrict__ dAv, float* __restrict__ y,
             float* __restrict__ Hs, float* __restrict__ Ps){
  int gb = blockIdx.x;
  int dir = gb >> 9;
  int idx = gb & 511;
  int c = idx & (NCH-1);
  int h = (idx >> 4) & 15;
  int b = idx >> 8;
  int p = threadIdx.x;
  int t0 = c*CT;
  __shared__ __align__(16) float sB[CT][16];
  __shared__ __align__(16) float sC[CT][16];
  __shared__ float sdt[CT];
  __shared__ float sdA[CT];
  const float* xb  = xs + (size_t)dir*XSN + ((size_t)b*SEQ + t0)*DIN + h*HD;
  float*       yb  = y  + (size_t)dir*YN  + ((size_t)b*SEQ + t0)*DIN + h*HD;
  const float* Bb  = Bm + (size_t)dir*BCN + ((size_t)b*SEQ + t0)*DSTATE;
  const float* Cb  = Cm + (size_t)dir*BCN + ((size_t)b*SEQ + t0)*DSTATE;
  const float* dtb = dtv + (size_t)dir*DTN + ((size_t)b*SEQ + t0)*NH + h;
  const float* dAb = dAv + (size_t)dir*DTN + ((size_t)b*SEQ + t0)*NH + h;
#pragma unroll
  for (int k = 0; k < (CT*16)/64; k++){
    int i = p + k*64;
    ((float*)sB)[i] = Bb[i];
    ((float*)sC)[i] = Cb[i];
  }
#pragma unroll
  for (int k = 0; k < CT/64; k++){
    int i = p + k*64;
    sdt[i] = dtb[(size_t)i*NH];
    sdA[i] = dAb[(size_t)i*NH];
  }
  __syncthreads();

  float hst[16];
#pragma unroll
  for (int n = 0; n < 16; n++) hst[n] = 0.f;
  float P = 1.f;
  float xcur[16], xnxt[16];
#pragma unroll
  for (int j = 0; j < 16; j++) xcur[j] = xb[(size_t)j*DIN + p];

  for (int tt = 0; tt < CT; tt += 16){
    bool pf = (tt + 16 < CT);
    if (pf){
#pragma unroll
      for (int j = 0; j < 16; j++) xnxt[j] = xb[(size_t)(tt+16+j)*DIN + p];
    }
#pragma unroll
    for (int j = 0; j < 16; j++){
      int t = tt + j;
      float xv = xcur[j]*sdt[t];
      float dA = sdA[t];
      P *= dA;
      float4 b0 = *(const float4*)&sB[t][0];
      float4 b1 = *(const float4*)&sB[t][4];
      float4 b2 = *(const float4*)&sB[t][8];
      float4 b3 = *(const float4*)&sB[t][12];
      hst[0]  = fmaf(dA, hst[0],  b0.x*xv);
      hst[1]  = fmaf(dA, hst[1],  b0.y*xv);
      hst[2]  = fmaf(dA, hst[2],  b0.z*xv);
      hst[3]  = fmaf(dA, hst[3],  b0.w*xv);
      hst[4]  = fmaf(dA, hst[4],  b1.x*xv);
      hst[5]  = fmaf(dA, hst[5],  b1.y*xv);
      hst[6]  = fmaf(dA, hst[6],  b1.z*xv);
      hst[7]  = fmaf(dA, hst[7],  b1.w*xv);
      hst[8]  = fmaf(dA, hst[8],  b2.x*xv);
      hst[9]  = fmaf(dA, hst[9],  b2.y*xv);
      hst[10] = fmaf(dA, hst[10], b2.z*xv);
      hst[11] = fmaf(dA, hst[11], b2.w*xv);
      hst[12] = fmaf(dA, hst[12], b3.x*xv);
      hst[13] = fmaf(dA, hst[13], b3.y*xv);
      hst[14] = fmaf(dA, hst[14], b3.z*xv);
      hst[15] = fmaf(dA, hst[15], b3.w*xv);
      float4 c0 = *(const float4*)&sC[t][0];
      float4 c1 = *(const float4*)&sC[t][4];
      float4 c2 = *(const float4*)&sC[t][8];
      float4 c3 = *(const float4*)&sC[t][12];
      float a0 = hst[0]*c0.x;  a0 = fmaf(hst[1],  c0.y, a0);
      a0 = fmaf(hst[2],  c0.z, a0); a0 = fmaf(hst[3],  c0.w, a0);
      float a1 = hst[4]*c1.x;  a1 = fmaf(hst[5],  c1.y, a1);
      a1 = fmaf(hst[6],  c1.z, a1); a1 = fmaf(hst[7],  c1.w, a1);
      float a2 = hst[8]*c2.x;  a2 = fmaf(hst[9],  c2.y, a2);
      a2 = fmaf(hst[10], c2.z, a2); a2 = fmaf(hst[11], c2.w, a2);
      float a3 = hst[12]*c3.x; a3 = fmaf(hst[13], c3.y, a3);
      a3 = fmaf(hst[14], c3.z, a3); a3 = fmaf(hst[15], c3.w, a3);
      yb[(size_t)t*DIN + p] = (a0+a1)+(a2+a3);
    }
    if (pf){
#pragma unroll
      for (int j = 0; j < 16; j++) xcur[j] = xnxt[j];
    }
  }
  size_t base = (size_t)dir*HSN + ((size_t)((b*NH + h)*NCH + c))*1024;
#pragma unroll
  for (int n = 0; n < 16; n++) Hs[base + n*64 + p] = hst[n];
  if (p == 0) Ps[dir*512 + (b*NH + h)*NCH + c] = P;
}

__global__ __launch_bounds__(64)
void scanC_k(const float* __restrict__ Cm, const float* __restrict__ dAv,
             const float* __restrict__ Hs, const float* __restrict__ Ps,
             float* __restrict__ y){
  int gb = blockIdx.x;
  int dir = gb >> 9;
  int idx = gb & 511;
  int c = idx & (NCH-1);
  if (c == 0) return;
  int h = (idx >> 4) & 15;
  int b = idx >> 8;
  int p = threadIdx.x;
  int t0 = c*CT;
  int bh = b*NH + h;
  float hstart[16];
#pragma unroll
  for (int n = 0; n < 16; n++) hstart[n] = 0.f;
  for (int j = 0; j < c; j++){
    float Pj = Ps[dir*512 + bh*NCH + j];
    const float* Hj = Hs + (size_t)dir*HSN + ((size_t)(bh*NCH + j))*1024;
#pragma unroll
    for (int n = 0; n < 16; n++) hstart[n] = fmaf(Pj, hstart[n], Hj[n*64 + p]);
  }
  __shared__ __align__(16) float sC[CT][16];
  __shared__ float sdA[CT];
  const float* Cb  = Cm + (size_t)dir*BCN + ((size_t)b*SEQ + t0)*DSTATE;
  const float* dAb = dAv + (size_t)dir*DTN + ((size_t)b*SEQ + t0)*NH + h;
  float*       yb  = y  + (size_t)dir*YN  + ((size_t)b*SEQ + t0)*DIN + h*HD;
#pragma unroll
  for (int k = 0; k < (CT*16)/64; k++){
    int i = p + k*64;
    ((float*)sC)[i] = Cb[i];
  }
#pragma unroll
  for (int k = 0; k < CT/64; k++){
    int i = p + k*64;
    sdA[i] = dAb[(size_t)i*NH];
  }
  __syncthreads();

  float cp = 1.f;
  float ycur[16], ynxt[16];
#pragma unroll
  for (int j = 0; j < 16; j++) ycur[j] = yb[(size_t)j*DIN + p];
  for (int tt = 0; tt < CT; tt += 16){
    bool pf = (tt + 16 < CT);
    if (pf){
#pragma unroll
      for (int j = 0; j < 16; j++) ynxt[j] = yb[(size_t)(tt+16+j)*DIN + p];
    }
#pragma unroll
    for (int j = 0; j < 16; j++){
      int t = tt + j;
      cp *= sdA[t];
      float4 c0 = *(const float4*)&sC[t][0];
      float4 c1 = *(const float4*)&sC[t][4];
      float4 c2 = *(const float4*)&sC[t][8];
      float4 c3 = *(const float4*)&sC[t][12];
      float a0 = hstart[0]*c0.x;  a0 = fmaf(hstart[1],  c0.y, a0);
      a0 = fmaf(hstart[2],  c0.z, a0); a0 = fmaf(hstart[3],  c0.w, a0);
      float a1 = hstart[4]*c1.x;  a1 = fmaf(hstart[5],  c1.y, a1);
      a1 = fmaf(hstart[6],  c1.z, a1); a1 = fmaf(hstart[7],  c1.w, a1);
      float a2 = hstart[8]*c2.x;  a2 = fmaf(hstart[9],  c2.y, a2);
      a2 = fmaf(hstart[10], c2.z, a2); a2 = fmaf(hstart[11], c2.w, a2);
      float a3 = hstart[12]*c3.x; a3 = fmaf(hstart[13], c3.y, a3);
      a3 = fmaf(hstart[14], c3.z, a3); a3 = fmaf(hstart[15], c3.w, a3);
      float dot = (a0+a1)+(a2+a3);
      yb[(size_t)t*DIN + p] = ycur[j] + cp*dot;
    }
    if (pf){
#pragma unroll
      for (int j = 0; j < 16; j++) ycur[j] = ynxt[j];
    }
  }
}

// ---------------- y = (yscan + D*x)*silu(z); rmsnorm(1024); out bf16; both dirs ----------------
__global__ __launch_bounds__(256)
void gated_rms_k(const float* __restrict__ y, const float* __restrict__ xs,
                 const float* __restrict__ zx,
                 const float* __restrict__ Dp0, const float* __restrict__ Dp1,
                 const float* __restrict__ nw0, const float* __restrict__ nw1,
                 unsigned short* __restrict__ out){
  __shared__ float sbuf[4];
  int r = blockIdx.x;
  int dir = blockIdx.y;
  const float* Dp = dir ? Dp1 : Dp0;
  const float* normw = dir ? nw1 : nw0;
  const float* yr = y + (size_t)dir*YN + (size_t)r*DIN;
  const float* xr = xs + (size_t)dir*XSN + (size_t)r*DIN;
  const float* zr = zx + (size_t)dir*ZXN + (size_t)r*DINPROJ;
  unsigned short* outr = out + (size_t)dir*((size_t)ROWS*DIN) + (size_t)r*DIN;
  int d0 = threadIdx.x*4;
  float4 yv4 = *(const float4*)&yr[d0];
  float4 xv4 = *(const float4*)&xr[d0];
  float4 zv4 = *(const float4*)&zr[d0];
  float Dv = Dp[d0 >> 6];
  float vals[4]; float ss = 0.f;
  float yv[4] = {yv4.x, yv4.y, yv4.z, yv4.w};
  float xv[4] = {xv4.x, xv4.y, xv4.z, xv4.w};
  float zv[4] = {zv4.x, zv4.y, zv4.z, zv4.w};
#pragma unroll
  for (int i = 0; i < 4; i++){
    float g = (yv[i] + Dv*xv[i]) * (zv[i]*sigf(zv[i]));
    vals[i] = g; ss += g*g;
  }
  ss = block_reduce_256(ss, sbuf);
  float rs = rsqrtf(ss*(1.f/DIN) + 1e-5f);
  ushort4 o;
  o.x = f2bf(normw[d0+0]*vals[0]*rs);
  o.y = f2bf(normw[d0+1]*vals[1]*rs);
  o.z = f2bf(normw[d0+2]*vals[2]*rs);
  o.w = f2bf(normw[d0+3]*vals[3]*rs);
  *(ushort4*)&outr[d0] = o;
}

// ---------------- hsum = outf + flip(outb) + hid; h2_bf = rmsnorm(hsum) ----------------
__global__ __launch_bounds__(256)
void addres_rms_k(const float* __restrict__ outf, const float* __restrict__ outb,
                  const float* __restrict__ hid, const float* __restrict__ w,
                  float* __restrict__ hsum, unsigned short* __restrict__ h2b){
  __shared__ float sbuf[4];
  int r = blockIdx.x;
  int l = r & (SEQ-1);
  int rb = (r - l) + ((SEQ-1) - l);
  float vals[2]; float ss = 0.f;
#pragma unroll
  for (int i = 0; i < 2; i++){
    int d = threadIdx.x + i*256;
    float v = outf[(size_t)r*DM + d] + outb[(size_t)rb*DM + d] + hid[(size_t)r*DM + d];
    hsum[(size_t)r*DM + d] = v;
    vals[i] = v; ss += v*v;
  }
  ss = block_reduce_256(ss, sbuf);
  float rs = rsqrtf(ss*(1.f/DM) + 1e-6f);
#pragma unroll
  for (int i = 0; i < 2; i++){
    int d = threadIdx.x + i*256;
    h2b[(size_t)r*DM + d] = f2bf(w[d]*vals[i]*rs);
  }
}

extern "C" void kernel_launch(void* const* d_in, const int* in_sizes, int n_in,
                              void* d_out, int out_size, void* d_ws, size_t ws_size,
                              hipStream_t stream){
  const float* hid     = (const float*)d_in[0];
  const float* norm1_w = (const float*)d_in[1];
  const float* wfc_w   = (const float*)d_in[2];
  const float* wfc_b   = (const float*)d_in[3];
  const float* gfc_w   = (const float*)d_in[4];
  const float* gfc_b   = (const float*)d_in[5];
  const float* norm2_w = (const float*)d_in[6];
  const float* fc1_w   = (const float*)d_in[7];
  const float* fc1_b   = (const float*)d_in[8];
  const float* fc2_w   = (const float*)d_in[9];
  const float* fc2_b   = (const float*)d_in[10];
  const float* inproj[2]  = {(const float*)d_in[11], (const float*)d_in[19]};
  const float* convw[2]   = {(const float*)d_in[12], (const float*)d_in[20]};
  const float* convb[2]   = {(const float*)d_in[13], (const float*)d_in[21]};
  const float* dtbias[2]  = {(const float*)d_in[14], (const float*)d_in[22]};
  const float* Alog[2]    = {(const float*)d_in[15], (const float*)d_in[23]};
  const float* Dp[2]      = {(const float*)d_in[16], (const float*)d_in[24]};
  const float* normw[2]   = {(const float*)d_in[17], (const float*)d_in[25]};
  const float* outproj[2] = {(const float*)d_in[18], (const float*)d_in[26]};

  float* ws = (float*)d_ws;
  float* zx    = ws;                        // 2*ZXN = 17,170,432
  float* xs    = zx + 2*ZXN;                // 2*XSN = 8,388,608
  float* Bmb   = xs + 2*XSN;                // 131,072
  float* Cmb   = Bmb + 2*BCN;               // 131,072
  float* dtv   = Cmb + 2*BCN;               // 131,072
  float* dAv   = dtv + 2*DTN;               // 131,072
  float* ysc   = dAv + 2*DTN;               // 2*YN = 8,388,608
  float* outd  = ysc + 2*YN;                // 4,194,304 (dir-strided by 2,097,152)
  float* hsum  = outd + 4194304;            // 2,097,152 (overlays Hs/Ps during scan)
  float* hnorm = hsum + 2097152;            // 2,097,152
  unsigned short* hnorm_bf = (unsigned short*)(hnorm + 2097152);      // 1,048,576 f
  unsigned short* ysc_bf   = (unsigned short*)(hnorm + 2097152 + 1048576); // 4,194,304 f
  unsigned short* wbf      = (unsigned short*)(hnorm + 2097152 + 1048576 + 4194304); // 2,686,976 f
  // overlays:
  float* Hs = hsum;                       // 2*HSN = 1,048,576 (scan phase only)
  float* Ps = hsum + 2*HSN;               // 1024
  unsigned short* a1_bf = (unsigned short*)zx;   // after scans: zx free post gated_rms
  unsigned short* h2_bf = (unsigned short*)xs;
  unsigned short* wi0 = wbf,            * wi1 = wbf + 1114112;
  unsigned short* wo0 = wbf + 2228224,  * wo1 = wbf + 2752512;
  unsigned short* wf1 = wbf + 3276800,  * wf2 = wbf + 4325376;

  size_t need_bytes = (size_t)50790400*4;   // ~203 MB
  if (ws_size < need_bytes) return;

  // weight casts
  castpad2_k<<<(2*2176*512)/256, 256, 0, stream>>>(inproj[0], inproj[1], wi0, wi1, 2096, 512, 2176);
  castpad2_k<<<(2*512*1024)/256, 256, 0, stream>>>(outproj[0], outproj[1], wo0, wo1, 512, 1024, 512);
  castpad2_k<<<(2048*512)/256, 256, 0, stream>>>(fc1_w, fc1_w, wf1, wf1, 2048, 512, 2048);
  castpad2_k<<<(512*2048)/256, 256, 0, stream>>>(fc2_w, fc2_w, wf2, wf2, 512, 2048, 512);

  rmsnorm512_k<<<ROWS, 256, 0, stream>>>(hid, norm1_w, hnorm, hnorm_bf, 1e-6f);
  gated_fusion_k<<<BSZ*(SEQ/16), 256, 0, stream>>>(hnorm, hnorm_bf, wfc_w, wfc_b, gfc_w, gfc_b);

  // inproj both dirs: 128x128 tile, depth-2 / 3 buffers (48 KB LDS)
  mgemm_k<8,2,4,4,2,2,3><<<dim3(2176/128, 4096/128, 2), 512, 0, stream>>>(
      hnorm_bf, 0, wi0, wi1, nullptr, nullptr, nullptr, zx, nullptr, ZXN,
      512, DINPROJ, -1, 0);
  skinny48_k<<<dim3(ROWS, 2), 256, 0, stream>>>(hnorm, inproj[0], inproj[1], zx);
  conv_dt_k<<<dim3(5, ROWS/4, 2), 256, 0, stream>>>(
      zx, convw[0], convw[1], convb[0], convb[1], dtbias[0], dtbias[1],
      Alog[0], Alog[1], xs, Bmb, Cmb, dtv, dAv);
  scanA_k<<<2*BSZ*NH*NCH, 64, 0, stream>>>(xs, Bmb, Cmb, dtv, dAv, ysc, Hs, Ps);
  scanC_k<<<2*BSZ*NH*NCH, 64, 0, stream>>>(Cmb, dAv, Hs, Ps, ysc);
  gated_rms_k<<<dim3(ROWS, 2), 256, 0, stream>>>(
      ysc, xs, zx, Dp[0], Dp[1], normw[0], normw[1], ysc_bf);
  // outproj both dirs: 64x64 tile, depth-3 / 4 buffers (32 KB LDS)
  mgemm_k<8,2,4,2,1,3,4><<<dim3(512/64, 4096/64, 2), 512, 0, stream>>>(
      ysc_bf, (size_t)ROWS*DIN, wo0, wo1, nullptr, nullptr, nullptr,
      outd, nullptr, 2097152, 1024, DM, 0, 0);

  addres_rms_k<<<ROWS, 256, 0, stream>>>(outd, outd + 2097152, hid, norm2_w, hsum, h2_bf);
  mgemm_k<8,2,4,4,2,2,3><<<dim3(2048/128, 4096/128, 1), 512, 0, stream>>>(
      h2_bf, 0, wf1, wf1, fc1_b, nullptr, nullptr, nullptr, a1_bf, 0,
      512, DFF, 0, 1);
  mgemm_k<8,2,4,2,1,3,4><<<dim3(512/64, 4096/64, 1), 512, 0, stream>>>(
      a1_bf, 0, wf2, wf2, fc2_b, hsum, hid, (float*)d_out, nullptr, 0,
      2048, DM, 0, 0);
}

// Round 8
// 247.904 us; speedup vs baseline: 9.4115x; 1.0867x over previous
//
#include <hip/hip_runtime.h>
#include <math.h>

#define SEQ 2048
#define BSZ 2
#define DM 512
#define DIN 1024
#define DSTATE 16
#define NH 16
#define HD 64
#define CONVDIM 1056
#define DINPROJ 2096
#define DFF 2048
#define ROWS (BSZ*SEQ)
#define NCH 16
#define CT  (SEQ/NCH)
// per-direction strides
#define ZXBN 8388608ull   // shorts: 4096 x 2048 bf16
#define ZXTN 196608ull    // floats: 4096 x 48 fp32 tail (B/C conv in + dt)
#define XSN 4194304ull
#define BCN 65536ull
#define DTN 65536ull
#define YN  4194304ull
#define HSN 524288ull

typedef short bf16x8 __attribute__((ext_vector_type(8)));
typedef float f32x4  __attribute__((ext_vector_type(4)));

__device__ __forceinline__ float sigf(float x){ return 1.f/(1.f+expf(-x)); }

__device__ __forceinline__ unsigned short f2bf(float f){
  union { float f; unsigned u; } v; v.f = f;
  unsigned r = (v.u + 0x7FFFu + ((v.u >> 16) & 1u)) >> 16;
  return (unsigned short)r;
}
__device__ __forceinline__ float bf2f(unsigned short h){
  union { unsigned u; float f; } v; v.u = ((unsigned)h) << 16;
  return v.f;
}

template<int N> __device__ __forceinline__ void s_wait_vmcnt(){
  if constexpr (N == 0)      asm volatile("s_waitcnt vmcnt(0)" ::: "memory");
  else if constexpr (N == 1) asm volatile("s_waitcnt vmcnt(1)" ::: "memory");
  else if constexpr (N == 2) asm volatile("s_waitcnt vmcnt(2)" ::: "memory");
  else if constexpr (N == 3) asm volatile("s_waitcnt vmcnt(3)" ::: "memory");
  else                       asm volatile("s_waitcnt vmcnt(4)" ::: "memory");
}

__device__ __forceinline__ float wave_reduce(float v){
#pragma unroll
  for (int o = 32; o > 0; o >>= 1) v += __shfl_down(v, o);
  return v;
}

__device__ __forceinline__ float block_reduce_256(float v, float* sbuf){
  v = wave_reduce(v);
  int lane = threadIdx.x & 63, wid = threadIdx.x >> 6;
  if (lane == 0) sbuf[wid] = v;
  __syncthreads();
  float s = sbuf[0] + sbuf[1] + sbuf[2] + sbuf[3];
  __syncthreads();
  return s;
}

// ---------------- weight cast + N-pad to bf16 (paired) ----------------
__global__ __launch_bounds__(256)
void castpad2_k(const float* __restrict__ in0, const float* __restrict__ in1,
                unsigned short* __restrict__ out0, unsigned short* __restrict__ out1,
                int N, int K, int Npad){
  int tot = Npad*K;
  int idx = blockIdx.x*256 + threadIdx.x;
  const float* in = in0; unsigned short* out = out0;
  if (idx >= tot){ idx -= tot; in = in1; out = out1; }
  if (idx >= tot) return;
  int n = idx / K, k = idx - n*K;
  out[idx] = (n < N) ? f2bf(in[(size_t)n*K + k]) : (unsigned short)0;
}

// ---------------- rmsnorm over D=512, writes fp32 + bf16 ----------------
__global__ __launch_bounds__(256)
void rmsnorm512_k(const float* __restrict__ x, const float* __restrict__ w,
                  float* __restrict__ y, unsigned short* __restrict__ yb, float eps){
  __shared__ float sbuf[4];
  int r = blockIdx.x;
  const float* xr = x + (size_t)r*DM;
  float v0 = xr[threadIdx.x];
  float v1 = xr[threadIdx.x + 256];
  float ss = block_reduce_256(v0*v0 + v1*v1, sbuf);
  float rs = rsqrtf(ss*(1.f/DM) + eps);
  float o0 = w[threadIdx.x]*v0*rs;
  float o1 = w[threadIdx.x+256]*v1*rs;
  y[(size_t)r*DM + threadIdx.x]       = o0;
  y[(size_t)r*DM + threadIdx.x + 256] = o1;
  yb[(size_t)r*DM + threadIdx.x]       = f2bf(o0);
  yb[(size_t)r*DM + threadIdx.x + 256] = f2bf(o1);
}

// ---------------- gated fusion (query rows, updates fp32 + bf16) ----------------
__global__ __launch_bounds__(256)
void gated_fusion_k(float* __restrict__ h, unsigned short* __restrict__ hb,
                    const float* __restrict__ wfc_w, const float* __restrict__ wfc_b,
                    const float* __restrict__ gfc_w, const float* __restrict__ gfc_b){
  int c = blockIdx.x;
  float* base = h + (size_t)c*16*DM;
  float* qrow = base + 15*DM;
  unsigned short* qrow_b = hb + (size_t)c*16*DM + 15*DM;
  __shared__ float q[DM];
  __shared__ float dots[16];
  for (int i = threadIdx.x; i < DM; i += 256) q[i] = qrow[i];
  __syncthreads();
  int wid = threadIdx.x >> 6, lane = threadIdx.x & 63;
  for (int f = wid; f < 16; f += 4){
    const float* wf = (f < 15) ? (wfc_w + (size_t)f*DM) : gfc_w;
    float s = 0.f;
    for (int i = lane; i < DM; i += 64) s += q[i]*wf[i];
    s = wave_reduce(s);
    if (lane == 0) dots[f] = s;
  }
  __syncthreads();
  if (threadIdx.x == 0){
    float mx = -1e30f;
    for (int f = 0; f < 15; f++){ dots[f] += wfc_b[f]; mx = fmaxf(mx, dots[f]); }
    float sum = 0.f;
    for (int f = 0; f < 15; f++){ float e = expf(dots[f]-mx); dots[f] = e; sum += e; }
    float inv = 1.f/sum;
    for (int f = 0; f < 15; f++) dots[f] *= inv;
    float g = sigf(dots[15] + gfc_b[0]);
    dots[15] = g*0.98f + 0.01f;
  }
  __syncthreads();
  float gate = dots[15];
  for (int d = threadIdx.x; d < DM; d += 256){
    float agg = 0.f;
#pragma unroll
    for (int f = 0; f < 15; f++) agg += base[(size_t)f*DM + d]*dots[f];
    float qn = q[d]*(1.f-gate) + agg*gate;
    qrow[d] = qn;
    qrow_b[d] = f2bf(qn);
  }
}

// ---------------- MFMA bf16 GEMM, counted-vmcnt pipeline + XCD swizzle ----------------
// C = A @ W^T.  A:(M,K) bf16 (rows flipped per-SEQ if flip), W:(N,K) bf16.
// DEPTH tiles in flight over NBUF cyclic LDS buffers; counted vmcnt per iter.
// Bank-conflict fix: K-chunk rotation on GLOBAL source, inverted on read slot.
// XCD swizzle: nwg per z-slice must be %8==0 (all our grids are 512).
template<int NW, int WM, int WN, int FM, int FN, int DEPTH, int NBUF>
__global__ __launch_bounds__(NW*64)
void mgemm_k(const unsigned short* __restrict__ A, size_t Astride,
             const unsigned short* __restrict__ W0, const unsigned short* __restrict__ W1,
             const float* __restrict__ bias, const float* __restrict__ add1,
             const float* __restrict__ add2, float* __restrict__ Cf,
             unsigned short* __restrict__ Cb, size_t Cstride,
             int K, int Nreal, int flipArg, int act){
  constexpr int BM = WM*FM*16;
  constexpr int BN = WN*FN*16;
  constexpr int NG = (BM+BN)/16;
  constexpr int L  = NG/NW;
  static_assert(NG % NW == 0, "staging must be uniform per wave");
  constexpr int BUFS = (BM+BN)*32;        // shorts per K-tile buffer
  __shared__ unsigned short S[NBUF*BUFS];
  int tid = threadIdx.x;
  int w = tid >> 6, lane = tid & 63;
  // XCD-aware remap of (x,y) within this z-slice
  int gx = gridDim.x;
  int nwg = gx*gridDim.y;
  int bid = blockIdx.x + gx*blockIdx.y;
  int swz = (bid & 7)*(nwg >> 3) + (bid >> 3);
  int n0 = (swz % gx)*BN, m0 = (swz / gx)*BM;
  int dir = blockIdx.z;
  const unsigned short* Aa = A + (size_t)dir*Astride;
  const unsigned short* Wd = dir ? W1 : W0;
  int flip = (flipArg < 0) ? dir : flipArg;
  int wr = w / WN, wc = w % WN;

  f32x4 acc[FM][FN];
#pragma unroll
  for (int i = 0; i < FM; i++)
#pragma unroll
    for (int j = 0; j < FN; j++)
#pragma unroll
      for (int r = 0; r < 4; r++) acc[i][j][r] = 0.f;

  const unsigned short* gp[L];
  int gdst[L];
#pragma unroll
  for (int gi = 0; gi < L; gi++){
    int g = w + gi*NW;
    int r16 = lane >> 2, cch = lane & 3;
    int r = g*16 + r16;
    const unsigned short* src;
    if (r < BM){
      int gm = m0 + r;
      if (flip) gm = (gm & ~(SEQ-1)) | ((SEQ-1) - (gm & (SEQ-1)));
      src = Aa + (size_t)gm*K;
    } else {
      src = Wd + (size_t)(n0 + (r - BM))*K;
    }
    int c2 = (cch + ((r16 >> 1) & 3)) & 3;   // rotated source chunk
    gp[gi] = src + c2*8;
    gdst[gi] = g*16*32;                       // shorts (linear dest)
  }
  int aoff[FM], boff[FN];
#pragma unroll
  for (int i = 0; i < FM; i++){
    int R = wr*FM*16 + i*16 + (lane & 15);
    int slot = ((lane >> 4) - ((R >> 1) & 3)) & 3;
    aoff[i] = R*32 + slot*8;
  }
#pragma unroll
  for (int j = 0; j < FN; j++){
    int R = BM + wc*FN*16 + j*16 + (lane & 15);
    int slot = ((lane >> 4) - ((R >> 1) & 3)) & 3;
    boff[j] = R*32 + slot*8;
  }

  int T = K >> 5;
  // prologue: stage tiles 0..DEPTH-1
#pragma unroll
  for (int jt = 0; jt < DEPTH; jt++){
#pragma unroll
    for (int gi = 0; gi < L; gi++)
      __builtin_amdgcn_global_load_lds(
        (const __attribute__((address_space(1))) void*)(gp[gi] + (jt << 5)),
        (__attribute__((address_space(3))) void*)&S[jt*BUFS + gdst[gi]], 16, 0, 0);
  }

  int cs = 0;
  for (int t = 0; t < T; t++){
    int rem = T - 1 - t;
    if (rem >= DEPTH-1)             s_wait_vmcnt<L*(DEPTH-1)>();
    else if constexpr (DEPTH >= 3){ if (rem == 1) s_wait_vmcnt<L>(); else s_wait_vmcnt<0>(); }
    else                            s_wait_vmcnt<0>();
    __builtin_amdgcn_s_barrier();
    __builtin_amdgcn_sched_barrier(0);
    const unsigned short* buf = &S[cs*BUFS];
    bf16x8 af[FM], bfr[FN];
#pragma unroll
    for (int i = 0; i < FM; i++) af[i] = *(const bf16x8*)&buf[aoff[i]];
#pragma unroll
    for (int j = 0; j < FN; j++) bfr[j] = *(const bf16x8*)&buf[boff[j]];
#pragma unroll
    for (int i = 0; i < FM; i++)
#pragma unroll
      for (int j = 0; j < FN; j++)
        acc[i][j] = __builtin_amdgcn_mfma_f32_16x16x32_bf16(af[i], bfr[j], acc[i][j], 0, 0, 0);
    if (t + DEPTH < T){
      int ss = cs + DEPTH; if (ss >= NBUF) ss -= NBUF;
#pragma unroll
      for (int gi = 0; gi < L; gi++)
        __builtin_amdgcn_global_load_lds(
          (const __attribute__((address_space(1))) void*)(gp[gi] + ((t + DEPTH) << 5)),
          (__attribute__((address_space(3))) void*)&S[ss*BUFS + gdst[gi]], 16, 0, 0);
    }
    cs = (cs + 1 == NBUF) ? 0 : cs + 1;
  }

  // epilogue: D layout col=lane&15, row=(lane>>4)*4+r
  float* Cfd = Cf ? Cf + (size_t)dir*Cstride : nullptr;
  unsigned short* Cbd = Cb ? Cb + (size_t)dir*Cstride : nullptr;
  int mbase = m0 + wr*FM*16 + (lane >> 4)*4;
  int nbase = n0 + wc*FN*16 + (lane & 15);
#pragma unroll
  for (int i = 0; i < FM; i++){
#pragma unroll
    for (int j = 0; j < FN; j++){
      int col = nbase + j*16;
      if (col < Nreal){
        float bv = bias ? bias[col] : 0.f;
#pragma unroll
        for (int r = 0; r < 4; r++){
          size_t idx = (size_t)(mbase + i*16 + r)*Nreal + col;
          float x = acc[i][j][r] + bv;
          if (act) x = x*sigf(x);
          if (add1) x += add1[idx] + add2[idx];
          if (Cbd) Cbd[idx] = f2bf(x); else Cfd[idx] = x;
        }
      }
    }
  }
}

// ---------------- fp32 zx tail: cols 2048..2095 -> zxt (48 cols), both dirs ----------------
__global__ __launch_bounds__(256)
void skinny48_k(const float* __restrict__ hnorm,
                const float* __restrict__ W0, const float* __restrict__ W1,
                float* __restrict__ zxt){
  int r = blockIdx.x;
  int dir = blockIdx.y;
  const float* W = dir ? W1 : W0;
  float* zt = zxt + (size_t)dir*ZXTN;
  int rf = dir ? ((r & ~(SEQ-1)) | ((SEQ-1) - (r & (SEQ-1)))) : r;
  __shared__ float row[DM];
  row[threadIdx.x] = hnorm[(size_t)rf*DM + threadIdx.x];
  row[threadIdx.x + 256] = hnorm[(size_t)rf*DM + threadIdx.x + 256];
  __syncthreads();
  int wv = threadIdx.x >> 6, lane = threadIdx.x & 63;
  for (int c = wv; c < 48; c += 4){
    const float* wr = W + (size_t)(2048 + c)*DM;
    float s = 0.f;
#pragma unroll
    for (int i = lane; i < DM; i += 64) s += row[i]*wr[i];
    s = wave_reduce(s);
    if (lane == 0) zt[(size_t)r*48 + c] = s;
  }
}

// ---------------- causal conv4 + silu + split + dt/dA, 4 rows/block, both dirs ----------------
// x-conv inputs (channels 0..1023) from zxb bf16 cols 1024..2047; B/C conv inputs
// (channels 1024..1055) from zxt fp32 cols 0..31; dt heads from zxt cols 32..47.
__global__ __launch_bounds__(256)
void conv_dt_k(const unsigned short* __restrict__ zxb, const float* __restrict__ zxt,
               const float* __restrict__ convw0, const float* __restrict__ convw1,
               const float* __restrict__ convb0, const float* __restrict__ convb1,
               const float* __restrict__ dtbias0, const float* __restrict__ dtbias1,
               const float* __restrict__ Alog0, const float* __restrict__ Alog1,
               float* __restrict__ xs, float* __restrict__ Bm, float* __restrict__ Cm,
               float* __restrict__ dtv, float* __restrict__ dAv){
  int dir = blockIdx.z;
  const unsigned short* zb = zxb + (size_t)dir*ZXBN;
  const float* zt = zxt + (size_t)dir*ZXTN;
  const float* convw = dir ? convw1 : convw0;
  const float* convb = dir ? convb1 : convb0;
  int r0 = blockIdx.y*4;
  int l0 = r0 & (SEQ-1);
  int rbase = r0 - l0;
  int c = blockIdx.x*256 + threadIdx.x;
  if (c < CONVDIM){
    float w0 = convw[c*4+0], w1 = convw[c*4+1], w2 = convw[c*4+2], w3 = convw[c*4+3];
    float bv = convb[c];
    float v[7];
#pragma unroll
    for (int i = 0; i < 7; i++){
      int ls = l0 - 3 + i;
      if (ls < 0) v[i] = 0.f;
      else if (c < DIN) v[i] = bf2f(zb[(size_t)(rbase+ls)*2048 + 1024 + c]);
      else v[i] = zt[(size_t)(rbase+ls)*48 + (c - DIN)];
    }
#pragma unroll
    for (int j = 0; j < 4; j++){
      float acc = bv + v[j]*w0 + v[j+1]*w1 + v[j+2]*w2 + v[j+3]*w3;
      float val = acc*sigf(acc);
      int r = r0 + j;
      if (c < DIN) xs[(size_t)dir*XSN + (size_t)r*DIN + c] = val;
      else if (c < DIN + DSTATE) Bm[(size_t)dir*BCN + (size_t)r*DSTATE + (c - DIN)] = val;
      else Cm[(size_t)dir*BCN + (size_t)r*DSTATE + (c - DIN - DSTATE)] = val;
    }
  } else if (blockIdx.x == 4 && threadIdx.x >= 64 && threadIdx.x < 128){
    const float* dtbias = dir ? dtbias1 : dtbias0;
    const float* Alog   = dir ? Alog1 : Alog0;
    int i = threadIdx.x - 64;       // 0..63 -> 4 rows x 16 heads
    int j = i >> 4, hh = i & 15;
    int r = r0 + j;
    float x = zt[(size_t)r*48 + 32 + hh] + dtbias[hh];
    float sp = (x > 20.f) ? x : log1pf(expf(x));
    dtv[(size_t)dir*DTN + (size_t)r*NH + hh] = sp;
    dAv[(size_t)dir*DTN + (size_t)r*NH + hh] = expf(-expf(Alog[hh])*sp);
  }
}

// ================= chunked selective scan (both dirs in one launch) =================
__global__ __launch_bounds__(64)
void scanA_k(const float* __restrict__ xs, const float* __restrict__ Bm,
             const float* __restrict__ Cm, const float* __restrict__ dtv,
             const float* __restrict__ dAv, float* __restrict__ y,
             float* __restrict__ Hs, float* __restrict__ Ps){
  int gb = blockIdx.x;
  int dir = gb >> 9;
  int idx = gb & 511;
  int c = idx & (NCH-1);
  int h = (idx >> 4) & 15;
  int b = idx >> 8;
  int p = threadIdx.x;
  int t0 = c*CT;
  __shared__ __align__(16) float sB[CT][16];
  __shared__ __align__(16) float sC[CT][16];
  __shared__ float sdt[CT];
  __shared__ float sdA[CT];
  const float* xb  = xs + (size_t)dir*XSN + ((size_t)b*SEQ + t0)*DIN + h*HD;
  float*       yb  = y  + (size_t)dir*YN  + ((size_t)b*SEQ + t0)*DIN + h*HD;
  const float* Bb  = Bm + (size_t)dir*BCN + ((size_t)b*SEQ + t0)*DSTATE;
  const float* Cb  = Cm + (size_t)dir*BCN + ((size_t)b*SEQ + t0)*DSTATE;
  const float* dtb = dtv + (size_t)dir*DTN + ((size_t)b*SEQ + t0)*NH + h;
  const float* dAb = dAv + (size_t)dir*DTN + ((size_t)b*SEQ + t0)*NH + h;
#pragma unroll
  for (int k = 0; k < (CT*16)/64; k++){
    int i = p + k*64;
    ((float*)sB)[i] = Bb[i];
    ((float*)sC)[i] = Cb[i];
  }
#pragma unroll
  for (int k = 0; k < CT/64; k++){
    int i = p + k*64;
    sdt[i] = dtb[(size_t)i*NH];
    sdA[i] = dAb[(size_t)i*NH];
  }
  __syncthreads();

  float hst[16];
#pragma unroll
  for (int n = 0; n < 16; n++) hst[n] = 0.f;
  float P = 1.f;
  float xcur[16], xnxt[16];
#pragma unroll
  for (int j = 0; j < 16; j++) xcur[j] = xb[(size_t)j*DIN + p];

  for (int tt = 0; tt < CT; tt += 16){
    bool pf = (tt + 16 < CT);
    if (pf){
#pragma unroll
      for (int j = 0; j < 16; j++) xnxt[j] = xb[(size_t)(tt+16+j)*DIN + p];
    }
#pragma unroll
    for (int j = 0; j < 16; j++){
      int t = tt + j;
      float xv = xcur[j]*sdt[t];
      float dA = sdA[t];
      P *= dA;
      float4 b0 = *(const float4*)&sB[t][0];
      float4 b1 = *(const float4*)&sB[t][4];
      float4 b2 = *(const float4*)&sB[t][8];
      float4 b3 = *(const float4*)&sB[t][12];
      hst[0]  = fmaf(dA, hst[0],  b0.x*xv);
      hst[1]  = fmaf(dA, hst[1],  b0.y*xv);
      hst[2]  = fmaf(dA, hst[2],  b0.z*xv);
      hst[3]  = fmaf(dA, hst[3],  b0.w*xv);
      hst[4]  = fmaf(dA, hst[4],  b1.x*xv);
      hst[5]  = fmaf(dA, hst[5],  b1.y*xv);
      hst[6]  = fmaf(dA, hst[6],  b1.z*xv);
      hst[7]  = fmaf(dA, hst[7],  b1.w*xv);
      hst[8]  = fmaf(dA, hst[8],  b2.x*xv);
      hst[9]  = fmaf(dA, hst[9],  b2.y*xv);
      hst[10] = fmaf(dA, hst[10], b2.z*xv);
      hst[11] = fmaf(dA, hst[11], b2.w*xv);
      hst[12] = fmaf(dA, hst[12], b3.x*xv);
      hst[13] = fmaf(dA, hst[13], b3.y*xv);
      hst[14] = fmaf(dA, hst[14], b3.z*xv);
      hst[15] = fmaf(dA, hst[15], b3.w*xv);
      float4 c0 = *(const float4*)&sC[t][0];
      float4 c1 = *(const float4*)&sC[t][4];
      float4 c2 = *(const float4*)&sC[t][8];
      float4 c3 = *(const float4*)&sC[t][12];
      float a0 = hst[0]*c0.x;  a0 = fmaf(hst[1],  c0.y, a0);
      a0 = fmaf(hst[2],  c0.z, a0); a0 = fmaf(hst[3],  c0.w, a0);
      float a1 = hst[4]*c1.x;  a1 = fmaf(hst[5],  c1.y, a1);
      a1 = fmaf(hst[6],  c1.z, a1); a1 = fmaf(hst[7],  c1.w, a1);
      float a2 = hst[8]*c2.x;  a2 = fmaf(hst[9],  c2.y, a2);
      a2 = fmaf(hst[10], c2.z, a2); a2 = fmaf(hst[11], c2.w, a2);
      float a3 = hst[12]*c3.x; a3 = fmaf(hst[13], c3.y, a3);
      a3 = fmaf(hst[14], c3.z, a3); a3 = fmaf(hst[15], c3.w, a3);
      yb[(size_t)t*DIN + p] = (a0+a1)+(a2+a3);
    }
    if (pf){
#pragma unroll
      for (int j = 0; j < 16; j++) xcur[j] = xnxt[j];
    }
  }
  size_t base = (size_t)dir*HSN + ((size_t)((b*NH + h)*NCH + c))*1024;
#pragma unroll
  for (int n = 0; n < 16; n++) Hs[base + n*64 + p] = hst[n];
  if (p == 0) Ps[dir*512 + (b*NH + h)*NCH + c] = P;
}

__global__ __launch_bounds__(64)
void scanC_k(const float* __restrict__ Cm, const float* __restrict__ dAv,
             const float* __restrict__ Hs, const float* __restrict__ Ps,
             float* __restrict__ y){
  int gb = blockIdx.x;
  int dir = gb >> 9;
  int idx = gb & 511;
  int c = idx & (NCH-1);
  if (c == 0) return;
  int h = (idx >> 4) & 15;
  int b = idx >> 8;
  int p = threadIdx.x;
  int t0 = c*CT;
  int bh = b*NH + h;
  float hstart[16];
#pragma unroll
  for (int n = 0; n < 16; n++) hstart[n] = 0.f;
  for (int j = 0; j < c; j++){
    float Pj = Ps[dir*512 + bh*NCH + j];
    const float* Hj = Hs + (size_t)dir*HSN + ((size_t)(bh*NCH + j))*1024;
#pragma unroll
    for (int n = 0; n < 16; n++) hstart[n] = fmaf(Pj, hstart[n], Hj[n*64 + p]);
  }
  __shared__ __align__(16) float sC[CT][16];
  __shared__ float sdA[CT];
  const float* Cb  = Cm + (size_t)dir*BCN + ((size_t)b*SEQ + t0)*DSTATE;
  const float* dAb = dAv + (size_t)dir*DTN + ((size_t)b*SEQ + t0)*NH + h;
  float*       yb  = y  + (size_t)dir*YN  + ((size_t)b*SEQ + t0)*DIN + h*HD;
#pragma unroll
  for (int k = 0; k < (CT*16)/64; k++){
    int i = p + k*64;
    ((float*)sC)[i] = Cb[i];
  }
#pragma unroll
  for (int k = 0; k < CT/64; k++){
    int i = p + k*64;
    sdA[i] = dAb[(size_t)i*NH];
  }
  __syncthreads();

  float cp = 1.f;
  float ycur[16], ynxt[16];
#pragma unroll
  for (int j = 0; j < 16; j++) ycur[j] = yb[(size_t)j*DIN + p];
  for (int tt = 0; tt < CT; tt += 16){
    bool pf = (tt + 16 < CT);
    if (pf){
#pragma unroll
      for (int j = 0; j < 16; j++) ynxt[j] = yb[(size_t)(tt+16+j)*DIN + p];
    }
#pragma unroll
    for (int j = 0; j < 16; j++){
      int t = tt + j;
      cp *= sdA[t];
      float4 c0 = *(const float4*)&sC[t][0];
      float4 c1 = *(const float4*)&sC[t][4];
      float4 c2 = *(const float4*)&sC[t][8];
      float4 c3 = *(const float4*)&sC[t][12];
      float a0 = hstart[0]*c0.x;  a0 = fmaf(hstart[1],  c0.y, a0);
      a0 = fmaf(hstart[2],  c0.z, a0); a0 = fmaf(hstart[3],  c0.w, a0);
      float a1 = hstart[4]*c1.x;  a1 = fmaf(hstart[5],  c1.y, a1);
      a1 = fmaf(hstart[6],  c1.z, a1); a1 = fmaf(hstart[7],  c1.w, a1);
      float a2 = hstart[8]*c2.x;  a2 = fmaf(hstart[9],  c2.y, a2);
      a2 = fmaf(hstart[10], c2.z, a2); a2 = fmaf(hstart[11], c2.w, a2);
      float a3 = hstart[12]*c3.x; a3 = fmaf(hstart[13], c3.y, a3);
      a3 = fmaf(hstart[14], c3.z, a3); a3 = fmaf(hstart[15], c3.w, a3);
      float dot = (a0+a1)+(a2+a3);
      yb[(size_t)t*DIN + p] = ycur[j] + cp*dot;
    }
    if (pf){
#pragma unroll
      for (int j = 0; j < 16; j++) ycur[j] = ynxt[j];
    }
  }
}

// ---------------- y = (yscan + D*x)*silu(z); rmsnorm(1024); out bf16; both dirs ----------------
__global__ __launch_bounds__(256)
void gated_rms_k(const float* __restrict__ y, const float* __restrict__ xs,
                 const unsigned short* __restrict__ zxb,
                 const float* __restrict__ Dp0, const float* __restrict__ Dp1,
                 const float* __restrict__ nw0, const float* __restrict__ nw1,
                 unsigned short* __restrict__ out){
  __shared__ float sbuf[4];
  int r = blockIdx.x;
  int dir = blockIdx.y;
  const float* Dp = dir ? Dp1 : Dp0;
  const float* normw = dir ? nw1 : nw0;
  const float* yr = y + (size_t)dir*YN + (size_t)r*DIN;
  const float* xr = xs + (size_t)dir*XSN + (size_t)r*DIN;
  const unsigned short* zr = zxb + (size_t)dir*ZXBN + (size_t)r*2048;
  unsigned short* outr = out + (size_t)dir*((size_t)ROWS*DIN) + (size_t)r*DIN;
  int d0 = threadIdx.x*4;
  float4 yv4 = *(const float4*)&yr[d0];
  float4 xv4 = *(const float4*)&xr[d0];
  ushort4 zu4 = *(const ushort4*)&zr[d0];
  float Dv = Dp[d0 >> 6];
  float vals[4]; float ss = 0.f;
  float yv[4] = {yv4.x, yv4.y, yv4.z, yv4.w};
  float xv[4] = {xv4.x, xv4.y, xv4.z, xv4.w};
  float zv[4] = {bf2f(zu4.x), bf2f(zu4.y), bf2f(zu4.z), bf2f(zu4.w)};
#pragma unroll
  for (int i = 0; i < 4; i++){
    float g = (yv[i] + Dv*xv[i]) * (zv[i]*sigf(zv[i]));
    vals[i] = g; ss += g*g;
  }
  ss = block_reduce_256(ss, sbuf);
  float rs = rsqrtf(ss*(1.f/DIN) + 1e-5f);
  ushort4 o;
  o.x = f2bf(normw[d0+0]*vals[0]*rs);
  o.y = f2bf(normw[d0+1]*vals[1]*rs);
  o.z = f2bf(normw[d0+2]*vals[2]*rs);
  o.w = f2bf(normw[d0+3]*vals[3]*rs);
  *(ushort4*)&outr[d0] = o;
}

// ---------------- hsum = outf + flip(outb) + hid; h2_bf = rmsnorm(hsum) ----------------
__global__ __launch_bounds__(256)
void addres_rms_k(const float* __restrict__ outf, const float* __restrict__ outb,
                  const float* __restrict__ hid, const float* __restrict__ w,
                  float* __restrict__ hsum, unsigned short* __restrict__ h2b){
  __shared__ float sbuf[4];
  int r = blockIdx.x;
  int l = r & (SEQ-1);
  int rb = (r - l) + ((SEQ-1) - l);
  float vals[2]; float ss = 0.f;
#pragma unroll
  for (int i = 0; i < 2; i++){
    int d = threadIdx.x + i*256;
    float v = outf[(size_t)r*DM + d] + outb[(size_t)rb*DM + d] + hid[(size_t)r*DM + d];
    hsum[(size_t)r*DM + d] = v;
    vals[i] = v; ss += v*v;
  }
  ss = block_reduce_256(ss, sbuf);
  float rs = rsqrtf(ss*(1.f/DM) + 1e-6f);
#pragma unroll
  for (int i = 0; i < 2; i++){
    int d = threadIdx.x + i*256;
    h2b[(size_t)r*DM + d] = f2bf(w[d]*vals[i]*rs);
  }
}

extern "C" void kernel_launch(void* const* d_in, const int* in_sizes, int n_in,
                              void* d_out, int out_size, void* d_ws, size_t ws_size,
                              hipStream_t stream){
  const float* hid     = (const float*)d_in[0];
  const float* norm1_w = (const float*)d_in[1];
  const float* wfc_w   = (const float*)d_in[2];
  const float* wfc_b   = (const float*)d_in[3];
  const float* gfc_w   = (const float*)d_in[4];
  const float* gfc_b   = (const float*)d_in[5];
  const float* norm2_w = (const float*)d_in[6];
  const float* fc1_w   = (const float*)d_in[7];
  const float* fc1_b   = (const float*)d_in[8];
  const float* fc2_w   = (const float*)d_in[9];
  const float* fc2_b   = (const float*)d_in[10];
  const float* inproj[2]  = {(const float*)d_in[11], (const float*)d_in[19]};
  const float* convw[2]   = {(const float*)d_in[12], (const float*)d_in[20]};
  const float* convb[2]   = {(const float*)d_in[13], (const float*)d_in[21]};
  const float* dtbias[2]  = {(const float*)d_in[14], (const float*)d_in[22]};
  const float* Alog[2]    = {(const float*)d_in[15], (const float*)d_in[23]};
  const float* Dp[2]      = {(const float*)d_in[16], (const float*)d_in[24]};
  const float* normw[2]   = {(const float*)d_in[17], (const float*)d_in[25]};
  const float* outproj[2] = {(const float*)d_in[18], (const float*)d_in[26]};

  float* ws = (float*)d_ws;
  unsigned short* zxb = (unsigned short*)ws;        // 2 x 4096x2048 bf16 = 8,388,608 f
  float* zxt   = ws + 8388608;              // 2 x 4096x48 = 393,216 f
  float* xs    = zxt + 2*ZXTN;              // 8,388,608 f
  float* Bmb   = xs + 2*XSN;                // 131,072
  float* Cmb   = Bmb + 2*BCN;               // 131,072
  float* dtv   = Cmb + 2*BCN;               // 131,072
  float* dAv   = dtv + 2*DTN;               // 131,072
  float* ysc   = dAv + 2*DTN;               // 8,388,608 f
  float* outd  = ysc + 2*YN;                // 4,194,304 (dir-strided by 2,097,152)
  float* hsum  = outd + 4194304;            // 2,097,152 (overlays Hs/Ps during scan)
  float* hnorm = hsum + 2097152;            // 2,097,152
  unsigned short* hnorm_bf = (unsigned short*)(hnorm + 2097152);            // 1,048,576 f
  unsigned short* ysc_bf   = (unsigned short*)(hnorm + 2097152 + 1048576); // 4,194,304 f
  unsigned short* wbf      = (unsigned short*)(hnorm + 2097152 + 1048576 + 4194304); // 2,621,440 f
  // overlays:
  float* Hs = hsum;                       // 2*HSN = 1,048,576 (scan phase only)
  float* Ps = hsum + 2*HSN;               // 1024
  unsigned short* a1_bf = (unsigned short*)zxb;   // zxb free after gated_rms
  unsigned short* h2_bf = (unsigned short*)xs;    // xs free after gated_rms
  unsigned short* wi0 = wbf,            * wi1 = wbf + 1048576;   // 2048x512 each
  unsigned short* wo0 = wbf + 2097152,  * wo1 = wbf + 2621440;   // 512x1024 each
  unsigned short* wf1 = wbf + 3145728;                            // 2048x512
  unsigned short* wf2 = wbf + 4194304;                            // 512x2048
  size_t need_bytes = (size_t)44957696*4;   // ~180 MB
  if (ws_size < need_bytes) return;

  // weight casts (wi: only first 2048 rows needed - tail handled by skinny48)
  castpad2_k<<<(2*2048*512)/256, 256, 0, stream>>>(inproj[0], inproj[1], wi0, wi1, 2048, 512, 2048);
  castpad2_k<<<(2*512*1024)/256, 256, 0, stream>>>(outproj[0], outproj[1], wo0, wo1, 512, 1024, 512);
  castpad2_k<<<(2048*512)/256, 256, 0, stream>>>(fc1_w, fc1_w, wf1, wf1, 2048, 512, 2048);
  castpad2_k<<<(512*2048)/256, 256, 0, stream>>>(fc2_w, fc2_w, wf2, wf2, 512, 2048, 512);

  rmsnorm512_k<<<ROWS, 256, 0, stream>>>(hid, norm1_w, hnorm, hnorm_bf, 1e-6f);
  gated_fusion_k<<<BSZ*(SEQ/16), 256, 0, stream>>>(hnorm, hnorm_bf, wfc_w, wfc_b, gfc_w, gfc_b);

  // inproj both dirs: 4096x2048x512, 128x128 tile, depth-2/3buf, bf16 out
  mgemm_k<8,2,4,4,2,2,3><<<dim3(2048/128, 4096/128, 2), 512, 0, stream>>>(
      hnorm_bf, 0, wi0, wi1, nullptr, nullptr, nullptr, nullptr, zxb, ZXBN,
      512, 2048, -1, 0);
  skinny48_k<<<dim3(ROWS, 2), 256, 0, stream>>>(hnorm, inproj[0], inproj[1], zxt);
  conv_dt_k<<<dim3(5, ROWS/4, 2), 256, 0, stream>>>(
      zxb, zxt, convw[0], convw[1], convb[0], convb[1], dtbias[0], dtbias[1],
      Alog[0], Alog[1], xs, Bmb, Cmb, dtv, dAv);
  scanA_k<<<2*BSZ*NH*NCH, 64, 0, stream>>>(xs, Bmb, Cmb, dtv, dAv, ysc, Hs, Ps);
  scanC_k<<<2*BSZ*NH*NCH, 64, 0, stream>>>(Cmb, dAv, Hs, Ps, ysc);
  gated_rms_k<<<dim3(ROWS, 2), 256, 0, stream>>>(
      ysc, xs, zxb, Dp[0], Dp[1], normw[0], normw[1], ysc_bf);
  // outproj both dirs: 64x64 tile, depth-3/4buf
  mgemm_k<8,2,4,2,1,3,4><<<dim3(512/64, 4096/64, 2), 512, 0, stream>>>(
      ysc_bf, (size_t)ROWS*DIN, wo0, wo1, nullptr, nullptr, nullptr,
      outd, nullptr, 2097152, 1024, DM, 0, 0);

  addres_rms_k<<<ROWS, 256, 0, stream>>>(outd, outd + 2097152, hid, norm2_w, hsum, h2_bf);
  mgemm_k<8,2,4,4,2,2,3><<<dim3(2048/128, 4096/128, 1), 512, 0, stream>>>(
      h2_bf, 0, wf1, wf1, fc1_b, nullptr, nullptr, nullptr, a1_bf, 0,
      512, DFF, 0, 1);
  mgemm_k<8,2,4,2,1,3,4><<<dim3(512/64, 4096/64, 1), 512, 0, stream>>>(
      a1_bf, 0, wf2, wf2, fc2_b, hsum, hid, (float*)d_out, nullptr, 0,
      2048, DM, 0, 0);
}